// Round 3
// baseline (304.265 us; speedup 1.0000x reference)
//
#include <hip/hip_runtime.h>
#include <cstdint>
#include <cstddef>

// Problem constants (B, C, N fixed by the reference)
#define KB_  8
#define KC_  512
#define KC2_ 256
#define KN_  2048

typedef __attribute__((ext_vector_type(8))) __bf16 bf16x8;
typedef __attribute__((ext_vector_type(4))) float f32x4;

__device__ __forceinline__ unsigned short f2bf(float f) {
  union { float f; unsigned u; } x; x.f = f;
  unsigned r = x.u + 0x7fffu + ((x.u >> 16) & 1u);  // RNE (finite values only)
  return (unsigned short)(r >> 16);
}
__device__ __forceinline__ float bf2f(unsigned short h) {
  union { unsigned u; float f; } x; x.u = ((unsigned)h) << 16;
  return x.f;
}

// async global->LDS, 16B per lane; LDS dest = wave-uniform base + lane*16
#define GLD16(g, l) __builtin_amdgcn_global_load_lds( \
    (__attribute__((address_space(1))) void*)(g),     \
    (__attribute__((address_space(3))) void*)(l), 16, 0, 0)

// ---------------- weight fp32 -> bf16 convert (single) ----------------
__global__ __launch_bounds__(256) void cvt_kernel(const float* __restrict__ in,
                                                  unsigned short* __restrict__ out, int n) {
  int i = (blockIdx.x * 256 + threadIdx.x) * 4;
  if (i >= n) return;
  float4 f = *(const float4*)(in + i);
  ushort4 u = { f2bf(f.x), f2bf(f.y), f2bf(f.z), f2bf(f.w) };
  *(ushort4*)(out + i) = u;
}

// ---------------- weight fp32 -> bf16 hi/lo pair ----------------
__global__ __launch_bounds__(256) void cvt_pair_kernel(const float* __restrict__ in,
                                                       unsigned short* __restrict__ hi,
                                                       unsigned short* __restrict__ lo, int n) {
  int i = (blockIdx.x * 256 + threadIdx.x) * 4;
  if (i >= n) return;
  float4 f = *(const float4*)(in + i);
  ushort4 h = { f2bf(f.x), f2bf(f.y), f2bf(f.z), f2bf(f.w) };
  ushort4 l = { f2bf(f.x - bf2f(h.x)), f2bf(f.y - bf2f(h.y)),
                f2bf(f.z - bf2f(h.z)), f2bf(f.w - bf2f(h.w)) };
  *(ushort4*)(hi + i) = h;
  *(ushort4*)(lo + i) = l;
}

// ---------------- tiled transpose: fp32 [R][Cc] -> bf16 hi/lo [Cc][R] ----------------
__global__ __launch_bounds__(256) void transpose_pair_kernel(const float* __restrict__ in,
                                                             long sIn,
                                                             unsigned short* __restrict__ hi,
                                                             unsigned short* __restrict__ lo,
                                                             long sOut, int R, int Cc) {
  int b = blockIdx.z;
  const float* I = in + (size_t)b * sIn;
  __shared__ float tile[64][65];
  int t = threadIdx.x;
  int r0 = blockIdx.y * 64, c0 = blockIdx.x * 64;
#pragma unroll
  for (int k = 0; k < 4; k++) {
    int vi = k * 256 + t, rr = vi >> 4, cv = vi & 15;
    float4 f = *(const float4*)&I[(size_t)(r0 + rr) * Cc + c0 + cv * 4];
    tile[rr][cv * 4 + 0] = f.x; tile[rr][cv * 4 + 1] = f.y;
    tile[rr][cv * 4 + 2] = f.z; tile[rr][cv * 4 + 3] = f.w;
  }
  __syncthreads();
#pragma unroll
  for (int k = 0; k < 4; k++) {
    int vi = k * 256 + t, cc = vi >> 4, rv = vi & 15;
    float f0 = tile[rv * 4 + 0][cc], f1 = tile[rv * 4 + 1][cc];
    float f2 = tile[rv * 4 + 2][cc], f3 = tile[rv * 4 + 3][cc];
    ushort4 h = { f2bf(f0), f2bf(f1), f2bf(f2), f2bf(f3) };
    ushort4 l = { f2bf(f0 - bf2f(h.x)), f2bf(f1 - bf2f(h.y)),
                  f2bf(f2 - bf2f(h.z)), f2bf(f3 - bf2f(h.w)) };
    size_t o = (size_t)b * sOut + (size_t)(c0 + cc) * R + r0 + rv * 4;
    *(ushort4*)&hi[o] = h;
    *(ushort4*)&lo[o] = l;
  }
}

// ---------------- tiled transpose: bf16 [R][Cc] -> bf16 [Cc][R] ----------------
__global__ __launch_bounds__(256) void transpose_bf_kernel(const unsigned short* __restrict__ in,
                                                           long sIn,
                                                           unsigned short* __restrict__ out,
                                                           long sOut, int R, int Cc) {
  int b = blockIdx.z;
  const unsigned short* I = in + (size_t)b * sIn;
  __shared__ unsigned short tile[64][72];
  int t = threadIdx.x;
  int r0 = blockIdx.y * 64, c0 = blockIdx.x * 64;
#pragma unroll
  for (int k = 0; k < 4; k++) {
    int vi = k * 256 + t, rr = vi >> 4, cv = vi & 15;
    ushort4 u = *(const ushort4*)&I[(size_t)(r0 + rr) * Cc + c0 + cv * 4];
    tile[rr][cv * 4 + 0] = u.x; tile[rr][cv * 4 + 1] = u.y;
    tile[rr][cv * 4 + 2] = u.z; tile[rr][cv * 4 + 3] = u.w;
  }
  __syncthreads();
#pragma unroll
  for (int k = 0; k < 4; k++) {
    int vi = k * 256 + t, cc = vi >> 4, rv = vi & 15;
    ushort4 u = { tile[rv * 4 + 0][cc], tile[rv * 4 + 1][cc],
                  tile[rv * 4 + 2][cc], tile[rv * 4 + 3][cc] };
    *(ushort4*)&out[(size_t)b * sOut + (size_t)(c0 + cc) * R + r0 + rv * 4] = u;
  }
}

// ---------------- per-row max & 1/sum(exp) over energy rows ----------------
__global__ __launch_bounds__(256) void rowstats_kernel(const float* __restrict__ energy,
                                                       float* __restrict__ rm,
                                                       float* __restrict__ rsv) {
  int b = blockIdx.y;
  int n = blockIdx.x * 4 + (threadIdx.x >> 6);
  int lane = threadIdx.x & 63;
  const float* e = energy + ((size_t)b * KN_ + n) * KN_;
  float4 v[8];
  float mx = -3.4e38f;
#pragma unroll
  for (int i = 0; i < 8; i++) {
    v[i] = *(const float4*)&e[(i * 64 + lane) * 4];
    mx = fmaxf(mx, fmaxf(fmaxf(v[i].x, v[i].y), fmaxf(v[i].z, v[i].w)));
  }
#pragma unroll
  for (int o = 32; o > 0; o >>= 1) mx = fmaxf(mx, __shfl_xor(mx, o, 64));
  float s = 0.f;
#pragma unroll
  for (int i = 0; i < 8; i++)
    s += __expf(v[i].x - mx) + __expf(v[i].y - mx) + __expf(v[i].z - mx) + __expf(v[i].w - mx);
#pragma unroll
  for (int o = 32; o > 0; o >>= 1) s += __shfl_xor(s, o, 64);
  if (lane == 0) {
    rm[(size_t)b * KN_ + n] = mx;
    rsv[(size_t)b * KN_ + n] = 1.0f / s;
  }
}

// ---------------- softmax + transpose: p[n][m] -> pT[m][n] bf16; partial colsums ----
__global__ __launch_bounds__(256) void softmaxT_kernel(const float* __restrict__ energy,
                                                       const float* __restrict__ rm,
                                                       const float* __restrict__ rsv,
                                                       unsigned short* __restrict__ pT,
                                                       float* __restrict__ colpart) {
  int b = blockIdx.z;
  const float* E = energy + (size_t)b * KN_ * KN_;
  unsigned short* O = pT + (size_t)b * KN_ * KN_;
  __shared__ float tile[64][65];
  int t = threadIdx.x;
  int r0 = blockIdx.y * 64, c0 = blockIdx.x * 64;  // r = n (rows), c = m (cols)
#pragma unroll
  for (int k = 0; k < 4; k++) {
    int vi = k * 256 + t, rr = vi >> 4, cv = vi & 15;
    int n = r0 + rr;
    float m_ = rm[(size_t)b * KN_ + n], si = rsv[(size_t)b * KN_ + n];
    float4 f = *(const float4*)&E[(size_t)n * KN_ + c0 + cv * 4];
    tile[rr][cv * 4 + 0] = __expf(f.x - m_) * si;
    tile[rr][cv * 4 + 1] = __expf(f.y - m_) * si;
    tile[rr][cv * 4 + 2] = __expf(f.z - m_) * si;
    tile[rr][cv * 4 + 3] = __expf(f.w - m_) * si;
  }
  __syncthreads();
  if (t < 64) {  // deterministic partial column sums (reduced later)
    float s = 0.f;
#pragma unroll
    for (int r = 0; r < 64; r++) s += tile[r][t];
    colpart[(((size_t)b * 32) + blockIdx.y) * KN_ + c0 + t] = s;
  }
#pragma unroll
  for (int k = 0; k < 4; k++) {
    int vi = k * 256 + t, cc = vi >> 4, rv = vi & 15;
    ushort4 u;
    u.x = f2bf(tile[rv * 4 + 0][cc]); u.y = f2bf(tile[rv * 4 + 1][cc]);
    u.z = f2bf(tile[rv * 4 + 2][cc]); u.w = f2bf(tile[rv * 4 + 3][cc]);
    *(ushort4*)&O[(size_t)(c0 + cc) * KN_ + r0 + rv * 4] = u;
  }
}

__global__ __launch_bounds__(256) void colreduce_kernel(const float* __restrict__ colpart,
                                                        float* __restrict__ colsum) {
  int b = blockIdx.y;
  int m = blockIdx.x * 256 + threadIdx.x;
  float s = 0.f;
#pragma unroll
  for (int r = 0; r < 32; r++) s += colpart[((size_t)b * 32 + r) * KN_ + m];
  colsum[(size_t)b * KN_ + m] = s;
}

// ---------------- epilogue variants ----------------
enum { EPI_BIAS = 1, EPI_F32 = 2, EPI_XR = 3, EPI_FINAL = 4, EPI_PAIR = 5 };

struct EpiParams {
  const float* bias;
  const float* xf;  long xf_stride;
  const float* colsum; long cs_stride;
  const float* gamma; const float* beta; const float* mean; const float* var;
};

// ---------------- MFMA GEMM (single bf16): C[M][N] = A[M][K] * Bt[N][K]^T ----------------
template<int EPI>
__global__ __launch_bounds__(256) void gemm_kernel(
    const unsigned short* __restrict__ A, long sA, int lda,
    const unsigned short* __restrict__ Bt, long sB, int ldb,
    void* __restrict__ Cv, long sC, int ldc,
    int K, EpiParams ep) {
  const int b = blockIdx.z;
  A  += (size_t)b * sA;
  Bt += (size_t)b * sB;
  const int m0 = blockIdx.y * 128, n0 = blockIdx.x * 128;
  __shared__ unsigned short As[128][32];
  __shared__ unsigned short Bs[128][32];
  const int t = threadIdx.x, lane = t & 63, w = t >> 6;
  const int wr = w >> 1, wc = w & 1;
  const int srow = t >> 2, scol = (t & 3) * 8;
  const int lr = lane & 15, lk = (lane >> 4) * 8;

  f32x4 acc[4][4];
  const f32x4 z = {0.f, 0.f, 0.f, 0.f};
#pragma unroll
  for (int i = 0; i < 4; i++)
#pragma unroll
    for (int j = 0; j < 4; j++) acc[i][j] = z;

  for (int kt = 0; kt < K; kt += 32) {
    const unsigned short* gA = A + (size_t)(m0 + srow) * lda + kt + scol;
    const unsigned short* gB = Bt + (size_t)(n0 + srow) * ldb + kt + scol;
    char* lA = (char*)(&As[0][0]);
    char* lB = (char*)(&Bs[0][0]);
    GLD16(gA, lA + w * 1024);
    GLD16(gA + (size_t)64 * lda, lA + 4096 + w * 1024);
    GLD16(gB, lB + w * 1024);
    GLD16(gB + (size_t)64 * ldb, lB + 4096 + w * 1024);
    __syncthreads();
    bf16x8 af[4], bfv[4];
#pragma unroll
    for (int i = 0; i < 4; i++) af[i] = *(const bf16x8*)&As[wr * 64 + i * 16 + lr][lk];
#pragma unroll
    for (int j = 0; j < 4; j++) bfv[j] = *(const bf16x8*)&Bs[wc * 64 + j * 16 + lr][lk];
#pragma unroll
    for (int i = 0; i < 4; i++)
#pragma unroll
      for (int j = 0; j < 4; j++)
        acc[i][j] = __builtin_amdgcn_mfma_f32_16x16x32_bf16(af[i], bfv[j], acc[i][j], 0, 0, 0);
    __syncthreads();
  }

#pragma unroll
  for (int i = 0; i < 4; i++) {
#pragma unroll
    for (int r = 0; r < 4; r++) {
      const int row = m0 + wr * 64 + i * 16 + ((lane >> 4) << 2) + r;
      float pbias = 0.f, pinv = 1.f, padd = 0.f;
      if constexpr (EPI == EPI_BIAS) pbias = ep.bias[row];
      if constexpr (EPI == EPI_FINAL) {
        pbias = ep.bias[row];
        float iv = ep.gamma[row] * rsqrtf(ep.var[row] + 1e-5f);
        pinv = iv;
        padd = ep.beta[row] - ep.mean[row] * iv;
      }
#pragma unroll
      for (int j = 0; j < 4; j++) {
        const int col = n0 + wc * 64 + j * 16 + lr;
        float v = acc[i][j][r];
        if constexpr (EPI == EPI_BIAS) {
          ((unsigned short*)Cv)[(size_t)b * sC + (size_t)row * ldc + col] = f2bf(v + pbias);
        } else if constexpr (EPI == EPI_F32) {
          ((float*)Cv)[(size_t)b * sC + (size_t)row * ldc + col] = v;
        } else if constexpr (EPI == EPI_XR) {
          float cs = ep.colsum[(size_t)b * ep.cs_stride + col];
          float xval = ep.xf[(size_t)b * ep.xf_stride + (size_t)row * ldc + col];
          ((unsigned short*)Cv)[(size_t)b * sC + (size_t)row * ldc + col] =
              f2bf(xval - v / (1e-9f + cs));
        } else {  // EPI_FINAL
          float h = (v + pbias) * pinv + padd;
          h = fmaxf(h, 0.f);
          float xval = ep.xf[(size_t)b * ep.xf_stride + (size_t)row * ldc + col];
          ((float*)Cv)[(size_t)b * sC + (size_t)row * ldc + col] = h + xval;
        }
      }
    }
  }
}

// ---------------- MFMA GEMM, split hi/lo operands (fp32-grade): ----------------
// C = (Ahi+Alo)(Bhi+Blo)^T ~= Ahi*Bhi + Ahi*Blo + Alo*Bhi
template<int EPI>
__global__ __launch_bounds__(256) void gemm_split_kernel(
    const unsigned short* __restrict__ Ahi, const unsigned short* __restrict__ Alo,
    long sA, int lda,
    const unsigned short* __restrict__ Bhi, const unsigned short* __restrict__ Blo,
    long sB, int ldb,
    void* __restrict__ Cv, void* __restrict__ Cv2, long sC, int ldc, int K) {
  const int b = blockIdx.z;
  Ahi += (size_t)b * sA; Alo += (size_t)b * sA;
  Bhi += (size_t)b * sB; Blo += (size_t)b * sB;
  const int m0 = blockIdx.y * 128, n0 = blockIdx.x * 128;
  __shared__ unsigned short Ah[128][32], Al[128][32], Bh[128][32], Bl[128][32];
  const int t = threadIdx.x, lane = t & 63, w = t >> 6;
  const int wr = w >> 1, wc = w & 1;
  const int srow = t >> 2, scol = (t & 3) * 8;
  const int lr = lane & 15, lk = (lane >> 4) * 8;

  f32x4 acc[4][4];
  const f32x4 z = {0.f, 0.f, 0.f, 0.f};
#pragma unroll
  for (int i = 0; i < 4; i++)
#pragma unroll
    for (int j = 0; j < 4; j++) acc[i][j] = z;

  for (int kt = 0; kt < K; kt += 32) {
    const size_t ga = (size_t)(m0 + srow) * lda + kt + scol;
    const size_t gb = (size_t)(n0 + srow) * ldb + kt + scol;
    GLD16(Ahi + ga, (char*)(&Ah[0][0]) + w * 1024);
    GLD16(Ahi + ga + (size_t)64 * lda, (char*)(&Ah[0][0]) + 4096 + w * 1024);
    GLD16(Alo + ga, (char*)(&Al[0][0]) + w * 1024);
    GLD16(Alo + ga + (size_t)64 * lda, (char*)(&Al[0][0]) + 4096 + w * 1024);
    GLD16(Bhi + gb, (char*)(&Bh[0][0]) + w * 1024);
    GLD16(Bhi + gb + (size_t)64 * ldb, (char*)(&Bh[0][0]) + 4096 + w * 1024);
    GLD16(Blo + gb, (char*)(&Bl[0][0]) + w * 1024);
    GLD16(Blo + gb + (size_t)64 * ldb, (char*)(&Bl[0][0]) + 4096 + w * 1024);
    __syncthreads();
    bf16x8 ah[4], al[4], bh[4], bl[4];
#pragma unroll
    for (int i = 0; i < 4; i++) {
      ah[i] = *(const bf16x8*)&Ah[wr * 64 + i * 16 + lr][lk];
      al[i] = *(const bf16x8*)&Al[wr * 64 + i * 16 + lr][lk];
    }
#pragma unroll
    for (int j = 0; j < 4; j++) {
      bh[j] = *(const bf16x8*)&Bh[wc * 64 + j * 16 + lr][lk];
      bl[j] = *(const bf16x8*)&Bl[wc * 64 + j * 16 + lr][lk];
    }
#pragma unroll
    for (int i = 0; i < 4; i++)
#pragma unroll
      for (int j = 0; j < 4; j++) {
        acc[i][j] = __builtin_amdgcn_mfma_f32_16x16x32_bf16(al[i], bh[j], acc[i][j], 0, 0, 0);
        acc[i][j] = __builtin_amdgcn_mfma_f32_16x16x32_bf16(ah[i], bl[j], acc[i][j], 0, 0, 0);
        acc[i][j] = __builtin_amdgcn_mfma_f32_16x16x32_bf16(ah[i], bh[j], acc[i][j], 0, 0, 0);
      }
    __syncthreads();
  }

#pragma unroll
  for (int i = 0; i < 4; i++) {
#pragma unroll
    for (int r = 0; r < 4; r++) {
      const int row = m0 + wr * 64 + i * 16 + ((lane >> 4) << 2) + r;
#pragma unroll
      for (int j = 0; j < 4; j++) {
        const int col = n0 + wc * 64 + j * 16 + lr;
        float v = acc[i][j][r];
        size_t o = (size_t)b * sC + (size_t)row * ldc + col;
        if constexpr (EPI == EPI_F32) {
          ((float*)Cv)[o] = v;
        } else {  // EPI_PAIR: store hi/lo bf16 decomposition
          unsigned short h = f2bf(v);
          ((unsigned short*)Cv)[o] = h;
          ((unsigned short*)Cv2)[o] = f2bf(v - bf2f(h));
        }
      }
    }
  }
}

// ---------------- launcher ----------------
extern "C" void kernel_launch(void* const* d_in, const int* in_sizes, int n_in,
                              void* d_out, int out_size, void* d_ws, size_t ws_size,
                              hipStream_t stream) {
  (void)in_sizes; (void)n_in; (void)out_size; (void)ws_size;
  const float* q     = (const float*)d_in[0];
  const float* x     = (const float*)d_in[1];
  const float* Wq    = (const float*)d_in[2];
  const float* Wk    = (const float*)d_in[3];
  const float* Wv    = (const float*)d_in[4];
  const float* bv    = (const float*)d_in[5];
  const float* Wt    = (const float*)d_in[6];
  const float* bt    = (const float*)d_in[7];
  const float* gamma = (const float*)d_in[8];
  const float* beta  = (const float*)d_in[9];
  const float* rmean = (const float*)d_in[10];
  const float* rvar  = (const float*)d_in[11];
  float* out = (float*)d_out;

  // ---------- static workspace plan with lifetime-based aliasing ----------
  // Region A (80 MiB): qT/xT/xq/xk hi+lo pairs — all dead after the energy GEMM.
  //   pT (64 MiB) aliases region A from softmaxT onward.
  // energy (128 MiB): dead after softmaxT; t_ (8 MiB) and tT (8 MiB) alias it.
  // Peak ≈ 220 MiB (fits the ws budget that round-0's 242 MB layout exceeded... stayed under).
  const size_t SZ_qT = (size_t)KB_ * KN_ * KC_ * 2;   // 16 MiB
  const size_t SZ_xT = (size_t)KB_ * KN_ * KC2_ * 2;  //  8 MiB
  char* ws = (char*)d_ws;
  size_t off = 0;
  auto alloc = [&](size_t bytes) {
    char* p = ws + off;
    off += (bytes + 255) & ~(size_t)255;
    return p;
  };
  // --- region A ---
  unsigned short* qThi = (unsigned short*)alloc(SZ_qT);
  unsigned short* qTlo = (unsigned short*)alloc(SZ_qT);
  unsigned short* xThi = (unsigned short*)alloc(SZ_xT);
  unsigned short* xTlo = (unsigned short*)alloc(SZ_xT);
  unsigned short* xqhi = (unsigned short*)alloc(SZ_xT);
  unsigned short* xqlo = (unsigned short*)alloc(SZ_xT);
  unsigned short* xkhi = (unsigned short*)alloc(SZ_xT);
  unsigned short* xklo = (unsigned short*)alloc(SZ_xT);
  unsigned short* pT   = qThi;  // alias: live only after region A is dead
  // --- persistent small/medium buffers ---
  unsigned short* x_v  = (unsigned short*)alloc((size_t)KB_ * KC2_ * KN_ * 2);
  unsigned short* Wqhi = (unsigned short*)alloc((size_t)KC2_ * KC_ * 2);
  unsigned short* Wqlo = (unsigned short*)alloc((size_t)KC2_ * KC_ * 2);
  unsigned short* Wkhi = (unsigned short*)alloc((size_t)KC2_ * KC2_ * 2);
  unsigned short* Wklo = (unsigned short*)alloc((size_t)KC2_ * KC2_ * 2);
  unsigned short* Wvb  = (unsigned short*)alloc((size_t)KC2_ * KC_ * 2);
  unsigned short* Wtb  = (unsigned short*)alloc((size_t)KC2_ * KC2_ * 2);
  float* rm      = (float*)alloc((size_t)KB_ * KN_ * 4);
  float* rsv     = (float*)alloc((size_t)KB_ * KN_ * 4);
  float* colsum  = (float*)alloc((size_t)KB_ * KN_ * 4);
  float* colpart = (float*)alloc((size_t)KB_ * 32 * KN_ * 4);
  // --- energy region (aliased by t_/tT after softmaxT) ---
  float* energy = (float*)alloc((size_t)KB_ * KN_ * KN_ * 4);
  unsigned short* t_ = (unsigned short*)energy;
  unsigned short* tT = (unsigned short*)((char*)energy + SZ_xT);

  dim3 blk(256);

  // weights -> bf16 (split pairs on the Q/K path)
  cvt_pair_kernel<<<dim3(KC2_ * KC_ / 1024), blk, 0, stream>>>(Wq, Wqhi, Wqlo, KC2_ * KC_);
  cvt_pair_kernel<<<dim3(KC2_ * KC2_ / 1024), blk, 0, stream>>>(Wk, Wkhi, Wklo, KC2_ * KC2_);
  cvt_kernel<<<dim3(KC2_ * KC_ / 1024), blk, 0, stream>>>(Wv, Wvb, KC2_ * KC_);
  cvt_kernel<<<dim3(KC2_ * KC2_ / 1024), blk, 0, stream>>>(Wt, Wtb, KC2_ * KC2_);

  // q^T, x^T fp32 -> hi/lo bf16 pairs, transposed so K is contiguous
  transpose_pair_kernel<<<dim3(KN_ / 64, KC_ / 64, KB_), blk, 0, stream>>>(
      q, (long)KC_ * KN_, qThi, qTlo, (long)KN_ * KC_, KC_, KN_);
  transpose_pair_kernel<<<dim3(KN_ / 64, KC2_ / 64, KB_), blk, 0, stream>>>(
      x, (long)KC2_ * KN_, xThi, xTlo, (long)KN_ * KC2_, KC2_, KN_);

  // x_q[b][n][o] = qT[n][:] . Wq[o][:]   (fp32-grade, stored as hi/lo pair)
  gemm_split_kernel<EPI_PAIR><<<dim3(KC2_ / 128, KN_ / 128, KB_), blk, 0, stream>>>(
      qThi, qTlo, (long)KN_ * KC_, KC_, Wqhi, Wqlo, 0, KC_,
      xqhi, xqlo, (long)KN_ * KC2_, KC2_, KC_);
  // x_kT[b][m][o] = xT[m][:] . Wk[o][:]  (fp32-grade, hi/lo pair)
  gemm_split_kernel<EPI_PAIR><<<dim3(KC2_ / 128, KN_ / 128, KB_), blk, 0, stream>>>(
      xThi, xTlo, (long)KN_ * KC2_, KC2_, Wkhi, Wklo, 0, KC2_,
      xkhi, xklo, (long)KN_ * KC2_, KC2_, KC2_);
  // x_v[b][o][n] = Wv[o][:] . qT[n][:] + bv[o]   (single bf16 is enough here)
  EpiParams e3{}; e3.bias = bv;
  gemm_kernel<EPI_BIAS><<<dim3(KN_ / 128, KC2_ / 128, KB_), blk, 0, stream>>>(
      Wvb, 0, KC_, qThi, (long)KN_ * KC_, KC_, x_v, (long)KC2_ * KN_, KN_, KC_, e3);
  // energy[b][n][m] = x_q[n][:] . x_kT[m][:]  (fp32-grade)
  gemm_split_kernel<EPI_F32><<<dim3(KN_ / 128, KN_ / 128, KB_), blk, 0, stream>>>(
      xqhi, xqlo, (long)KN_ * KC2_, KC2_, xkhi, xklo, (long)KN_ * KC2_, KC2_,
      energy, nullptr, (long)KN_ * KN_, KN_, KC2_);

  // softmax stats, transposed probabilities (pT aliases region A — xq/xk now dead)
  rowstats_kernel<<<dim3(KN_ / 4, KB_), blk, 0, stream>>>(energy, rm, rsv);
  softmaxT_kernel<<<dim3(KN_ / 64, KN_ / 64, KB_), blk, 0, stream>>>(energy, rm, rsv, pT, colpart);
  colreduce_kernel<<<dim3(KN_ / 256, KB_), blk, 0, stream>>>(colpart, colsum);

  // t[b][c][m] = x[b][c][m] - (x_v[c][:] . pT[m][:]) / (1e-9 + colsum[m])
  // (t_ aliases the energy region — energy is dead now)
  EpiParams e5{}; e5.xf = x; e5.xf_stride = (long)KC2_ * KN_;
  e5.colsum = colsum; e5.cs_stride = KN_;
  gemm_kernel<EPI_XR><<<dim3(KN_ / 128, KC2_ / 128, KB_), blk, 0, stream>>>(
      x_v, (long)KC2_ * KN_, KN_, pT, (long)KN_ * KN_, KN_,
      t_, (long)KC2_ * KN_, KN_, KN_, e5);

  // t^T for the last GEMM
  transpose_bf_kernel<<<dim3(KN_ / 64, KC2_ / 64, KB_), blk, 0, stream>>>(
      t_, (long)KC2_ * KN_, tT, (long)KN_ * KC2_, KC2_, KN_);

  // out[b][o][n] = relu(BN(Wt[o][:] . tT[n][:] + bt[o])) + x[b][o][n]
  EpiParams e6{}; e6.bias = bt; e6.xf = x; e6.xf_stride = (long)KC2_ * KN_;
  e6.gamma = gamma; e6.beta = beta; e6.mean = rmean; e6.var = rvar;
  gemm_kernel<EPI_FINAL><<<dim3(KN_ / 128, KC2_ / 128, KB_), blk, 0, stream>>>(
      Wtb, 0, KC2_, tT, (long)KN_ * KC2_, KC2_,
      out, (long)KC2_ * KN_, KN_, KC2_, e6);
}

// Round 4
// 268.908 us; speedup vs baseline: 1.1315x; 1.1315x over previous
//
#include <hip/hip_runtime.h>
#include <cstdint>
#include <cstddef>

// Problem constants (B, C, N fixed by the reference)
#define KB_  8
#define KC_  512
#define KC2_ 256
#define KN_  2048

typedef __attribute__((ext_vector_type(8))) __bf16 bf16x8;
typedef __attribute__((ext_vector_type(8))) unsigned short u16x8;
typedef __attribute__((ext_vector_type(4))) float f32x4;

__device__ __forceinline__ unsigned short f2bf(float f) {
  union { float f; unsigned u; } x; x.f = f;
  unsigned r = x.u + 0x7fffu + ((x.u >> 16) & 1u);  // RNE (finite values only)
  return (unsigned short)(r >> 16);
}
__device__ __forceinline__ float bf2f(unsigned short h) {
  union { unsigned u; float f; } x; x.u = ((unsigned)h) << 16;
  return x.f;
}

// async global->LDS, 16B per lane; LDS dest = wave-uniform base + lane*16
#define GLD16(g, l) __builtin_amdgcn_global_load_lds( \
    (__attribute__((address_space(1))) void*)(g),     \
    (__attribute__((address_space(3))) void*)(l), 16, 0, 0)

// bijective XCD-aware block swizzle (nb % 8 == 0 for all our grids)
__device__ __forceinline__ void xcd_swizzle(int& bx, int& by, int& bz) {
  const int gx = gridDim.x, gy = gridDim.y;
  const int nb = gx * gy * (int)gridDim.z;
  int f = ((int)blockIdx.z * gy + (int)blockIdx.y) * gx + (int)blockIdx.x;
  if ((nb & 7) == 0) f = (f & 7) * (nb >> 3) + (f >> 3);
  const int gxy = gx * gy;
  bz = f / gxy; int rem = f - bz * gxy;
  by = rem / gx; bx = rem - by * gx;
}

// ---------------- weight fp32 -> bf16 convert (single) ----------------
__global__ __launch_bounds__(256) void cvt_kernel(const float* __restrict__ in,
                                                  unsigned short* __restrict__ out, int n) {
  int i = (blockIdx.x * 256 + threadIdx.x) * 4;
  if (i >= n) return;
  float4 f = *(const float4*)(in + i);
  ushort4 u = { f2bf(f.x), f2bf(f.y), f2bf(f.z), f2bf(f.w) };
  *(ushort4*)(out + i) = u;
}

// ---------------- weight fp32 -> bf16 hi/lo pair ----------------
__global__ __launch_bounds__(256) void cvt_pair_kernel(const float* __restrict__ in,
                                                       unsigned short* __restrict__ hi,
                                                       unsigned short* __restrict__ lo, int n) {
  int i = (blockIdx.x * 256 + threadIdx.x) * 4;
  if (i >= n) return;
  float4 f = *(const float4*)(in + i);
  ushort4 h = { f2bf(f.x), f2bf(f.y), f2bf(f.z), f2bf(f.w) };
  ushort4 l = { f2bf(f.x - bf2f(h.x)), f2bf(f.y - bf2f(h.y)),
                f2bf(f.z - bf2f(h.z)), f2bf(f.w - bf2f(h.w)) };
  *(ushort4*)(hi + i) = h;
  *(ushort4*)(lo + i) = l;
}

// ---------------- tiled transpose: fp32 [R][Cc] -> bf16 hi/lo [Cc][R] ----------------
__global__ __launch_bounds__(256) void transpose_pair_kernel(const float* __restrict__ in,
                                                             long sIn,
                                                             unsigned short* __restrict__ hi,
                                                             unsigned short* __restrict__ lo,
                                                             long sOut, int R, int Cc) {
  int b = blockIdx.z;
  const float* I = in + (size_t)b * sIn;
  __shared__ float tile[64][65];
  int t = threadIdx.x;
  int r0 = blockIdx.y * 64, c0 = blockIdx.x * 64;
#pragma unroll
  for (int k = 0; k < 4; k++) {
    int vi = k * 256 + t, rr = vi >> 4, cv = vi & 15;
    float4 f = *(const float4*)&I[(size_t)(r0 + rr) * Cc + c0 + cv * 4];
    tile[rr][cv * 4 + 0] = f.x; tile[rr][cv * 4 + 1] = f.y;
    tile[rr][cv * 4 + 2] = f.z; tile[rr][cv * 4 + 3] = f.w;
  }
  __syncthreads();
#pragma unroll
  for (int k = 0; k < 4; k++) {
    int vi = k * 256 + t, cc = vi >> 4, rv = vi & 15;
    float f0 = tile[rv * 4 + 0][cc], f1 = tile[rv * 4 + 1][cc];
    float f2 = tile[rv * 4 + 2][cc], f3 = tile[rv * 4 + 3][cc];
    ushort4 h = { f2bf(f0), f2bf(f1), f2bf(f2), f2bf(f3) };
    ushort4 l = { f2bf(f0 - bf2f(h.x)), f2bf(f1 - bf2f(h.y)),
                  f2bf(f2 - bf2f(h.z)), f2bf(f3 - bf2f(h.w)) };
    size_t o = (size_t)b * sOut + (size_t)(c0 + cc) * R + r0 + rv * 4;
    *(ushort4*)&hi[o] = h;
    *(ushort4*)&lo[o] = l;
  }
}

// ---------------- tiled transpose: bf16 [R][Cc] -> bf16 [Cc][R] ----------------
__global__ __launch_bounds__(256) void transpose_bf_kernel(const unsigned short* __restrict__ in,
                                                           long sIn,
                                                           unsigned short* __restrict__ out,
                                                           long sOut, int R, int Cc) {
  int b = blockIdx.z;
  const unsigned short* I = in + (size_t)b * sIn;
  __shared__ unsigned short tile[64][72];
  int t = threadIdx.x;
  int r0 = blockIdx.y * 64, c0 = blockIdx.x * 64;
#pragma unroll
  for (int k = 0; k < 4; k++) {
    int vi = k * 256 + t, rr = vi >> 4, cv = vi & 15;
    ushort4 u = *(const ushort4*)&I[(size_t)(r0 + rr) * Cc + c0 + cv * 4];
    tile[rr][cv * 4 + 0] = u.x; tile[rr][cv * 4 + 1] = u.y;
    tile[rr][cv * 4 + 2] = u.z; tile[rr][cv * 4 + 3] = u.w;
  }
  __syncthreads();
#pragma unroll
  for (int k = 0; k < 4; k++) {
    int vi = k * 256 + t, cc = vi >> 4, rv = vi & 15;
    ushort4 u = { tile[rv * 4 + 0][cc], tile[rv * 4 + 1][cc],
                  tile[rv * 4 + 2][cc], tile[rv * 4 + 3][cc] };
    *(ushort4*)&out[(size_t)b * sOut + (size_t)(c0 + cc) * R + r0 + rv * 4] = u;
  }
}

// ---------------- rsv[b][n] = 1 / sum_k rowpart[b][n][k] ----------------
__global__ __launch_bounds__(256) void rowreduce_kernel(const float* __restrict__ rowpart,
                                                        float* __restrict__ rsv) {
  int idx = blockIdx.x * 256 + threadIdx.x;  // 8*2048 rows
  const float* p = rowpart + (size_t)idx * 32;
  float s = 0.f;
#pragma unroll
  for (int k = 0; k < 32; k++) s += p[k];
  rsv[idx] = 1.0f / s;
}

// ---------------- denom[b][m] = sum_n uT[b][m][n] * rsv[b][n] ----------------
__global__ __launch_bounds__(256) void denom_kernel(const unsigned short* __restrict__ uT,
                                                    const float* __restrict__ rsv,
                                                    float* __restrict__ denom) {
  int b = blockIdx.y;
  int m = blockIdx.x * 4 + (threadIdx.x >> 6);
  int lane = threadIdx.x & 63;
  const unsigned short* U = uT + ((size_t)b * KN_ + m) * KN_;
  const float* R = rsv + (size_t)b * KN_;
  float s = 0.f;
#pragma unroll
  for (int c = 0; c < 4; c++) {
    int n = c * 512 + lane * 8;
    u16x8 u = *(const u16x8*)&U[n];
    float4 r0 = *(const float4*)&R[n];
    float4 r1 = *(const float4*)&R[n + 4];
    s += bf2f(u[0]) * r0.x + bf2f(u[1]) * r0.y + bf2f(u[2]) * r0.z + bf2f(u[3]) * r0.w;
    s += bf2f(u[4]) * r1.x + bf2f(u[5]) * r1.y + bf2f(u[6]) * r1.z + bf2f(u[7]) * r1.w;
  }
#pragma unroll
  for (int o = 32; o > 0; o >>= 1) s += __shfl_xor(s, o, 64);
  if (lane == 0) denom[(size_t)b * KN_ + m] = s;
}

// ---------------- energy kernel: fused split-GEMM + exp + transpose + row-partials ------
// E[n][m] = xq[n][:] . xk[m][:] (fp32-grade via hi/lo); u = exp(E-40);
// writes uT[b][m][n] (bf16) and rowpart[b][n][32] (partial row sums of u, fp32).
__global__ __launch_bounds__(256) void energy_kernel(
    const unsigned short* __restrict__ Ahi, const unsigned short* __restrict__ Alo,
    const unsigned short* __restrict__ Bhi, const unsigned short* __restrict__ Blo,
    unsigned short* __restrict__ uT, float* __restrict__ rowpart) {
  int bx, by, b;
  xcd_swizzle(bx, by, b);  // grid (16,16,8): each XCD owns one batch
  Ahi += (size_t)b * KN_ * KC2_; Alo += (size_t)b * KN_ * KC2_;
  Bhi += (size_t)b * KN_ * KC2_; Blo += (size_t)b * KN_ * KC2_;
  const int m0 = by * 128;  // rows  = n (query idx)
  const int n0 = bx * 128;  // cols  = m (key idx)
  __shared__ __align__(16) char smem[32768];  // 4x8KB staging; reused for transpose
  const int t = threadIdx.x, lane = t & 63, w = t >> 6;
  const int wr = w >> 1, wc = w & 1;
  const int srow = t >> 2, scol = (t & 3) * 8;
  const int lr = lane & 15, lk = (lane >> 4) * 8;

  f32x4 acc[4][4];
  const f32x4 z = {0.f, 0.f, 0.f, 0.f};
#pragma unroll
  for (int i = 0; i < 4; i++)
#pragma unroll
    for (int j = 0; j < 4; j++) acc[i][j] = z;

  for (int kt = 0; kt < KC2_; kt += 32) {
    const size_t ga = (size_t)(m0 + srow) * KC2_ + kt + scol;
    const size_t gb = (size_t)(n0 + srow) * KC2_ + kt + scol;
    GLD16(Ahi + ga, smem + 0 + w * 1024);
    GLD16(Ahi + ga + (size_t)64 * KC2_, smem + 4096 + w * 1024);
    GLD16(Alo + ga, smem + 8192 + w * 1024);
    GLD16(Alo + ga + (size_t)64 * KC2_, smem + 12288 + w * 1024);
    GLD16(Bhi + gb, smem + 16384 + w * 1024);
    GLD16(Bhi + gb + (size_t)64 * KC2_, smem + 20480 + w * 1024);
    GLD16(Blo + gb, smem + 24576 + w * 1024);
    GLD16(Blo + gb + (size_t)64 * KC2_, smem + 28672 + w * 1024);
    __syncthreads();
    bf16x8 ah[4], al[4], bh[4], bl[4];
#pragma unroll
    for (int i = 0; i < 4; i++) {
      ah[i] = *(const bf16x8*)(smem + 0    + (wr * 64 + i * 16 + lr) * 64 + lk * 2);
      al[i] = *(const bf16x8*)(smem + 8192 + (wr * 64 + i * 16 + lr) * 64 + lk * 2);
    }
#pragma unroll
    for (int j = 0; j < 4; j++) {
      bh[j] = *(const bf16x8*)(smem + 16384 + (wc * 64 + j * 16 + lr) * 64 + lk * 2);
      bl[j] = *(const bf16x8*)(smem + 24576 + (wc * 64 + j * 16 + lr) * 64 + lk * 2);
    }
#pragma unroll
    for (int i = 0; i < 4; i++)
#pragma unroll
      for (int j = 0; j < 4; j++) {
        acc[i][j] = __builtin_amdgcn_mfma_f32_16x16x32_bf16(al[i], bh[j], acc[i][j], 0, 0, 0);
        acc[i][j] = __builtin_amdgcn_mfma_f32_16x16x32_bf16(ah[i], bl[j], acc[i][j], 0, 0, 0);
        acc[i][j] = __builtin_amdgcn_mfma_f32_16x16x32_bf16(ah[i], bh[j], acc[i][j], 0, 0, 0);
      }
    __syncthreads();
  }

  // ---- epilogue: u = exp(E - 40) ----
#pragma unroll
  for (int i = 0; i < 4; i++)
#pragma unroll
    for (int j = 0; j < 4; j++)
#pragma unroll
      for (int r = 0; r < 4; r++) acc[i][j][r] = __expf(acc[i][j][r] - 40.f);

  // ---- partial row sums: each wave reduces its 64 cols via 16-lane shuffles ----
#pragma unroll
  for (int i = 0; i < 4; i++) {
#pragma unroll
    for (int r = 0; r < 4; r++) {
      float s = acc[i][0][r] + acc[i][1][r] + acc[i][2][r] + acc[i][3][r];
      s += __shfl_xor(s, 1, 64); s += __shfl_xor(s, 2, 64);
      s += __shfl_xor(s, 4, 64); s += __shfl_xor(s, 8, 64);
      if ((lane & 15) == 0) {
        int row = m0 + wr * 64 + i * 16 + ((lane >> 4) << 2) + r;
        rowpart[((size_t)b * KN_ + row) * 32 + bx * 2 + wc] = s;
      }
    }
  }

  // ---- transpose to uT via LDS (reuse staging smem; XOR-swizzled banks) ----
  // write: lds byte (col*256 + row*2) ^ ((col&15)<<4), packed 2 rows per b32
#pragma unroll
  for (int i = 0; i < 4; i++) {
#pragma unroll
    for (int j = 0; j < 4; j++) {
#pragma unroll
      for (int r2 = 0; r2 < 4; r2 += 2) {
        int row = wr * 64 + i * 16 + ((lane >> 4) << 2) + r2;
        int col = wc * 64 + j * 16 + lr;
        unsigned pk = (unsigned)f2bf(acc[i][j][r2]) |
                      ((unsigned)f2bf(acc[i][j][r2 + 1]) << 16);
        int a = ((col << 8) + (row << 1)) ^ ((col & 15) << 4);
        *(unsigned*)(smem + a) = pk;
      }
    }
  }
  __syncthreads();
  // read linear per uT row, write coalesced 128B per thread
  {
    int col = t >> 1, h = t & 1;
    size_t gbase = ((size_t)b * KN_ + (n0 + col)) * KN_ + m0 + h * 64;
#pragma unroll
    for (int c = 0; c < 8; c++) {
      int a = ((col << 8) + (h << 7) + (c << 4)) ^ ((col & 15) << 4);
      *(bf16x8*)&uT[gbase + c * 8] = *(const bf16x8*)(smem + a);
    }
  }
}

// ---------------- epilogue variants ----------------
enum { EPI_VSCALE = 1, EPI_XR = 3, EPI_FINAL = 4, EPI_PAIR = 5 };

struct EpiParams {
  const float* bias;
  const float* xf;  long xf_stride;
  const float* colsum; long cs_stride;
  const float* scale; long scale_stride;
  const float* gamma; const float* beta; const float* mean; const float* var;
};

// ---------------- MFMA GEMM (single bf16): C[M][N] = A[M][K] * Bt[N][K]^T ----------------
template<int EPI>
__global__ __launch_bounds__(256) void gemm_kernel(
    const unsigned short* __restrict__ A, long sA, int lda,
    const unsigned short* __restrict__ Bt, long sB, int ldb,
    void* __restrict__ Cv, long sC, int ldc,
    int K, EpiParams ep) {
  int bx, by, b;
  xcd_swizzle(bx, by, b);
  A  += (size_t)b * sA;
  Bt += (size_t)b * sB;
  const int m0 = by * 128, n0 = bx * 128;
  __shared__ unsigned short As[128][32];
  __shared__ unsigned short Bs[128][32];
  const int t = threadIdx.x, lane = t & 63, w = t >> 6;
  const int wr = w >> 1, wc = w & 1;
  const int srow = t >> 2, scol = (t & 3) * 8;
  const int lr = lane & 15, lk = (lane >> 4) * 8;

  f32x4 acc[4][4];
  const f32x4 z = {0.f, 0.f, 0.f, 0.f};
#pragma unroll
  for (int i = 0; i < 4; i++)
#pragma unroll
    for (int j = 0; j < 4; j++) acc[i][j] = z;

  for (int kt = 0; kt < K; kt += 32) {
    const unsigned short* gA = A + (size_t)(m0 + srow) * lda + kt + scol;
    const unsigned short* gB = Bt + (size_t)(n0 + srow) * ldb + kt + scol;
    char* lA = (char*)(&As[0][0]);
    char* lB = (char*)(&Bs[0][0]);
    GLD16(gA, lA + w * 1024);
    GLD16(gA + (size_t)64 * lda, lA + 4096 + w * 1024);
    GLD16(gB, lB + w * 1024);
    GLD16(gB + (size_t)64 * ldb, lB + 4096 + w * 1024);
    __syncthreads();
    bf16x8 af[4], bfv[4];
#pragma unroll
    for (int i = 0; i < 4; i++) af[i] = *(const bf16x8*)&As[wr * 64 + i * 16 + lr][lk];
#pragma unroll
    for (int j = 0; j < 4; j++) bfv[j] = *(const bf16x8*)&Bs[wc * 64 + j * 16 + lr][lk];
#pragma unroll
    for (int i = 0; i < 4; i++)
#pragma unroll
      for (int j = 0; j < 4; j++)
        acc[i][j] = __builtin_amdgcn_mfma_f32_16x16x32_bf16(af[i], bfv[j], acc[i][j], 0, 0, 0);
    __syncthreads();
  }

#pragma unroll
  for (int i = 0; i < 4; i++) {
#pragma unroll
    for (int r = 0; r < 4; r++) {
      const int row = m0 + wr * 64 + i * 16 + ((lane >> 4) << 2) + r;
      float pbias = 0.f, pinv = 1.f, padd = 0.f;
      if constexpr (EPI == EPI_VSCALE) pbias = ep.bias[row];
      if constexpr (EPI == EPI_FINAL) {
        pbias = ep.bias[row];
        float iv = ep.gamma[row] * rsqrtf(ep.var[row] + 1e-5f);
        pinv = iv;
        padd = ep.beta[row] - ep.mean[row] * iv;
      }
#pragma unroll
      for (int j = 0; j < 4; j++) {
        const int col = n0 + wc * 64 + j * 16 + lr;
        float v = acc[i][j][r];
        if constexpr (EPI == EPI_VSCALE) {
          float sc = ep.scale[(size_t)b * ep.scale_stride + col];
          ((unsigned short*)Cv)[(size_t)b * sC + (size_t)row * ldc + col] =
              f2bf((v + pbias) * sc);
        } else if constexpr (EPI == EPI_XR) {
          float cs = ep.colsum[(size_t)b * ep.cs_stride + col];
          float xval = ep.xf[(size_t)b * ep.xf_stride + (size_t)row * ldc + col];
          ((unsigned short*)Cv)[(size_t)b * sC + (size_t)row * ldc + col] =
              f2bf(xval - v / (1e-9f + cs));
        } else {  // EPI_FINAL
          float h = (v + pbias) * pinv + padd;
          h = fmaxf(h, 0.f);
          float xval = ep.xf[(size_t)b * ep.xf_stride + (size_t)row * ldc + col];
          ((float*)Cv)[(size_t)b * sC + (size_t)row * ldc + col] = h + xval;
        }
      }
    }
  }
}

// ---------------- MFMA GEMM, split hi/lo operands -> bf16 hi/lo pair out ----------------
template<int EPI>
__global__ __launch_bounds__(256) void gemm_split_kernel(
    const unsigned short* __restrict__ Ahi, const unsigned short* __restrict__ Alo,
    long sA, int lda,
    const unsigned short* __restrict__ Bhi, const unsigned short* __restrict__ Blo,
    long sB, int ldb,
    void* __restrict__ Cv, void* __restrict__ Cv2, long sC, int ldc, int K) {
  int bx, by, b;
  xcd_swizzle(bx, by, b);
  Ahi += (size_t)b * sA; Alo += (size_t)b * sA;
  Bhi += (size_t)b * sB; Blo += (size_t)b * sB;
  const int m0 = by * 128, n0 = bx * 128;
  __shared__ unsigned short Ah[128][32], Al[128][32], Bh[128][32], Bl[128][32];
  const int t = threadIdx.x, lane = t & 63, w = t >> 6;
  const int wr = w >> 1, wc = w & 1;
  const int srow = t >> 2, scol = (t & 3) * 8;
  const int lr = lane & 15, lk = (lane >> 4) * 8;

  f32x4 acc[4][4];
  const f32x4 z = {0.f, 0.f, 0.f, 0.f};
#pragma unroll
  for (int i = 0; i < 4; i++)
#pragma unroll
    for (int j = 0; j < 4; j++) acc[i][j] = z;

  for (int kt = 0; kt < K; kt += 32) {
    const size_t ga = (size_t)(m0 + srow) * lda + kt + scol;
    const size_t gb = (size_t)(n0 + srow) * ldb + kt + scol;
    GLD16(Ahi + ga, (char*)(&Ah[0][0]) + w * 1024);
    GLD16(Ahi + ga + (size_t)64 * lda, (char*)(&Ah[0][0]) + 4096 + w * 1024);
    GLD16(Alo + ga, (char*)(&Al[0][0]) + w * 1024);
    GLD16(Alo + ga + (size_t)64 * lda, (char*)(&Al[0][0]) + 4096 + w * 1024);
    GLD16(Bhi + gb, (char*)(&Bh[0][0]) + w * 1024);
    GLD16(Bhi + gb + (size_t)64 * ldb, (char*)(&Bh[0][0]) + 4096 + w * 1024);
    GLD16(Blo + gb, (char*)(&Bl[0][0]) + w * 1024);
    GLD16(Blo + gb + (size_t)64 * ldb, (char*)(&Bl[0][0]) + 4096 + w * 1024);
    __syncthreads();
    bf16x8 ah[4], al[4], bh[4], bl[4];
#pragma unroll
    for (int i = 0; i < 4; i++) {
      ah[i] = *(const bf16x8*)&Ah[wr * 64 + i * 16 + lr][lk];
      al[i] = *(const bf16x8*)&Al[wr * 64 + i * 16 + lr][lk];
    }
#pragma unroll
    for (int j = 0; j < 4; j++) {
      bh[j] = *(const bf16x8*)&Bh[wc * 64 + j * 16 + lr][lk];
      bl[j] = *(const bf16x8*)&Bl[wc * 64 + j * 16 + lr][lk];
    }
#pragma unroll
    for (int i = 0; i < 4; i++)
#pragma unroll
      for (int j = 0; j < 4; j++) {
        acc[i][j] = __builtin_amdgcn_mfma_f32_16x16x32_bf16(al[i], bh[j], acc[i][j], 0, 0, 0);
        acc[i][j] = __builtin_amdgcn_mfma_f32_16x16x32_bf16(ah[i], bl[j], acc[i][j], 0, 0, 0);
        acc[i][j] = __builtin_amdgcn_mfma_f32_16x16x32_bf16(ah[i], bh[j], acc[i][j], 0, 0, 0);
      }
    __syncthreads();
  }

#pragma unroll
  for (int i = 0; i < 4; i++) {
#pragma unroll
    for (int r = 0; r < 4; r++) {
      const int row = m0 + wr * 64 + i * 16 + ((lane >> 4) << 2) + r;
#pragma unroll
      for (int j = 0; j < 4; j++) {
        const int col = n0 + wc * 64 + j * 16 + lr;
        float v = acc[i][j][r];
        size_t o = (size_t)b * sC + (size_t)row * ldc + col;
        unsigned short h = f2bf(v);
        ((unsigned short*)Cv)[o] = h;
        ((unsigned short*)Cv2)[o] = f2bf(v - bf2f(h));
      }
    }
  }
}

// ---------------- launcher ----------------
extern "C" void kernel_launch(void* const* d_in, const int* in_sizes, int n_in,
                              void* d_out, int out_size, void* d_ws, size_t ws_size,
                              hipStream_t stream) {
  (void)in_sizes; (void)n_in; (void)out_size; (void)ws_size;
  const float* q     = (const float*)d_in[0];
  const float* x     = (const float*)d_in[1];
  const float* Wq    = (const float*)d_in[2];
  const float* Wk    = (const float*)d_in[3];
  const float* Wv    = (const float*)d_in[4];
  const float* bv    = (const float*)d_in[5];
  const float* Wt    = (const float*)d_in[6];
  const float* bt    = (const float*)d_in[7];
  const float* gamma = (const float*)d_in[8];
  const float* beta  = (const float*)d_in[9];
  const float* rmean = (const float*)d_in[10];
  const float* rvar  = (const float*)d_in[11];
  float* out = (float*)d_out;

  // workspace (~171 MiB, no aliasing needed)
  const size_t SZ_qT = (size_t)KB_ * KN_ * KC_ * 2;   // 16 MiB
  const size_t SZ_xT = (size_t)KB_ * KN_ * KC2_ * 2;  //  8 MiB
  char* ws = (char*)d_ws;
  size_t off = 0;
  auto alloc = [&](size_t bytes) {
    char* p = ws + off;
    off += (bytes + 255) & ~(size_t)255;
    return p;
  };
  unsigned short* qThi = (unsigned short*)alloc(SZ_qT);
  unsigned short* qTlo = (unsigned short*)alloc(SZ_qT);
  unsigned short* xThi = (unsigned short*)alloc(SZ_xT);
  unsigned short* xTlo = (unsigned short*)alloc(SZ_xT);
  unsigned short* xqhi = (unsigned short*)alloc(SZ_xT);
  unsigned short* xqlo = (unsigned short*)alloc(SZ_xT);
  unsigned short* xkhi = (unsigned short*)alloc(SZ_xT);
  unsigned short* xklo = (unsigned short*)alloc(SZ_xT);
  unsigned short* x_v  = (unsigned short*)alloc((size_t)KB_ * KC2_ * KN_ * 2);
  unsigned short* t_   = (unsigned short*)alloc(SZ_xT);
  unsigned short* tT   = (unsigned short*)alloc(SZ_xT);
  unsigned short* Wqhi = (unsigned short*)alloc((size_t)KC2_ * KC_ * 2);
  unsigned short* Wqlo = (unsigned short*)alloc((size_t)KC2_ * KC_ * 2);
  unsigned short* Wkhi = (unsigned short*)alloc((size_t)KC2_ * KC2_ * 2);
  unsigned short* Wklo = (unsigned short*)alloc((size_t)KC2_ * KC2_ * 2);
  unsigned short* Wvb  = (unsigned short*)alloc((size_t)KC2_ * KC_ * 2);
  unsigned short* Wtb  = (unsigned short*)alloc((size_t)KC2_ * KC2_ * 2);
  float* rsv     = (float*)alloc((size_t)KB_ * KN_ * 4);
  float* denom   = (float*)alloc((size_t)KB_ * KN_ * 4);
  float* rowpart = (float*)alloc((size_t)KB_ * KN_ * 32 * 4);
  unsigned short* uT = (unsigned short*)alloc((size_t)KB_ * KN_ * KN_ * 2);  // 64 MiB

  dim3 blk(256);

  // weights -> bf16
  cvt_pair_kernel<<<dim3(KC2_ * KC_ / 1024), blk, 0, stream>>>(Wq, Wqhi, Wqlo, KC2_ * KC_);
  cvt_pair_kernel<<<dim3(KC2_ * KC2_ / 1024), blk, 0, stream>>>(Wk, Wkhi, Wklo, KC2_ * KC2_);
  cvt_kernel<<<dim3(KC2_ * KC_ / 1024), blk, 0, stream>>>(Wv, Wvb, KC2_ * KC_);
  cvt_kernel<<<dim3(KC2_ * KC2_ / 1024), blk, 0, stream>>>(Wt, Wtb, KC2_ * KC2_);

  // q^T, x^T fp32 -> hi/lo bf16 pairs (K contiguous)
  transpose_pair_kernel<<<dim3(KN_ / 64, KC_ / 64, KB_), blk, 0, stream>>>(
      q, (long)KC_ * KN_, qThi, qTlo, (long)KN_ * KC_, KC_, KN_);
  transpose_pair_kernel<<<dim3(KN_ / 64, KC2_ / 64, KB_), blk, 0, stream>>>(
      x, (long)KC2_ * KN_, xThi, xTlo, (long)KN_ * KC2_, KC2_, KN_);

  // x_q / x_kT projections (fp32-grade, hi/lo pairs out)
  gemm_split_kernel<EPI_PAIR><<<dim3(KC2_ / 128, KN_ / 128, KB_), blk, 0, stream>>>(
      qThi, qTlo, (long)KN_ * KC_, KC_, Wqhi, Wqlo, 0, KC_,
      xqhi, xqlo, (long)KN_ * KC2_, KC2_, KC_);
  gemm_split_kernel<EPI_PAIR><<<dim3(KC2_ / 128, KN_ / 128, KB_), blk, 0, stream>>>(
      xThi, xTlo, (long)KN_ * KC2_, KC2_, Wkhi, Wklo, 0, KC2_,
      xkhi, xklo, (long)KN_ * KC2_, KC2_, KC2_);

  // energy + exp + transpose + row partials (fused)
  energy_kernel<<<dim3(KN_ / 128, KN_ / 128, KB_), blk, 0, stream>>>(
      xqhi, xqlo, xkhi, xklo, uT, rowpart);
  rowreduce_kernel<<<dim3(KB_ * KN_ / 256), blk, 0, stream>>>(rowpart, rsv);

  // x_v'[b][o][n] = (Wv[o][:].qT[n][:] + bv[o]) * rsv[b][n]
  EpiParams e3{}; e3.bias = bv; e3.scale = rsv; e3.scale_stride = KN_;
  gemm_kernel<EPI_VSCALE><<<dim3(KN_ / 128, KC2_ / 128, KB_), blk, 0, stream>>>(
      Wvb, 0, KC_, qThi, (long)KN_ * KC_, KC_, x_v, (long)KC2_ * KN_, KN_, KC_, e3);

  // denom[b][m] = sum_n uT[m][n] * rsv[n]
  denom_kernel<<<dim3(KN_ / 4, KB_), blk, 0, stream>>>(uT, rsv, denom);

  // t[b][c][m] = x[b][c][m] - (x_v'[c][:].uT[m][:]) / (1e-9 + denom[m])
  EpiParams e5{}; e5.xf = x; e5.xf_stride = (long)KC2_ * KN_;
  e5.colsum = denom; e5.cs_stride = KN_;
  gemm_kernel<EPI_XR><<<dim3(KN_ / 128, KC2_ / 128, KB_), blk, 0, stream>>>(
      x_v, (long)KC2_ * KN_, KN_, uT, (long)KN_ * KN_, KN_,
      t_, (long)KC2_ * KN_, KN_, KN_, e5);

  // t^T for the last GEMM
  transpose_bf_kernel<<<dim3(KN_ / 64, KC2_ / 64, KB_), blk, 0, stream>>>(
      t_, (long)KC2_ * KN_, tT, (long)KN_ * KC2_, KC2_, KN_);

  // out[b][o][n] = relu(BN(Wt[o][:].tT[n][:] + bt[o])) + x[b][o][n]
  EpiParams e6{}; e6.bias = bt; e6.xf = x; e6.xf_stride = (long)KC2_ * KN_;
  e6.gamma = gamma; e6.beta = beta; e6.mean = rmean; e6.var = rvar;
  gemm_kernel<EPI_FINAL><<<dim3(KN_ / 128, KC2_ / 128, KB_), blk, 0, stream>>>(
      Wtb, 0, KC2_, tT, (long)KN_ * KC2_, KC2_,
      out, (long)KC2_ * KN_, KN_, KC2_, e6);
}

// Round 5
// 258.200 us; speedup vs baseline: 1.1784x; 1.0415x over previous
//
#include <hip/hip_runtime.h>
#include <cstdint>
#include <cstddef>

// Problem constants (B, C, N fixed by the reference)
#define KB_  8
#define KC_  512
#define KC2_ 256
#define KN_  2048

typedef __attribute__((ext_vector_type(8))) __bf16 bf16x8;
typedef __attribute__((ext_vector_type(8))) unsigned short u16x8;
typedef __attribute__((ext_vector_type(4))) float f32x4;

__device__ __forceinline__ unsigned short f2bf(float f) {
  union { float f; unsigned u; } x; x.f = f;
  unsigned r = x.u + 0x7fffu + ((x.u >> 16) & 1u);  // RNE (finite values only)
  return (unsigned short)(r >> 16);
}
__device__ __forceinline__ float bf2f(unsigned short h) {
  union { unsigned u; float f; } x; x.u = ((unsigned)h) << 16;
  return x.f;
}

// async global->LDS, 16B per lane; LDS dest = wave-uniform base + lane*16
#define GLD16(g, l) __builtin_amdgcn_global_load_lds( \
    (__attribute__((address_space(1))) void*)(g),     \
    (__attribute__((address_space(3))) void*)(l), 16, 0, 0)

// bijective XCD-aware block swizzle (nb % 8 == 0 for all our grids)
__device__ __forceinline__ void xcd_swizzle(int& bx, int& by, int& bz) {
  const int gx = gridDim.x, gy = gridDim.y;
  const int nb = gx * gy * (int)gridDim.z;
  int f = ((int)blockIdx.z * gy + (int)blockIdx.y) * gx + (int)blockIdx.x;
  if ((nb & 7) == 0) f = (f & 7) * (nb >> 3) + (f >> 3);
  const int gxy = gx * gy;
  bz = f / gxy; int rem = f - bz * gxy;
  by = rem / gx; bx = rem - by * gx;
}

// ---------------- weight fp32 -> bf16 convert (single) ----------------
__global__ __launch_bounds__(256) void cvt_kernel(const float* __restrict__ in,
                                                  unsigned short* __restrict__ out, int n) {
  int i = (blockIdx.x * 256 + threadIdx.x) * 4;
  if (i >= n) return;
  float4 f = *(const float4*)(in + i);
  ushort4 u = { f2bf(f.x), f2bf(f.y), f2bf(f.z), f2bf(f.w) };
  *(ushort4*)(out + i) = u;
}

// ---------------- weight fp32 -> bf16 hi/lo pair ----------------
__global__ __launch_bounds__(256) void cvt_pair_kernel(const float* __restrict__ in,
                                                       unsigned short* __restrict__ hi,
                                                       unsigned short* __restrict__ lo, int n) {
  int i = (blockIdx.x * 256 + threadIdx.x) * 4;
  if (i >= n) return;
  float4 f = *(const float4*)(in + i);
  ushort4 h = { f2bf(f.x), f2bf(f.y), f2bf(f.z), f2bf(f.w) };
  ushort4 l = { f2bf(f.x - bf2f(h.x)), f2bf(f.y - bf2f(h.y)),
                f2bf(f.z - bf2f(h.z)), f2bf(f.w - bf2f(h.w)) };
  *(ushort4*)(hi + i) = h;
  *(ushort4*)(lo + i) = l;
}

// ---------------- tiled transpose: fp32 [R][Cc] -> bf16 hi/lo [Cc][R] ----------------
__global__ __launch_bounds__(256) void transpose_pair_kernel(const float* __restrict__ in,
                                                             long sIn,
                                                             unsigned short* __restrict__ hi,
                                                             unsigned short* __restrict__ lo,
                                                             long sOut, int R, int Cc) {
  int b = blockIdx.z;
  const float* I = in + (size_t)b * sIn;
  __shared__ float tile[64][65];
  int t = threadIdx.x;
  int r0 = blockIdx.y * 64, c0 = blockIdx.x * 64;
#pragma unroll
  for (int k = 0; k < 4; k++) {
    int vi = k * 256 + t, rr = vi >> 4, cv = vi & 15;
    float4 f = *(const float4*)&I[(size_t)(r0 + rr) * Cc + c0 + cv * 4];
    tile[rr][cv * 4 + 0] = f.x; tile[rr][cv * 4 + 1] = f.y;
    tile[rr][cv * 4 + 2] = f.z; tile[rr][cv * 4 + 3] = f.w;
  }
  __syncthreads();
#pragma unroll
  for (int k = 0; k < 4; k++) {
    int vi = k * 256 + t, cc = vi >> 4, rv = vi & 15;
    float f0 = tile[rv * 4 + 0][cc], f1 = tile[rv * 4 + 1][cc];
    float f2 = tile[rv * 4 + 2][cc], f3 = tile[rv * 4 + 3][cc];
    ushort4 h = { f2bf(f0), f2bf(f1), f2bf(f2), f2bf(f3) };
    ushort4 l = { f2bf(f0 - bf2f(h.x)), f2bf(f1 - bf2f(h.y)),
                  f2bf(f2 - bf2f(h.z)), f2bf(f3 - bf2f(h.w)) };
    size_t o = (size_t)b * sOut + (size_t)(c0 + cc) * R + r0 + rv * 4;
    *(ushort4*)&hi[o] = h;
    *(ushort4*)&lo[o] = l;
  }
}

// ---------------- rsv[b][n] = 1 / sum_k rowpart[b][n][k] ----------------
__global__ __launch_bounds__(256) void rowreduce_kernel(const float* __restrict__ rowpart,
                                                        float* __restrict__ rsv) {
  int idx = blockIdx.x * 256 + threadIdx.x;  // 8*2048 rows
  const float* p = rowpart + (size_t)idx * 32;
  float s = 0.f;
#pragma unroll
  for (int k = 0; k < 32; k++) s += p[k];
  rsv[idx] = 1.0f / s;
}

// ---------------- denom[b][m] = sum_n uT[b][m][n] * rsv[b][n] ----------------
__global__ __launch_bounds__(256) void denom_kernel(const unsigned short* __restrict__ uT,
                                                    const float* __restrict__ rsv,
                                                    float* __restrict__ denom) {
  int b = blockIdx.y;
  int m = blockIdx.x * 4 + (threadIdx.x >> 6);
  int lane = threadIdx.x & 63;
  const unsigned short* U = uT + ((size_t)b * KN_ + m) * KN_;
  const float* R = rsv + (size_t)b * KN_;
  float s = 0.f;
#pragma unroll
  for (int c = 0; c < 4; c++) {
    int n = c * 512 + lane * 8;
    u16x8 u = *(const u16x8*)&U[n];
    float4 r0 = *(const float4*)&R[n];
    float4 r1 = *(const float4*)&R[n + 4];
    s += bf2f(u[0]) * r0.x + bf2f(u[1]) * r0.y + bf2f(u[2]) * r0.z + bf2f(u[3]) * r0.w;
    s += bf2f(u[4]) * r1.x + bf2f(u[5]) * r1.y + bf2f(u[6]) * r1.z + bf2f(u[7]) * r1.w;
  }
#pragma unroll
  for (int o = 32; o > 0; o >>= 1) s += __shfl_xor(s, o, 64);
  if (lane == 0) denom[(size_t)b * KN_ + m] = s;
}

// ---------------- epilogue variants ----------------
enum { EPI_PAIR = 0, EPI_EXPT = 1, EPI_VSCALE = 2, EPI_PART = 3, EPI_FINAL = 4 };

struct EpiParams {
  const float* bias;
  const float* xf;  long xf_stride;
  const float* scale; long scale_stride;
  const float* gamma; const float* beta; const float* mean; const float* var;
  float* rowpart;
};

// ============== unified MFMA GEMM core, 128x128 tile, BK=32, segmented-K ==============
// Computes C[M][N] = A'[M][K] * B'[N][K]^T where, if seg>0 (K = 3*seg):
//   A' = [A0 | A1 | A0], B' = [B0 | B0 | B1]   (hi/lo compensated product)
// else A' = A0, B' = B0 (plain bf16 GEMM).
template<int EPI>
__device__ __forceinline__ void gemm_core(
    char* __restrict__ smem, int bx, int by, int b,
    const unsigned short* __restrict__ A0, const unsigned short* __restrict__ A1,
    long sA, int lda, int seg,
    const unsigned short* __restrict__ B0, const unsigned short* __restrict__ B1,
    long sB, int ldb,
    void* __restrict__ Cv, void* __restrict__ Cv2, long sC, int ldc, int K,
    const EpiParams& ep) {
  A0 += (size_t)b * sA; A1 += (size_t)b * sA;
  B0 += (size_t)b * sB; B1 += (size_t)b * sB;
  const int m0 = by * 128, n0 = bx * 128;
  const int t = threadIdx.x, lane = t & 63, w = t >> 6;
  const int wr = w >> 1, wc = w & 1;
  const int srow = t >> 2, scol = (t & 3) * 8;
  const int lr = lane & 15, lk = (lane >> 4) * 8;

  f32x4 acc[4][4];
  const f32x4 z = {0.f, 0.f, 0.f, 0.f};
#pragma unroll
  for (int i = 0; i < 4; i++)
#pragma unroll
    for (int j = 0; j < 4; j++) acc[i][j] = z;

  for (int kt = 0; kt < K; kt += 32) {
    int s = seg ? ((kt >= seg) + (kt >= 2 * seg)) : 0;
    int kl = kt - s * seg;
    const unsigned short* Ab = (s == 1) ? A1 : A0;
    const unsigned short* Bb = (s == 2) ? B1 : B0;
    const unsigned short* gA = Ab + (size_t)(m0 + srow) * lda + kl + scol;
    const unsigned short* gB = Bb + (size_t)(n0 + srow) * ldb + kl + scol;
    GLD16(gA, smem + w * 1024);
    GLD16(gA + (size_t)64 * lda, smem + 4096 + w * 1024);
    GLD16(gB, smem + 8192 + w * 1024);
    GLD16(gB + (size_t)64 * ldb, smem + 12288 + w * 1024);
    __syncthreads();
    bf16x8 af[4], bfv[4];
#pragma unroll
    for (int i = 0; i < 4; i++)
      af[i] = *(const bf16x8*)(smem + (wr * 64 + i * 16 + lr) * 64 + lk * 2);
#pragma unroll
    for (int j = 0; j < 4; j++)
      bfv[j] = *(const bf16x8*)(smem + 8192 + (wc * 64 + j * 16 + lr) * 64 + lk * 2);
#pragma unroll
    for (int i = 0; i < 4; i++)
#pragma unroll
      for (int j = 0; j < 4; j++)
        acc[i][j] = __builtin_amdgcn_mfma_f32_16x16x32_bf16(af[i], bfv[j], acc[i][j], 0, 0, 0);
    __syncthreads();
  }

  if constexpr (EPI == EPI_EXPT) {
    // ---- u = exp(E - 40) ----
#pragma unroll
    for (int i = 0; i < 4; i++)
#pragma unroll
      for (int j = 0; j < 4; j++)
#pragma unroll
        for (int r = 0; r < 4; r++) acc[i][j][r] = __expf(acc[i][j][r] - 40.f);

    // ---- partial row sums ----
#pragma unroll
    for (int i = 0; i < 4; i++) {
#pragma unroll
      for (int r = 0; r < 4; r++) {
        float s = acc[i][0][r] + acc[i][1][r] + acc[i][2][r] + acc[i][3][r];
        s += __shfl_xor(s, 1, 64); s += __shfl_xor(s, 2, 64);
        s += __shfl_xor(s, 4, 64); s += __shfl_xor(s, 8, 64);
        if ((lane & 15) == 0) {
          int row = m0 + wr * 64 + i * 16 + ((lane >> 4) << 2) + r;
          ep.rowpart[((size_t)b * KN_ + row) * 32 + bx * 2 + wc] = s;
        }
      }
    }

    // ---- transpose to uT via LDS (XOR-swizzled banks), coalesced write ----
    unsigned short* uT = (unsigned short*)Cv;
#pragma unroll
    for (int i = 0; i < 4; i++) {
#pragma unroll
      for (int j = 0; j < 4; j++) {
#pragma unroll
        for (int r2 = 0; r2 < 4; r2 += 2) {
          int row = wr * 64 + i * 16 + ((lane >> 4) << 2) + r2;
          int col = wc * 64 + j * 16 + lr;
          unsigned pk = (unsigned)f2bf(acc[i][j][r2]) |
                        ((unsigned)f2bf(acc[i][j][r2 + 1]) << 16);
          int a = ((col << 8) + (row << 1)) ^ ((col & 15) << 4);
          *(unsigned*)(smem + a) = pk;
        }
      }
    }
    __syncthreads();
    {
      int col = t >> 1, h = t & 1;
      size_t gbase = ((size_t)b * KN_ + (n0 + col)) * KN_ + m0 + h * 64;
#pragma unroll
      for (int c = 0; c < 8; c++) {
        int a = ((col << 8) + (h << 7) + (c << 4)) ^ ((col & 15) << 4);
        *(bf16x8*)&uT[gbase + c * 8] = *(const bf16x8*)(smem + a);
      }
    }
    return;
  }

#pragma unroll
  for (int i = 0; i < 4; i++) {
#pragma unroll
    for (int r = 0; r < 4; r++) {
      const int row = m0 + wr * 64 + i * 16 + ((lane >> 4) << 2) + r;
      float pbias = 0.f, pinv = 1.f, padd = 0.f;
      if constexpr (EPI == EPI_VSCALE) pbias = ep.bias[row];
      if constexpr (EPI == EPI_FINAL) {
        pbias = ep.bias[row];
        float iv = ep.gamma[row] * rsqrtf(ep.var[row] + 1e-5f);
        pinv = iv;
        padd = ep.beta[row] - ep.mean[row] * iv;
      }
#pragma unroll
      for (int j = 0; j < 4; j++) {
        const int col = n0 + wc * 64 + j * 16 + lr;
        float v = acc[i][j][r];
        size_t o = (size_t)b * sC + (size_t)row * ldc + col;
        if constexpr (EPI == EPI_PAIR) {
          unsigned short h = f2bf(v);
          ((unsigned short*)Cv)[o] = h;
          ((unsigned short*)Cv2)[o] = f2bf(v - bf2f(h));
        } else if constexpr (EPI == EPI_VSCALE) {
          float sc = ep.scale[(size_t)b * ep.scale_stride + col];
          ((unsigned short*)Cv)[o] = f2bf((v + pbias) * sc);
        } else if constexpr (EPI == EPI_PART) {
          ((float*)Cv)[o] = v;
        } else {  // EPI_FINAL
          float h = (v + pbias) * pinv + padd;
          h = fmaxf(h, 0.f);
          float xval = ep.xf[(size_t)b * ep.xf_stride + o - (size_t)b * sC];
          ((float*)Cv)[o] = h + xval;
        }
      }
    }
  }
}

// generic single-GEMM kernel (16 KB LDS, or 32 KB for energy's transpose scratch)
template<int EPI>
__global__ __launch_bounds__(256) void gemm_one(
    const unsigned short* __restrict__ A0, const unsigned short* __restrict__ A1,
    long sA, int lda, int seg,
    const unsigned short* __restrict__ B0, const unsigned short* __restrict__ B1,
    long sB, int ldb,
    void* __restrict__ Cv, void* __restrict__ Cv2, long sC, int ldc, int K,
    EpiParams ep) {
  __shared__ __align__(16) char smem[(EPI == EPI_EXPT) ? 32768 : 16384];
  int bx, by, b;
  xcd_swizzle(bx, by, b);
  gemm_core<EPI>(smem, bx, by, b, A0, A1, sA, lda, seg, B0, B1, sB, ldb,
                 Cv, Cv2, sC, ldc, K, ep);
}

// fused x_q + x_k projections: one 512-block launch (2 blocks/CU concurrent)
__global__ __launch_bounds__(256) void proj2_kernel(
    const unsigned short* __restrict__ qThi, const unsigned short* __restrict__ qTlo,
    const unsigned short* __restrict__ Wqhi, const unsigned short* __restrict__ Wqlo,
    unsigned short* __restrict__ xqhi, unsigned short* __restrict__ xqlo,
    const unsigned short* __restrict__ xThi, const unsigned short* __restrict__ xTlo,
    const unsigned short* __restrict__ Wkhi, const unsigned short* __restrict__ Wklo,
    unsigned short* __restrict__ xkhi, unsigned short* __restrict__ xklo) {
  __shared__ __align__(16) char smem[16384];
  int f = (int)blockIdx.x;
  f = (f & 7) * 64 + (f >> 3);  // XCD swizzle over 512
  EpiParams ep{};
  if (f < 256) {
    int bx = f & 1, by = (f >> 1) & 15, b = f >> 5;
    gemm_core<EPI_PAIR>(smem, bx, by, b, qThi, qTlo, (long)KN_ * KC_, KC_, KC_,
                        Wqhi, Wqlo, 0, KC_, xqhi, xqlo, (long)KN_ * KC2_, KC2_,
                        3 * KC_, ep);
  } else {
    int g = f - 256;
    int bx = g & 1, by = (g >> 1) & 15, b = g >> 5;
    gemm_core<EPI_PAIR>(smem, bx, by, b, xThi, xTlo, (long)KN_ * KC2_, KC2_, KC2_,
                        Wkhi, Wklo, 0, KC2_, xkhi, xklo, (long)KN_ * KC2_, KC2_,
                        3 * KC2_, ep);
  }
}

// XR partial GEMM: split-K x2 (grid (32,2,8)); P[s] = x_v'[c][k-half] . uT[m][k-half]^T
__global__ __launch_bounds__(256) void xr_kernel(
    const unsigned short* __restrict__ x_v, const unsigned short* __restrict__ uT,
    float* __restrict__ P) {
  __shared__ __align__(16) char smem[16384];
  int bx, by, b;
  xcd_swizzle(bx, by, b);
  int split = bx >> 4; bx &= 15;
  EpiParams ep{};
  gemm_core<EPI_PART>(smem, bx, by, b,
                      x_v + split * (KN_ / 2), nullptr, (long)KC2_ * KN_, KN_, 0,
                      uT + split * (KN_ / 2), nullptr, (long)KN_ * KN_, KN_,
                      P + (size_t)split * KB_ * KC2_ * KN_, nullptr,
                      (long)KC2_ * KN_, KN_, KN_ / 2, ep);
}

// reduce split-K partials + offset-attn renorm + residual-subtract + transpose -> tT[m][c]
__global__ __launch_bounds__(256) void xr_reduce_kernel(
    const float* __restrict__ P, const float* __restrict__ x,
    const float* __restrict__ denom, unsigned short* __restrict__ tT) {
  int b = blockIdx.z;
  const float* P0 = P + (size_t)b * KC2_ * KN_;
  const float* P1 = P0 + (size_t)KB_ * KC2_ * KN_;
  const float* X  = x + (size_t)b * KC2_ * KN_;
  const float* D  = denom + (size_t)b * KN_;
  __shared__ unsigned short tile[64][72];
  int t = threadIdx.x;
  int c0 = blockIdx.y * 64, m0 = blockIdx.x * 64;  // rows = c, cols = m
#pragma unroll
  for (int k = 0; k < 4; k++) {
    int vi = k * 256 + t, rr = vi >> 4, cv = vi & 15;
    size_t o = (size_t)(c0 + rr) * KN_ + m0 + cv * 4;
    float4 p0 = *(const float4*)&P0[o];
    float4 p1 = *(const float4*)&P1[o];
    float4 xv = *(const float4*)&X[o];
    float4 dv = *(const float4*)&D[m0 + cv * 4];
    tile[rr][cv * 4 + 0] = f2bf(xv.x - (p0.x + p1.x) / (1e-9f + dv.x));
    tile[rr][cv * 4 + 1] = f2bf(xv.y - (p0.y + p1.y) / (1e-9f + dv.y));
    tile[rr][cv * 4 + 2] = f2bf(xv.z - (p0.z + p1.z) / (1e-9f + dv.z));
    tile[rr][cv * 4 + 3] = f2bf(xv.w - (p0.w + p1.w) / (1e-9f + dv.w));
  }
  __syncthreads();
#pragma unroll
  for (int k = 0; k < 4; k++) {
    int vi = k * 256 + t, cc = vi >> 4, rv = vi & 15;
    ushort4 u = { tile[rv * 4 + 0][cc], tile[rv * 4 + 1][cc],
                  tile[rv * 4 + 2][cc], tile[rv * 4 + 3][cc] };
    *(ushort4*)&tT[(size_t)b * KN_ * KC2_ + (size_t)(m0 + cc) * KC2_ + c0 + rv * 4] = u;
  }
}

// ---------------- launcher ----------------
extern "C" void kernel_launch(void* const* d_in, const int* in_sizes, int n_in,
                              void* d_out, int out_size, void* d_ws, size_t ws_size,
                              hipStream_t stream) {
  (void)in_sizes; (void)n_in; (void)out_size; (void)ws_size;
  const float* q     = (const float*)d_in[0];
  const float* x     = (const float*)d_in[1];
  const float* Wq    = (const float*)d_in[2];
  const float* Wk    = (const float*)d_in[3];
  const float* Wv    = (const float*)d_in[4];
  const float* bv    = (const float*)d_in[5];
  const float* Wt    = (const float*)d_in[6];
  const float* bt    = (const float*)d_in[7];
  const float* gamma = (const float*)d_in[8];
  const float* beta  = (const float*)d_in[9];
  const float* rmean = (const float*)d_in[10];
  const float* rvar  = (const float*)d_in[11];
  float* out = (float*)d_out;

  // workspace (~196 MiB)
  const size_t SZ_qT = (size_t)KB_ * KN_ * KC_ * 2;   // 16 MiB
  const size_t SZ_xT = (size_t)KB_ * KN_ * KC2_ * 2;  //  8 MiB
  char* ws = (char*)d_ws;
  size_t off = 0;
  auto alloc = [&](size_t bytes) {
    char* p = ws + off;
    off += (bytes + 255) & ~(size_t)255;
    return p;
  };
  unsigned short* qThi = (unsigned short*)alloc(SZ_qT);
  unsigned short* qTlo = (unsigned short*)alloc(SZ_qT);
  unsigned short* xThi = (unsigned short*)alloc(SZ_xT);
  unsigned short* xTlo = (unsigned short*)alloc(SZ_xT);
  unsigned short* xqhi = (unsigned short*)alloc(SZ_xT);
  unsigned short* xqlo = (unsigned short*)alloc(SZ_xT);
  unsigned short* xkhi = (unsigned short*)alloc(SZ_xT);
  unsigned short* xklo = (unsigned short*)alloc(SZ_xT);
  unsigned short* x_v  = (unsigned short*)alloc((size_t)KB_ * KC2_ * KN_ * 2);
  unsigned short* tT   = (unsigned short*)alloc(SZ_xT);
  unsigned short* Wqhi = (unsigned short*)alloc((size_t)KC2_ * KC_ * 2);
  unsigned short* Wqlo = (unsigned short*)alloc((size_t)KC2_ * KC_ * 2);
  unsigned short* Wkhi = (unsigned short*)alloc((size_t)KC2_ * KC2_ * 2);
  unsigned short* Wklo = (unsigned short*)alloc((size_t)KC2_ * KC2_ * 2);
  unsigned short* Wvb  = (unsigned short*)alloc((size_t)KC2_ * KC_ * 2);
  unsigned short* Wtb  = (unsigned short*)alloc((size_t)KC2_ * KC2_ * 2);
  float* rsv     = (float*)alloc((size_t)KB_ * KN_ * 4);
  float* denom   = (float*)alloc((size_t)KB_ * KN_ * 4);
  float* rowpart = (float*)alloc((size_t)KB_ * KN_ * 32 * 4);
  float* P       = (float*)alloc((size_t)2 * KB_ * KC2_ * KN_ * 4);           // 32 MiB
  unsigned short* uT = (unsigned short*)alloc((size_t)KB_ * KN_ * KN_ * 2);   // 64 MiB

  dim3 blk(256);

  // weights -> bf16
  cvt_pair_kernel<<<dim3(KC2_ * KC_ / 1024), blk, 0, stream>>>(Wq, Wqhi, Wqlo, KC2_ * KC_);
  cvt_pair_kernel<<<dim3(KC2_ * KC2_ / 1024), blk, 0, stream>>>(Wk, Wkhi, Wklo, KC2_ * KC2_);
  cvt_kernel<<<dim3(KC2_ * KC_ / 1024), blk, 0, stream>>>(Wv, Wvb, KC2_ * KC_);
  cvt_kernel<<<dim3(KC2_ * KC2_ / 1024), blk, 0, stream>>>(Wt, Wtb, KC2_ * KC2_);

  // q^T, x^T fp32 -> hi/lo bf16 pairs (K contiguous)
  transpose_pair_kernel<<<dim3(KN_ / 64, KC_ / 64, KB_), blk, 0, stream>>>(
      q, (long)KC_ * KN_, qThi, qTlo, (long)KN_ * KC_, KC_, KN_);
  transpose_pair_kernel<<<dim3(KN_ / 64, KC2_ / 64, KB_), blk, 0, stream>>>(
      x, (long)KC2_ * KN_, xThi, xTlo, (long)KN_ * KC2_, KC2_, KN_);

  // x_q / x_kT projections (fp32-grade via segmented-K, one 512-block launch)
  proj2_kernel<<<dim3(512), blk, 0, stream>>>(qThi, qTlo, Wqhi, Wqlo, xqhi, xqlo,
                                              xThi, xTlo, Wkhi, Wklo, xkhi, xklo);

  // energy + exp + transpose + row partials (segmented-K, K' = 768)
  EpiParams eE{}; eE.rowpart = rowpart;
  gemm_one<EPI_EXPT><<<dim3(KN_ / 128, KN_ / 128, KB_), blk, 0, stream>>>(
      xqhi, xqlo, (long)KN_ * KC2_, KC2_, KC2_,
      xkhi, xklo, (long)KN_ * KC2_, KC2_,
      uT, nullptr, 0, 0, 3 * KC2_, eE);
  rowreduce_kernel<<<dim3(KB_ * KN_ / 256), blk, 0, stream>>>(rowpart, rsv);

  // x_v'[b][o][n] = (Wv[o][:].qT[n][:] + bv[o]) * rsv[b][n]
  EpiParams e3{}; e3.bias = bv; e3.scale = rsv; e3.scale_stride = KN_;
  gemm_one<EPI_VSCALE><<<dim3(KN_ / 128, KC2_ / 128, KB_), blk, 0, stream>>>(
      Wvb, nullptr, 0, KC_, 0, qThi, nullptr, (long)KN_ * KC_, KC_,
      x_v, nullptr, (long)KC2_ * KN_, KN_, KC_, e3);

  // denom[b][m] = sum_n uT[m][n] * rsv[n]
  denom_kernel<<<dim3(KN_ / 4, KB_), blk, 0, stream>>>(uT, rsv, denom);

  // x_r partials (split-K x2) then reduce + renorm + subtract + transpose -> tT
  xr_kernel<<<dim3(32, 2, 8), blk, 0, stream>>>(x_v, uT, P);
  xr_reduce_kernel<<<dim3(KN_ / 64, KC2_ / 64, KB_), blk, 0, stream>>>(P, x, denom, tT);

  // out[b][o][n] = relu(BN(Wt[o][:].tT[n][:] + bt[o])) + x[b][o][n]
  EpiParams e6{}; e6.bias = bt; e6.xf = x; e6.xf_stride = (long)KC2_ * KN_;
  e6.gamma = gamma; e6.beta = beta; e6.mean = rmean; e6.var = rvar;
  gemm_one<EPI_FINAL><<<dim3(KN_ / 128, KC2_ / 128, KB_), blk, 0, stream>>>(
      Wtb, nullptr, 0, KC2_, 0, tT, nullptr, (long)KN_ * KC2_, KC2_,
      out, nullptr, (long)KC2_ * KN_, KN_, KC2_, e6);
}

// Round 6
// 240.602 us; speedup vs baseline: 1.2646x; 1.0731x over previous
//
#include <hip/hip_runtime.h>
#include <cstdint>
#include <cstddef>

// Problem constants (B, C, N fixed by the reference)
#define KB_  8
#define KC_  512
#define KC2_ 256
#define KN_  2048

typedef __attribute__((ext_vector_type(8))) __bf16 bf16x8;
typedef __attribute__((ext_vector_type(8))) unsigned short u16x8;
typedef __attribute__((ext_vector_type(4))) float f32x4;

__device__ __forceinline__ unsigned short f2bf(float f) {
  union { float f; unsigned u; } x; x.f = f;
  unsigned r = x.u + 0x7fffu + ((x.u >> 16) & 1u);  // RNE (finite values only)
  return (unsigned short)(r >> 16);
}
__device__ __forceinline__ float bf2f(unsigned short h) {
  union { unsigned u; float f; } x; x.u = ((unsigned)h) << 16;
  return x.f;
}

// async global->LDS, 16B per lane; LDS dest = wave-uniform base + lane*16 (linear!)
#define GLD16(g, l) __builtin_amdgcn_global_load_lds( \
    (__attribute__((address_space(1))) void*)(g),     \
    (__attribute__((address_space(3))) void*)(l), 16, 0, 0)

// bijective XCD-aware block swizzle (nb % 8 == 0 for all our grids)
__device__ __forceinline__ void xcd_swizzle(int& bx, int& by, int& bz) {
  const int gx = gridDim.x, gy = gridDim.y;
  const int nb = gx * gy * (int)gridDim.z;
  int f = ((int)blockIdx.z * gy + (int)blockIdx.y) * gx + (int)blockIdx.x;
  if ((nb & 7) == 0) f = (f & 7) * (nb >> 3) + (f >> 3);
  const int gxy = gx * gy;
  bz = f / gxy; int rem = f - bz * gxy;
  by = rem / gx; bx = rem - by * gx;
}

// ---------------- weight fp32 -> bf16 convert (single) ----------------
__global__ __launch_bounds__(256) void cvt_kernel(const float* __restrict__ in,
                                                  unsigned short* __restrict__ out, int n) {
  int i = (blockIdx.x * 256 + threadIdx.x) * 4;
  if (i >= n) return;
  float4 f = *(const float4*)(in + i);
  ushort4 u = { f2bf(f.x), f2bf(f.y), f2bf(f.z), f2bf(f.w) };
  *(ushort4*)(out + i) = u;
}

// ---------------- weight fp32 -> bf16 hi/lo pair ----------------
__global__ __launch_bounds__(256) void cvt_pair_kernel(const float* __restrict__ in,
                                                       unsigned short* __restrict__ hi,
                                                       unsigned short* __restrict__ lo, int n) {
  int i = (blockIdx.x * 256 + threadIdx.x) * 4;
  if (i >= n) return;
  float4 f = *(const float4*)(in + i);
  ushort4 h = { f2bf(f.x), f2bf(f.y), f2bf(f.z), f2bf(f.w) };
  ushort4 l = { f2bf(f.x - bf2f(h.x)), f2bf(f.y - bf2f(h.y)),
                f2bf(f.z - bf2f(h.z)), f2bf(f.w - bf2f(h.w)) };
  *(ushort4*)(hi + i) = h;
  *(ushort4*)(lo + i) = l;
}

// ---------------- tiled transpose: fp32 [R][Cc] -> bf16 hi/lo [Cc][R] ----------------
__global__ __launch_bounds__(256) void transpose_pair_kernel(const float* __restrict__ in,
                                                             long sIn,
                                                             unsigned short* __restrict__ hi,
                                                             unsigned short* __restrict__ lo,
                                                             long sOut, int R, int Cc) {
  int b = blockIdx.z;
  const float* I = in + (size_t)b * sIn;
  __shared__ float tile[64][65];
  int t = threadIdx.x;
  int r0 = blockIdx.y * 64, c0 = blockIdx.x * 64;
#pragma unroll
  for (int k = 0; k < 4; k++) {
    int vi = k * 256 + t, rr = vi >> 4, cv = vi & 15;
    float4 f = *(const float4*)&I[(size_t)(r0 + rr) * Cc + c0 + cv * 4];
    tile[rr][cv * 4 + 0] = f.x; tile[rr][cv * 4 + 1] = f.y;
    tile[rr][cv * 4 + 2] = f.z; tile[rr][cv * 4 + 3] = f.w;
  }
  __syncthreads();
#pragma unroll
  for (int k = 0; k < 4; k++) {
    int vi = k * 256 + t, cc = vi >> 4, rv = vi & 15;
    float f0 = tile[rv * 4 + 0][cc], f1 = tile[rv * 4 + 1][cc];
    float f2 = tile[rv * 4 + 2][cc], f3 = tile[rv * 4 + 3][cc];
    ushort4 h = { f2bf(f0), f2bf(f1), f2bf(f2), f2bf(f3) };
    ushort4 l = { f2bf(f0 - bf2f(h.x)), f2bf(f1 - bf2f(h.y)),
                  f2bf(f2 - bf2f(h.z)), f2bf(f3 - bf2f(h.w)) };
    size_t o = (size_t)b * sOut + (size_t)(c0 + cc) * R + r0 + rv * 4;
    *(ushort4*)&hi[o] = h;
    *(ushort4*)&lo[o] = l;
  }
}

// ---------------- rsv[b][n] = 1 / sum_k rowpart[b][n][k] ----------------
__global__ __launch_bounds__(256) void rowreduce_kernel(const float* __restrict__ rowpart,
                                                        float* __restrict__ rsv) {
  int idx = blockIdx.x * 256 + threadIdx.x;  // 8*2048 rows
  const float* p = rowpart + (size_t)idx * 32;
  float s = 0.f;
#pragma unroll
  for (int k = 0; k < 32; k++) s += p[k];
  rsv[idx] = 1.0f / s;
}

// ---------------- denom[b][m] = sum_n uT[b][m][n] * rsv[b][n] ----------------
__global__ __launch_bounds__(256) void denom_kernel(const unsigned short* __restrict__ uT,
                                                    const float* __restrict__ rsv,
                                                    float* __restrict__ denom) {
  int b = blockIdx.y;
  int m = blockIdx.x * 4 + (threadIdx.x >> 6);
  int lane = threadIdx.x & 63;
  const unsigned short* U = uT + ((size_t)b * KN_ + m) * KN_;
  const float* R = rsv + (size_t)b * KN_;
  float s = 0.f;
#pragma unroll
  for (int c = 0; c < 4; c++) {
    int n = c * 512 + lane * 8;
    u16x8 u = *(const u16x8*)&U[n];
    float4 r0 = *(const float4*)&R[n];
    float4 r1 = *(const float4*)&R[n + 4];
    s += bf2f(u[0]) * r0.x + bf2f(u[1]) * r0.y + bf2f(u[2]) * r0.z + bf2f(u[3]) * r0.w;
    s += bf2f(u[4]) * r1.x + bf2f(u[5]) * r1.y + bf2f(u[6]) * r1.z + bf2f(u[7]) * r1.w;
  }
#pragma unroll
  for (int o = 32; o > 0; o >>= 1) s += __shfl_xor(s, o, 64);
  if (lane == 0) denom[(size_t)b * KN_ + m] = s;
}

// ---------------- energy kernel: 4-buffer split-GEMM + exp + transpose + row-partials ----
// E[n][m] = (ah+al)[n][:].(bh+bl)[m][:] ~ ah.bh + al.bh + ah.bl ; u = exp(E-40);
// writes uT[b][m][n] (bf16) and rowpart[b][n][32].
// LDS staging: linear dest (GLD16), pre-swizzled global source; swizzled ds_read
// (chunk ^= (row>>1)&3) -> 2 lanes/bank (free) instead of 8-way conflict.
__global__ __launch_bounds__(256) void energy_kernel(
    const unsigned short* __restrict__ Ahi, const unsigned short* __restrict__ Alo,
    const unsigned short* __restrict__ Bhi, const unsigned short* __restrict__ Blo,
    unsigned short* __restrict__ uT, float* __restrict__ rowpart) {
  int bx, by, b;
  xcd_swizzle(bx, by, b);  // grid (16,16,8): each XCD owns one batch
  Ahi += (size_t)b * KN_ * KC2_; Alo += (size_t)b * KN_ * KC2_;
  Bhi += (size_t)b * KN_ * KC2_; Blo += (size_t)b * KN_ * KC2_;
  const int m0 = by * 128;  // rows = n (query idx)
  const int n0 = bx * 128;  // cols = m (key idx)
  __shared__ __align__(16) char smem[32768];  // 4x8KB staging; reused for transpose
  const int t = threadIdx.x, lane = t & 63, w = t >> 6;
  const int wr = w >> 1, wc = w & 1;
  const int srow = t >> 2;
  const int scol = (((t & 3) ^ ((srow >> 1) & 3)) * 8);   // pre-swizzled k-chunk
  const int lr = lane & 15, lk = (lane >> 4) * 8;
  const int rsw = ((lr >> 1) & 3) << 4;                   // read-side XOR (bytes)

  f32x4 acc[4][4];
  const f32x4 z = {0.f, 0.f, 0.f, 0.f};
#pragma unroll
  for (int i = 0; i < 4; i++)
#pragma unroll
    for (int j = 0; j < 4; j++) acc[i][j] = z;

  for (int kt = 0; kt < KC2_; kt += 32) {
    const size_t ga = (size_t)(m0 + srow) * KC2_ + kt + scol;
    const size_t gb = (size_t)(n0 + srow) * KC2_ + kt + scol;
    GLD16(Ahi + ga, smem + 0 + w * 1024);
    GLD16(Ahi + ga + (size_t)64 * KC2_, smem + 4096 + w * 1024);
    GLD16(Alo + ga, smem + 8192 + w * 1024);
    GLD16(Alo + ga + (size_t)64 * KC2_, smem + 12288 + w * 1024);
    GLD16(Bhi + gb, smem + 16384 + w * 1024);
    GLD16(Bhi + gb + (size_t)64 * KC2_, smem + 20480 + w * 1024);
    GLD16(Blo + gb, smem + 24576 + w * 1024);
    GLD16(Blo + gb + (size_t)64 * KC2_, smem + 28672 + w * 1024);
    __syncthreads();
    bf16x8 ah[4], al[4], bh[4], bl[4];
#pragma unroll
    for (int i = 0; i < 4; i++) {
      int ro = (wr * 64 + i * 16 + lr) * 64 + ((lk * 2) ^ rsw);
      ah[i] = *(const bf16x8*)(smem + 0 + ro);
      al[i] = *(const bf16x8*)(smem + 8192 + ro);
    }
#pragma unroll
    for (int j = 0; j < 4; j++) {
      int ro = (wc * 64 + j * 16 + lr) * 64 + ((lk * 2) ^ rsw);
      bh[j] = *(const bf16x8*)(smem + 16384 + ro);
      bl[j] = *(const bf16x8*)(smem + 24576 + ro);
    }
#pragma unroll
    for (int i = 0; i < 4; i++)
#pragma unroll
      for (int j = 0; j < 4; j++) {
        acc[i][j] = __builtin_amdgcn_mfma_f32_16x16x32_bf16(al[i], bh[j], acc[i][j], 0, 0, 0);
        acc[i][j] = __builtin_amdgcn_mfma_f32_16x16x32_bf16(ah[i], bl[j], acc[i][j], 0, 0, 0);
        acc[i][j] = __builtin_amdgcn_mfma_f32_16x16x32_bf16(ah[i], bh[j], acc[i][j], 0, 0, 0);
      }
    __syncthreads();
  }

  // ---- u = exp(E - 40) ----
#pragma unroll
  for (int i = 0; i < 4; i++)
#pragma unroll
    for (int j = 0; j < 4; j++)
#pragma unroll
      for (int r = 0; r < 4; r++) acc[i][j][r] = __expf(acc[i][j][r] - 40.f);

  // ---- partial row sums ----
#pragma unroll
  for (int i = 0; i < 4; i++) {
#pragma unroll
    for (int r = 0; r < 4; r++) {
      float s = acc[i][0][r] + acc[i][1][r] + acc[i][2][r] + acc[i][3][r];
      s += __shfl_xor(s, 1, 64); s += __shfl_xor(s, 2, 64);
      s += __shfl_xor(s, 4, 64); s += __shfl_xor(s, 8, 64);
      if ((lane & 15) == 0) {
        int row = m0 + wr * 64 + i * 16 + ((lane >> 4) << 2) + r;
        rowpart[((size_t)b * KN_ + row) * 32 + bx * 2 + wc] = s;
      }
    }
  }

  // ---- transpose to uT via LDS (XOR-swizzled banks), coalesced write ----
#pragma unroll
  for (int i = 0; i < 4; i++) {
#pragma unroll
    for (int j = 0; j < 4; j++) {
#pragma unroll
      for (int r2 = 0; r2 < 4; r2 += 2) {
        int row = wr * 64 + i * 16 + ((lane >> 4) << 2) + r2;
        int col = wc * 64 + j * 16 + lr;
        unsigned pk = (unsigned)f2bf(acc[i][j][r2]) |
                      ((unsigned)f2bf(acc[i][j][r2 + 1]) << 16);
        int a = ((col << 8) + (row << 1)) ^ ((col & 15) << 4);
        *(unsigned*)(smem + a) = pk;
      }
    }
  }
  __syncthreads();
  {
    int col = t >> 1, h = t & 1;
    size_t gbase = ((size_t)b * KN_ + (n0 + col)) * KN_ + m0 + h * 64;
#pragma unroll
    for (int c = 0; c < 8; c++) {
      int a = ((col << 8) + (h << 7) + (c << 4)) ^ ((col & 15) << 4);
      *(bf16x8*)&uT[gbase + c * 8] = *(const bf16x8*)(smem + a);
    }
  }
}

// ---------------- epilogue variants ----------------
enum { EPI_PAIR = 0, EPI_VSCALE = 2, EPI_PART = 3, EPI_FINAL = 4 };

struct EpiParams {
  const float* bias;
  const float* xf;  long xf_stride;
  const float* scale; long scale_stride;
  const float* gamma; const float* beta; const float* mean; const float* var;
};

// ============== unified MFMA GEMM core, 128x128 tile, BK=64 (2 sub-tiles/barrier),
// segmented-K: if seg>0 (K = 3*seg): A' = [A0|A1|A0], B' = [B0|B0|B1]. ==============
template<int EPI>
__device__ __forceinline__ void gemm_core(
    char* __restrict__ smem, int bx, int by, int b,
    const unsigned short* __restrict__ A0, const unsigned short* __restrict__ A1,
    long sA, int lda, int seg,
    const unsigned short* __restrict__ B0, const unsigned short* __restrict__ B1,
    long sB, int ldb,
    void* __restrict__ Cv, void* __restrict__ Cv2, long sC, int ldc, int K,
    const EpiParams& ep) {
  A0 += (size_t)b * sA; A1 += (size_t)b * sA;
  B0 += (size_t)b * sB; B1 += (size_t)b * sB;
  const int m0 = by * 128, n0 = bx * 128;
  const int t = threadIdx.x, lane = t & 63, w = t >> 6;
  const int wr = w >> 1, wc = w & 1;
  const int srow = t >> 2;
  const int scol = (((t & 3) ^ ((srow >> 1) & 3)) * 8);   // pre-swizzled k-chunk
  const int lr = lane & 15, lk = (lane >> 4) * 8;
  const int rsw = ((lr >> 1) & 3) << 4;                   // read-side XOR (bytes)

  f32x4 acc[4][4];
  const f32x4 z = {0.f, 0.f, 0.f, 0.f};
#pragma unroll
  for (int i = 0; i < 4; i++)
#pragma unroll
    for (int j = 0; j < 4; j++) acc[i][j] = z;

  for (int kt = 0; kt < K; kt += 64) {
    int s = seg ? ((kt >= seg) + (kt >= 2 * seg)) : 0;
    int kl = kt - s * seg;
    const unsigned short* Ab = (s == 1) ? A1 : A0;
    const unsigned short* Bb = (s == 2) ? B1 : B0;
    const unsigned short* gA = Ab + (size_t)(m0 + srow) * lda + kl + scol;
    const unsigned short* gB = Bb + (size_t)(n0 + srow) * ldb + kl + scol;
    GLD16(gA, smem + w * 1024);                        // A k0, rows 0-63
    GLD16(gA + (size_t)64 * lda, smem + 4096 + w * 1024);
    GLD16(gA + 32, smem + 8192 + w * 1024);            // A k1
    GLD16(gA + (size_t)64 * lda + 32, smem + 12288 + w * 1024);
    GLD16(gB, smem + 16384 + w * 1024);                // B k0
    GLD16(gB + (size_t)64 * ldb, smem + 20480 + w * 1024);
    GLD16(gB + 32, smem + 24576 + w * 1024);           // B k1
    GLD16(gB + (size_t)64 * ldb + 32, smem + 28672 + w * 1024);
    __syncthreads();
#pragma unroll
    for (int kk = 0; kk < 2; kk++) {
      bf16x8 af[4], bfv[4];
#pragma unroll
      for (int i = 0; i < 4; i++)
        af[i] = *(const bf16x8*)(smem + kk * 8192 +
                                 (wr * 64 + i * 16 + lr) * 64 + ((lk * 2) ^ rsw));
#pragma unroll
      for (int j = 0; j < 4; j++)
        bfv[j] = *(const bf16x8*)(smem + 16384 + kk * 8192 +
                                  (wc * 64 + j * 16 + lr) * 64 + ((lk * 2) ^ rsw));
#pragma unroll
      for (int i = 0; i < 4; i++)
#pragma unroll
        for (int j = 0; j < 4; j++)
          acc[i][j] = __builtin_amdgcn_mfma_f32_16x16x32_bf16(af[i], bfv[j], acc[i][j], 0, 0, 0);
    }
    __syncthreads();
  }

#pragma unroll
  for (int i = 0; i < 4; i++) {
#pragma unroll
    for (int r = 0; r < 4; r++) {
      const int row = m0 + wr * 64 + i * 16 + ((lane >> 4) << 2) + r;
      float pbias = 0.f, pinv = 1.f, padd = 0.f;
      if constexpr (EPI == EPI_VSCALE) pbias = ep.bias[row];
      if constexpr (EPI == EPI_FINAL) {
        pbias = ep.bias[row];
        float iv = ep.gamma[row] * rsqrtf(ep.var[row] + 1e-5f);
        pinv = iv;
        padd = ep.beta[row] - ep.mean[row] * iv;
      }
#pragma unroll
      for (int j = 0; j < 4; j++) {
        const int col = n0 + wc * 64 + j * 16 + lr;
        float v = acc[i][j][r];
        size_t o = (size_t)b * sC + (size_t)row * ldc + col;
        if constexpr (EPI == EPI_PAIR) {
          unsigned short h = f2bf(v);
          ((unsigned short*)Cv)[o] = h;
          ((unsigned short*)Cv2)[o] = f2bf(v - bf2f(h));
        } else if constexpr (EPI == EPI_VSCALE) {
          float sc = ep.scale[(size_t)b * ep.scale_stride + col];
          ((unsigned short*)Cv)[o] = f2bf((v + pbias) * sc);
        } else if constexpr (EPI == EPI_PART) {
          ((float*)Cv)[o] = v;
        } else {  // EPI_FINAL
          float h = (v + pbias) * pinv + padd;
          h = fmaxf(h, 0.f);
          float xval = ep.xf[(size_t)b * ep.xf_stride + o - (size_t)b * sC];
          ((float*)Cv)[o] = h + xval;
        }
      }
    }
  }
}

// generic single-GEMM kernel (32 KB LDS)
template<int EPI>
__global__ __launch_bounds__(256) void gemm_one(
    const unsigned short* __restrict__ A0, const unsigned short* __restrict__ A1,
    long sA, int lda, int seg,
    const unsigned short* __restrict__ B0, const unsigned short* __restrict__ B1,
    long sB, int ldb,
    void* __restrict__ Cv, void* __restrict__ Cv2, long sC, int ldc, int K,
    EpiParams ep) {
  __shared__ __align__(16) char smem[32768];
  int bx, by, b;
  xcd_swizzle(bx, by, b);
  gemm_core<EPI>(smem, bx, by, b, A0, A1, sA, lda, seg, B0, B1, sB, ldb,
                 Cv, Cv2, sC, ldc, K, ep);
}

// fused x_q + x_k projections: one 512-block launch
__global__ __launch_bounds__(256) void proj2_kernel(
    const unsigned short* __restrict__ qThi, const unsigned short* __restrict__ qTlo,
    const unsigned short* __restrict__ Wqhi, const unsigned short* __restrict__ Wqlo,
    unsigned short* __restrict__ xqhi, unsigned short* __restrict__ xqlo,
    const unsigned short* __restrict__ xThi, const unsigned short* __restrict__ xTlo,
    const unsigned short* __restrict__ Wkhi, const unsigned short* __restrict__ Wklo,
    unsigned short* __restrict__ xkhi, unsigned short* __restrict__ xklo) {
  __shared__ __align__(16) char smem[32768];
  int f = (int)blockIdx.x;
  f = (f & 7) * 64 + (f >> 3);  // XCD swizzle over 512
  EpiParams ep{};
  if (f < 256) {
    int bx = f & 1, by = (f >> 1) & 15, b = f >> 5;
    gemm_core<EPI_PAIR>(smem, bx, by, b, qThi, qTlo, (long)KN_ * KC_, KC_, KC_,
                        Wqhi, Wqlo, 0, KC_, xqhi, xqlo, (long)KN_ * KC2_, KC2_,
                        3 * KC_, ep);
  } else {
    int g = f - 256;
    int bx = g & 1, by = (g >> 1) & 15, b = g >> 5;
    gemm_core<EPI_PAIR>(smem, bx, by, b, xThi, xTlo, (long)KN_ * KC2_, KC2_, KC2_,
                        Wkhi, Wklo, 0, KC2_, xkhi, xklo, (long)KN_ * KC2_, KC2_,
                        3 * KC2_, ep);
  }
}

// XR partial GEMM: split-K x2 (grid (32,2,8))
__global__ __launch_bounds__(256) void xr_kernel(
    const unsigned short* __restrict__ x_v, const unsigned short* __restrict__ uT,
    float* __restrict__ P) {
  __shared__ __align__(16) char smem[32768];
  int bx, by, b;
  xcd_swizzle(bx, by, b);
  int split = bx >> 4; bx &= 15;
  EpiParams ep{};
  gemm_core<EPI_PART>(smem, bx, by, b,
                      x_v + split * (KN_ / 2), nullptr, (long)KC2_ * KN_, KN_, 0,
                      uT + split * (KN_ / 2), nullptr, (long)KN_ * KN_, KN_,
                      P + (size_t)split * KB_ * KC2_ * KN_, nullptr,
                      (long)KC2_ * KN_, KN_, KN_ / 2, ep);
}

// reduce split-K partials + renorm + residual-subtract + transpose -> tT[m][c]
__global__ __launch_bounds__(256) void xr_reduce_kernel(
    const float* __restrict__ P, const float* __restrict__ x,
    const float* __restrict__ denom, unsigned short* __restrict__ tT) {
  int b = blockIdx.z;
  const float* P0 = P + (size_t)b * KC2_ * KN_;
  const float* P1 = P0 + (size_t)KB_ * KC2_ * KN_;
  const float* X  = x + (size_t)b * KC2_ * KN_;
  const float* D  = denom + (size_t)b * KN_;
  __shared__ unsigned short tile[64][72];
  int t = threadIdx.x;
  int c0 = blockIdx.y * 64, m0 = blockIdx.x * 64;  // rows = c, cols = m
#pragma unroll
  for (int k = 0; k < 4; k++) {
    int vi = k * 256 + t, rr = vi >> 4, cv = vi & 15;
    size_t o = (size_t)(c0 + rr) * KN_ + m0 + cv * 4;
    float4 p0 = *(const float4*)&P0[o];
    float4 p1 = *(const float4*)&P1[o];
    float4 xv = *(const float4*)&X[o];
    float4 dv = *(const float4*)&D[m0 + cv * 4];
    tile[rr][cv * 4 + 0] = f2bf(xv.x - (p0.x + p1.x) / (1e-9f + dv.x));
    tile[rr][cv * 4 + 1] = f2bf(xv.y - (p0.y + p1.y) / (1e-9f + dv.y));
    tile[rr][cv * 4 + 2] = f2bf(xv.z - (p0.z + p1.z) / (1e-9f + dv.z));
    tile[rr][cv * 4 + 3] = f2bf(xv.w - (p0.w + p1.w) / (1e-9f + dv.w));
  }
  __syncthreads();
#pragma unroll
  for (int k = 0; k < 4; k++) {
    int vi = k * 256 + t, cc = vi >> 4, rv = vi & 15;
    ushort4 u = { tile[rv * 4 + 0][cc], tile[rv * 4 + 1][cc],
                  tile[rv * 4 + 2][cc], tile[rv * 4 + 3][cc] };
    *(ushort4*)&tT[(size_t)b * KN_ * KC2_ + (size_t)(m0 + cc) * KC2_ + c0 + rv * 4] = u;
  }
}

// ---------------- launcher ----------------
extern "C" void kernel_launch(void* const* d_in, const int* in_sizes, int n_in,
                              void* d_out, int out_size, void* d_ws, size_t ws_size,
                              hipStream_t stream) {
  (void)in_sizes; (void)n_in; (void)out_size; (void)ws_size;
  const float* q     = (const float*)d_in[0];
  const float* x     = (const float*)d_in[1];
  const float* Wq    = (const float*)d_in[2];
  const float* Wk    = (const float*)d_in[3];
  const float* Wv    = (const float*)d_in[4];
  const float* bv    = (const float*)d_in[5];
  const float* Wt    = (const float*)d_in[6];
  const float* bt    = (const float*)d_in[7];
  const float* gamma = (const float*)d_in[8];
  const float* beta  = (const float*)d_in[9];
  const float* rmean = (const float*)d_in[10];
  const float* rvar  = (const float*)d_in[11];
  float* out = (float*)d_out;

  // workspace (~196 MiB)
  const size_t SZ_qT = (size_t)KB_ * KN_ * KC_ * 2;   // 16 MiB
  const size_t SZ_xT = (size_t)KB_ * KN_ * KC2_ * 2;  //  8 MiB
  char* ws = (char*)d_ws;
  size_t off = 0;
  auto alloc = [&](size_t bytes) {
    char* p = ws + off;
    off += (bytes + 255) & ~(size_t)255;
    return p;
  };
  unsigned short* qThi = (unsigned short*)alloc(SZ_qT);
  unsigned short* qTlo = (unsigned short*)alloc(SZ_qT);
  unsigned short* xThi = (unsigned short*)alloc(SZ_xT);
  unsigned short* xTlo = (unsigned short*)alloc(SZ_xT);
  unsigned short* xqhi = (unsigned short*)alloc(SZ_xT);
  unsigned short* xqlo = (unsigned short*)alloc(SZ_xT);
  unsigned short* xkhi = (unsigned short*)alloc(SZ_xT);
  unsigned short* xklo = (unsigned short*)alloc(SZ_xT);
  unsigned short* x_v  = (unsigned short*)alloc((size_t)KB_ * KC2_ * KN_ * 2);
  unsigned short* tT   = (unsigned short*)alloc(SZ_xT);
  unsigned short* Wqhi = (unsigned short*)alloc((size_t)KC2_ * KC_ * 2);
  unsigned short* Wqlo = (unsigned short*)alloc((size_t)KC2_ * KC_ * 2);
  unsigned short* Wkhi = (unsigned short*)alloc((size_t)KC2_ * KC2_ * 2);
  unsigned short* Wklo = (unsigned short*)alloc((size_t)KC2_ * KC2_ * 2);
  unsigned short* Wvb  = (unsigned short*)alloc((size_t)KC2_ * KC_ * 2);
  unsigned short* Wtb  = (unsigned short*)alloc((size_t)KC2_ * KC2_ * 2);
  float* rsv     = (float*)alloc((size_t)KB_ * KN_ * 4);
  float* denom   = (float*)alloc((size_t)KB_ * KN_ * 4);
  float* rowpart = (float*)alloc((size_t)KB_ * KN_ * 32 * 4);
  float* P       = (float*)alloc((size_t)2 * KB_ * KC2_ * KN_ * 4);           // 32 MiB
  unsigned short* uT = (unsigned short*)alloc((size_t)KB_ * KN_ * KN_ * 2);   // 64 MiB

  dim3 blk(256);

  // weights -> bf16
  cvt_pair_kernel<<<dim3(KC2_ * KC_ / 1024), blk, 0, stream>>>(Wq, Wqhi, Wqlo, KC2_ * KC_);
  cvt_pair_kernel<<<dim3(KC2_ * KC2_ / 1024), blk, 0, stream>>>(Wk, Wkhi, Wklo, KC2_ * KC2_);
  cvt_kernel<<<dim3(KC2_ * KC_ / 1024), blk, 0, stream>>>(Wv, Wvb, KC2_ * KC_);
  cvt_kernel<<<dim3(KC2_ * KC2_ / 1024), blk, 0, stream>>>(Wt, Wtb, KC2_ * KC2_);

  // q^T, x^T fp32 -> hi/lo bf16 pairs (K contiguous)
  transpose_pair_kernel<<<dim3(KN_ / 64, KC_ / 64, KB_), blk, 0, stream>>>(
      q, (long)KC_ * KN_, qThi, qTlo, (long)KN_ * KC_, KC_, KN_);
  transpose_pair_kernel<<<dim3(KN_ / 64, KC2_ / 64, KB_), blk, 0, stream>>>(
      x, (long)KC2_ * KN_, xThi, xTlo, (long)KN_ * KC2_, KC2_, KN_);

  // x_q / x_kT projections (fp32-grade via segmented-K)
  proj2_kernel<<<dim3(512), blk, 0, stream>>>(qThi, qTlo, Wqhi, Wqlo, xqhi, xqlo,
                                              xThi, xTlo, Wkhi, Wklo, xkhi, xklo);

  // energy + exp + transpose + row partials (4-buffer, 48 MFMA/barrier)
  energy_kernel<<<dim3(KN_ / 128, KN_ / 128, KB_), blk, 0, stream>>>(
      xqhi, xqlo, xkhi, xklo, uT, rowpart);
  rowreduce_kernel<<<dim3(KB_ * KN_ / 256), blk, 0, stream>>>(rowpart, rsv);

  // x_v'[b][o][n] = (Wv[o][:].qT[n][:] + bv[o]) * rsv[b][n]
  EpiParams e3{}; e3.bias = bv; e3.scale = rsv; e3.scale_stride = KN_;
  gemm_one<EPI_VSCALE><<<dim3(KN_ / 128, KC2_ / 128, KB_), blk, 0, stream>>>(
      Wvb, nullptr, 0, KC_, 0, qThi, nullptr, (long)KN_ * KC_, KC_,
      x_v, nullptr, (long)KC2_ * KN_, KN_, KC_, e3);

  // denom[b][m] = sum_n uT[m][n] * rsv[n]
  denom_kernel<<<dim3(KN_ / 4, KB_), blk, 0, stream>>>(uT, rsv, denom);

  // x_r partials (split-K x2) then reduce + renorm + subtract + transpose -> tT
  xr_kernel<<<dim3(32, 2, 8), blk, 0, stream>>>(x_v, uT, P);
  xr_reduce_kernel<<<dim3(KN_ / 64, KC2_ / 64, KB_), blk, 0, stream>>>(P, x, denom, tT);

  // out[b][o][n] = relu(BN(Wt[o][:].tT[n][:] + bt[o])) + x[b][o][n]
  EpiParams e6{}; e6.bias = bt; e6.xf = x; e6.xf_stride = (long)KC2_ * KN_;
  e6.gamma = gamma; e6.beta = beta; e6.mean = rmean; e6.var = rvar;
  gemm_one<EPI_FINAL><<<dim3(KN_ / 128, KC2_ / 128, KB_), blk, 0, stream>>>(
      Wtb, nullptr, 0, KC2_, 0, tT, nullptr, (long)KN_ * KC2_, KC2_,
      out, nullptr, (long)KC2_ * KN_, KN_, KC2_, e6);
}

// Round 7
// 209.345 us; speedup vs baseline: 1.4534x; 1.1493x over previous
//
#include <hip/hip_runtime.h>
#include <cstdint>
#include <cstddef>

// Problem constants (B, C, N fixed by the reference)
#define KB_  8
#define KC_  512
#define KC2_ 256
#define KN_  2048

typedef __attribute__((ext_vector_type(8))) __bf16 bf16x8;
typedef __attribute__((ext_vector_type(8))) unsigned short u16x8;
typedef __attribute__((ext_vector_type(4))) float f32x4;

__device__ __forceinline__ unsigned short f2bf(float f) {
  union { float f; unsigned u; } x; x.f = f;
  unsigned r = x.u + 0x7fffu + ((x.u >> 16) & 1u);  // RNE (finite values only)
  return (unsigned short)(r >> 16);
}
__device__ __forceinline__ float bf2f(unsigned short h) {
  union { unsigned u; float f; } x; x.u = ((unsigned)h) << 16;
  return x.f;
}

// async global->LDS, 16B per lane; LDS dest = wave-uniform base + lane*16 (linear!)
#define GLD16(g, l) __builtin_amdgcn_global_load_lds( \
    (__attribute__((address_space(1))) void*)(g),     \
    (__attribute__((address_space(3))) void*)(l), 16, 0, 0)

// bijective XCD-aware block swizzle (nb % 8 == 0 for all our grids)
__device__ __forceinline__ void xcd_swizzle(int& bx, int& by, int& bz) {
  const int gx = gridDim.x, gy = gridDim.y;
  const int nb = gx * gy * (int)gridDim.z;
  int f = ((int)blockIdx.z * gy + (int)blockIdx.y) * gx + (int)blockIdx.x;
  if ((nb & 7) == 0) f = (f & 7) * (nb >> 3) + (f >> 3);
  const int gxy = gx * gy;
  bz = f / gxy; int rem = f - bz * gxy;
  by = rem / gx; bx = rem - by * gx;
}

// ---------------- weight fp32 -> bf16 convert (single) ----------------
__global__ __launch_bounds__(256) void cvt_kernel(const float* __restrict__ in,
                                                  unsigned short* __restrict__ out, int n) {
  int i = (blockIdx.x * 256 + threadIdx.x) * 4;
  if (i >= n) return;
  float4 f = *(const float4*)(in + i);
  ushort4 u = { f2bf(f.x), f2bf(f.y), f2bf(f.z), f2bf(f.w) };
  *(ushort4*)(out + i) = u;
}

// ---------------- weight fp32 -> bf16 hi/lo pair ----------------
__global__ __launch_bounds__(256) void cvt_pair_kernel(const float* __restrict__ in,
                                                       unsigned short* __restrict__ hi,
                                                       unsigned short* __restrict__ lo, int n) {
  int i = (blockIdx.x * 256 + threadIdx.x) * 4;
  if (i >= n) return;
  float4 f = *(const float4*)(in + i);
  ushort4 h = { f2bf(f.x), f2bf(f.y), f2bf(f.z), f2bf(f.w) };
  ushort4 l = { f2bf(f.x - bf2f(h.x)), f2bf(f.y - bf2f(h.y)),
                f2bf(f.z - bf2f(h.z)), f2bf(f.w - bf2f(h.w)) };
  *(ushort4*)(hi + i) = h;
  *(ushort4*)(lo + i) = l;
}

// ---------------- tiled transpose: fp32 [R][Cc] -> bf16 hi/lo [Cc][R] ----------------
__global__ __launch_bounds__(256) void transpose_pair_kernel(const float* __restrict__ in,
                                                             long sIn,
                                                             unsigned short* __restrict__ hi,
                                                             unsigned short* __restrict__ lo,
                                                             long sOut, int R, int Cc) {
  int b = blockIdx.z;
  const float* I = in + (size_t)b * sIn;
  __shared__ float tile[64][65];
  int t = threadIdx.x;
  int r0 = blockIdx.y * 64, c0 = blockIdx.x * 64;
#pragma unroll
  for (int k = 0; k < 4; k++) {
    int vi = k * 256 + t, rr = vi >> 4, cv = vi & 15;
    float4 f = *(const float4*)&I[(size_t)(r0 + rr) * Cc + c0 + cv * 4];
    tile[rr][cv * 4 + 0] = f.x; tile[rr][cv * 4 + 1] = f.y;
    tile[rr][cv * 4 + 2] = f.z; tile[rr][cv * 4 + 3] = f.w;
  }
  __syncthreads();
#pragma unroll
  for (int k = 0; k < 4; k++) {
    int vi = k * 256 + t, cc = vi >> 4, rv = vi & 15;
    float f0 = tile[rv * 4 + 0][cc], f1 = tile[rv * 4 + 1][cc];
    float f2 = tile[rv * 4 + 2][cc], f3 = tile[rv * 4 + 3][cc];
    ushort4 h = { f2bf(f0), f2bf(f1), f2bf(f2), f2bf(f3) };
    ushort4 l = { f2bf(f0 - bf2f(h.x)), f2bf(f1 - bf2f(h.y)),
                  f2bf(f2 - bf2f(h.z)), f2bf(f3 - bf2f(h.w)) };
    size_t o = (size_t)b * sOut + (size_t)(c0 + cc) * R + r0 + rv * 4;
    *(ushort4*)&hi[o] = h;
    *(ushort4*)&lo[o] = l;
  }
}

// ---------------- rsv[b][n] = 1 / sum_k rowpart[b][n][k] ----------------
__global__ __launch_bounds__(256) void rowreduce_kernel(const float* __restrict__ rowpart,
                                                        float* __restrict__ rsv) {
  int idx = blockIdx.x * 256 + threadIdx.x;  // 8*2048 rows
  const float* p = rowpart + (size_t)idx * 32;
  float s = 0.f;
#pragma unroll
  for (int k = 0; k < 32; k++) s += p[k];
  rsv[idx] = 1.0f / s;
}

// ---------------- denom[b][m] = sum_n uT[b][m][n] * rsv[b][n] ----------------
__global__ __launch_bounds__(256) void denom_kernel(const unsigned short* __restrict__ uT,
                                                    const float* __restrict__ rsv,
                                                    float* __restrict__ denom) {
  int b = blockIdx.y;
  int m = blockIdx.x * 4 + (threadIdx.x >> 6);
  int lane = threadIdx.x & 63;
  const unsigned short* U = uT + ((size_t)b * KN_ + m) * KN_;
  const float* R = rsv + (size_t)b * KN_;
  float s = 0.f;
#pragma unroll
  for (int c = 0; c < 4; c++) {
    int n = c * 512 + lane * 8;
    u16x8 u = *(const u16x8*)&U[n];
    float4 r0 = *(const float4*)&R[n];
    float4 r1 = *(const float4*)&R[n + 4];
    s += bf2f(u[0]) * r0.x + bf2f(u[1]) * r0.y + bf2f(u[2]) * r0.z + bf2f(u[3]) * r0.w;
    s += bf2f(u[4]) * r1.x + bf2f(u[5]) * r1.y + bf2f(u[6]) * r1.z + bf2f(u[7]) * r1.w;
  }
#pragma unroll
  for (int o = 32; o > 0; o >>= 1) s += __shfl_xor(s, o, 64);
  if (lane == 0) denom[(size_t)b * KN_ + m] = s;
}

// ---------------- energy kernel: 2-phase dbuf split-GEMM + exp + transpose + row-partials ----
// E[n][m] = (ah+al).(bh+bl) ~ ah.bh + al.bh + ah.bl ; u = exp(E-40);
// writes uT[b][m][n] (bf16, coalesced 256B bursts) and rowpart[b][n][32].
__global__ __launch_bounds__(256) void energy_kernel(
    const unsigned short* __restrict__ Ahi, const unsigned short* __restrict__ Alo,
    const unsigned short* __restrict__ Bhi, const unsigned short* __restrict__ Blo,
    unsigned short* __restrict__ uT, float* __restrict__ rowpart) {
  int bx, by, b;
  xcd_swizzle(bx, by, b);  // grid (16,16,8): each XCD owns one batch
  Ahi += (size_t)b * KN_ * KC2_; Alo += (size_t)b * KN_ * KC2_;
  Bhi += (size_t)b * KN_ * KC2_; Blo += (size_t)b * KN_ * KC2_;
  const int m0 = by * 128;  // rows = n (query idx)
  const int n0 = bx * 128;  // cols = m (key idx)
  __shared__ __align__(16) char smem[65536];  // 2 phases x 32KB; phase0 reused for transpose
  const int t = threadIdx.x, lane = t & 63, w = t >> 6;
  const int wr = w >> 1, wc = w & 1;
  const int srow = t >> 2;
  const int scol = (((t & 3) ^ ((srow >> 1) & 3)) * 8);   // pre-swizzled k-chunk
  const int lr = lane & 15, lk = (lane >> 4) * 8;
  const int rsw = ((lr >> 1) & 3) << 4;                   // read-side XOR (bytes)

  auto STAGE = [&](char* dst, int kt) {
    const size_t ga = (size_t)(m0 + srow) * KC2_ + kt + scol;
    const size_t gb = (size_t)(n0 + srow) * KC2_ + kt + scol;
    GLD16(Ahi + ga, dst + 0 + w * 1024);
    GLD16(Ahi + ga + (size_t)64 * KC2_, dst + 4096 + w * 1024);
    GLD16(Alo + ga, dst + 8192 + w * 1024);
    GLD16(Alo + ga + (size_t)64 * KC2_, dst + 12288 + w * 1024);
    GLD16(Bhi + gb, dst + 16384 + w * 1024);
    GLD16(Bhi + gb + (size_t)64 * KC2_, dst + 20480 + w * 1024);
    GLD16(Blo + gb, dst + 24576 + w * 1024);
    GLD16(Blo + gb + (size_t)64 * KC2_, dst + 28672 + w * 1024);
  };

  f32x4 acc[4][4];
  const f32x4 z = {0.f, 0.f, 0.f, 0.f};
#pragma unroll
  for (int i = 0; i < 4; i++)
#pragma unroll
    for (int j = 0; j < 4; j++) acc[i][j] = z;

  STAGE(smem, 0);
  __syncthreads();
  for (int kt8 = 0; kt8 < 8; kt8++) {
    char* cur = smem + (kt8 & 1) * 32768;
    char* nxt = smem + ((kt8 & 1) ^ 1) * 32768;
    if (kt8 < 7) STAGE(nxt, (kt8 + 1) * 32);  // loads fly under this tile's MFMAs
    bf16x8 ah[4], al[4], bh[4], bl[4];
#pragma unroll
    for (int i = 0; i < 4; i++) {
      int ro = (wr * 64 + i * 16 + lr) * 64 + ((lk * 2) ^ rsw);
      ah[i] = *(const bf16x8*)(cur + 0 + ro);
      al[i] = *(const bf16x8*)(cur + 8192 + ro);
    }
#pragma unroll
    for (int j = 0; j < 4; j++) {
      int ro = (wc * 64 + j * 16 + lr) * 64 + ((lk * 2) ^ rsw);
      bh[j] = *(const bf16x8*)(cur + 16384 + ro);
      bl[j] = *(const bf16x8*)(cur + 24576 + ro);
    }
#pragma unroll
    for (int i = 0; i < 4; i++)
#pragma unroll
      for (int j = 0; j < 4; j++) {
        acc[i][j] = __builtin_amdgcn_mfma_f32_16x16x32_bf16(al[i], bh[j], acc[i][j], 0, 0, 0);
        acc[i][j] = __builtin_amdgcn_mfma_f32_16x16x32_bf16(ah[i], bl[j], acc[i][j], 0, 0, 0);
        acc[i][j] = __builtin_amdgcn_mfma_f32_16x16x32_bf16(ah[i], bh[j], acc[i][j], 0, 0, 0);
      }
    __syncthreads();  // drains next-stage vmcnt + this tile's lgkm + barrier
  }

  // ---- u = exp(E - 40) ----
#pragma unroll
  for (int i = 0; i < 4; i++)
#pragma unroll
    for (int j = 0; j < 4; j++)
#pragma unroll
      for (int r = 0; r < 4; r++) acc[i][j][r] = __expf(acc[i][j][r] - 40.f);

  // ---- partial row sums ----
#pragma unroll
  for (int i = 0; i < 4; i++) {
#pragma unroll
    for (int r = 0; r < 4; r++) {
      float s = acc[i][0][r] + acc[i][1][r] + acc[i][2][r] + acc[i][3][r];
      s += __shfl_xor(s, 1, 64); s += __shfl_xor(s, 2, 64);
      s += __shfl_xor(s, 4, 64); s += __shfl_xor(s, 8, 64);
      if ((lane & 15) == 0) {
        int row = m0 + wr * 64 + i * 16 + ((lane >> 4) << 2) + r;
        rowpart[((size_t)b * KN_ + row) * 32 + bx * 2 + wc] = s;
      }
    }
  }

  // ---- transpose to uT via LDS (XOR-swizzled banks) ----
  // write: byte (km*256 + qn*2) ^ ((km&15)<<4), km = local key idx, qn = local query idx
#pragma unroll
  for (int i = 0; i < 4; i++) {
#pragma unroll
    for (int j = 0; j < 4; j++) {
#pragma unroll
      for (int r2 = 0; r2 < 4; r2 += 2) {
        int qn = wr * 64 + i * 16 + ((lane >> 4) << 2) + r2;
        int km = wc * 64 + j * 16 + lr;
        unsigned pk = (unsigned)f2bf(acc[i][j][r2]) |
                      ((unsigned)f2bf(acc[i][j][r2 + 1]) << 16);
        int a = ((km << 8) + (qn << 1)) ^ ((km & 15) << 4);
        *(unsigned*)(smem + a) = pk;
      }
    }
  }
  __syncthreads();
  // read 16B per lane, 16 lanes cooperate per uT row -> 256B coalesced bursts
#pragma unroll
  for (int it = 0; it < 8; it++) {
    int km = (t >> 4) + it * 16, chunk = t & 15;
    int a = ((km << 8) + (chunk << 4)) ^ ((km & 15) << 4);
    size_t g = ((size_t)b * KN_ + (n0 + km)) * KN_ + m0 + chunk * 8;
    *(bf16x8*)&uT[g] = *(const bf16x8*)(smem + a);
  }
}

// ---------------- epilogue variants ----------------
enum { EPI_PAIR = 0, EPI_VSCALE = 2, EPI_PART = 3, EPI_FINAL = 4 };

struct EpiParams {
  const float* bias;
  const float* xf;  long xf_stride;
  const float* scale; long scale_stride;
  const float* gamma; const float* beta; const float* mean; const float* var;
};

// ============== unified MFMA GEMM core, 128x128 tile, BK=64, 2-phase dbuf,
// segmented-K: if seg>0 (K = 3*seg): A' = [A0|A1|A0], B' = [B0|B0|B1]. ==============
template<int EPI>
__device__ __forceinline__ void gemm_core(
    char* __restrict__ smem, int bx, int by, int b,
    const unsigned short* __restrict__ A0, const unsigned short* __restrict__ A1,
    long sA, int lda, int seg,
    const unsigned short* __restrict__ B0, const unsigned short* __restrict__ B1,
    long sB, int ldb,
    void* __restrict__ Cv, void* __restrict__ Cv2, long sC, int ldc, int K,
    const EpiParams& ep) {
  A0 += (size_t)b * sA; A1 += (size_t)b * sA;
  B0 += (size_t)b * sB; B1 += (size_t)b * sB;
  const int m0 = by * 128, n0 = bx * 128;
  const int t = threadIdx.x, lane = t & 63, w = t >> 6;
  const int wr = w >> 1, wc = w & 1;
  const int srow = t >> 2;
  const int scol = (((t & 3) ^ ((srow >> 1) & 3)) * 8);   // pre-swizzled k-chunk
  const int lr = lane & 15, lk = (lane >> 4) * 8;
  const int rsw = ((lr >> 1) & 3) << 4;                   // read-side XOR (bytes)

  auto STAGE = [&](char* dst, int kt) {
    int s = seg ? ((kt >= seg) + (kt >= 2 * seg)) : 0;
    int kl = kt - s * seg;
    const unsigned short* Ab = (s == 1) ? A1 : A0;
    const unsigned short* Bb = (s == 2) ? B1 : B0;
    const unsigned short* gA = Ab + (size_t)(m0 + srow) * lda + kl + scol;
    const unsigned short* gB = Bb + (size_t)(n0 + srow) * ldb + kl + scol;
    GLD16(gA, dst + w * 1024);                         // A k0
    GLD16(gA + (size_t)64 * lda, dst + 4096 + w * 1024);
    GLD16(gA + 32, dst + 8192 + w * 1024);             // A k1
    GLD16(gA + (size_t)64 * lda + 32, dst + 12288 + w * 1024);
    GLD16(gB, dst + 16384 + w * 1024);                 // B k0
    GLD16(gB + (size_t)64 * ldb, dst + 20480 + w * 1024);
    GLD16(gB + 32, dst + 24576 + w * 1024);            // B k1
    GLD16(gB + (size_t)64 * ldb + 32, dst + 28672 + w * 1024);
  };

  f32x4 acc[4][4];
  const f32x4 z = {0.f, 0.f, 0.f, 0.f};
#pragma unroll
  for (int i = 0; i < 4; i++)
#pragma unroll
    for (int j = 0; j < 4; j++) acc[i][j] = z;

  const int nt = K >> 6;
  STAGE(smem, 0);
  __syncthreads();
  for (int t8 = 0; t8 < nt; t8++) {
    char* cur = smem + (t8 & 1) * 32768;
    char* nxt = smem + ((t8 & 1) ^ 1) * 32768;
    if (t8 < nt - 1) STAGE(nxt, (t8 + 1) * 64);
#pragma unroll
    for (int kk = 0; kk < 2; kk++) {
      bf16x8 af[4], bfv[4];
#pragma unroll
      for (int i = 0; i < 4; i++)
        af[i] = *(const bf16x8*)(cur + kk * 8192 +
                                 (wr * 64 + i * 16 + lr) * 64 + ((lk * 2) ^ rsw));
#pragma unroll
      for (int j = 0; j < 4; j++)
        bfv[j] = *(const bf16x8*)(cur + 16384 + kk * 8192 +
                                  (wc * 64 + j * 16 + lr) * 64 + ((lk * 2) ^ rsw));
#pragma unroll
      for (int i = 0; i < 4; i++)
#pragma unroll
        for (int j = 0; j < 4; j++)
          acc[i][j] = __builtin_amdgcn_mfma_f32_16x16x32_bf16(af[i], bfv[j], acc[i][j], 0, 0, 0);
    }
    __syncthreads();
  }

#pragma unroll
  for (int i = 0; i < 4; i++) {
#pragma unroll
    for (int r = 0; r < 4; r++) {
      const int row = m0 + wr * 64 + i * 16 + ((lane >> 4) << 2) + r;
      float pbias = 0.f, pinv = 1.f, padd = 0.f;
      if constexpr (EPI == EPI_VSCALE) pbias = ep.bias[row];
      if constexpr (EPI == EPI_FINAL) {
        pbias = ep.bias[row];
        float iv = ep.gamma[row] * rsqrtf(ep.var[row] + 1e-5f);
        pinv = iv;
        padd = ep.beta[row] - ep.mean[row] * iv;
      }
#pragma unroll
      for (int j = 0; j < 4; j++) {
        const int col = n0 + wc * 64 + j * 16 + lr;
        float v = acc[i][j][r];
        size_t o = (size_t)b * sC + (size_t)row * ldc + col;
        if constexpr (EPI == EPI_PAIR) {
          unsigned short h = f2bf(v);
          ((unsigned short*)Cv)[o] = h;
          ((unsigned short*)Cv2)[o] = f2bf(v - bf2f(h));
        } else if constexpr (EPI == EPI_VSCALE) {
          float sc = ep.scale[(size_t)b * ep.scale_stride + col];
          ((unsigned short*)Cv)[o] = f2bf((v + pbias) * sc);
        } else if constexpr (EPI == EPI_PART) {
          ((float*)Cv)[o] = v;
        } else {  // EPI_FINAL
          float h = (v + pbias) * pinv + padd;
          h = fmaxf(h, 0.f);
          float xval = ep.xf[(size_t)b * ep.xf_stride + o - (size_t)b * sC];
          ((float*)Cv)[o] = h + xval;
        }
      }
    }
  }
}

// generic single-GEMM kernel (64 KB LDS, 2-phase)
template<int EPI>
__global__ __launch_bounds__(256) void gemm_one(
    const unsigned short* __restrict__ A0, const unsigned short* __restrict__ A1,
    long sA, int lda, int seg,
    const unsigned short* __restrict__ B0, const unsigned short* __restrict__ B1,
    long sB, int ldb,
    void* __restrict__ Cv, void* __restrict__ Cv2, long sC, int ldc, int K,
    EpiParams ep) {
  __shared__ __align__(16) char smem[65536];
  int bx, by, b;
  xcd_swizzle(bx, by, b);
  gemm_core<EPI>(smem, bx, by, b, A0, A1, sA, lda, seg, B0, B1, sB, ldb,
                 Cv, Cv2, sC, ldc, K, ep);
}

// fused x_q + x_k projections: one 512-block launch
__global__ __launch_bounds__(256) void proj2_kernel(
    const unsigned short* __restrict__ qThi, const unsigned short* __restrict__ qTlo,
    const unsigned short* __restrict__ Wqhi, const unsigned short* __restrict__ Wqlo,
    unsigned short* __restrict__ xqhi, unsigned short* __restrict__ xqlo,
    const unsigned short* __restrict__ xThi, const unsigned short* __restrict__ xTlo,
    const unsigned short* __restrict__ Wkhi, const unsigned short* __restrict__ Wklo,
    unsigned short* __restrict__ xkhi, unsigned short* __restrict__ xklo) {
  __shared__ __align__(16) char smem[65536];
  int f = (int)blockIdx.x;
  f = (f & 7) * 64 + (f >> 3);  // XCD swizzle over 512
  EpiParams ep{};
  if (f < 256) {
    int bx = f & 1, by = (f >> 1) & 15, b = f >> 5;
    gemm_core<EPI_PAIR>(smem, bx, by, b, qThi, qTlo, (long)KN_ * KC_, KC_, KC_,
                        Wqhi, Wqlo, 0, KC_, xqhi, xqlo, (long)KN_ * KC2_, KC2_,
                        3 * KC_, ep);
  } else {
    int g = f - 256;
    int bx = g & 1, by = (g >> 1) & 15, b = g >> 5;
    gemm_core<EPI_PAIR>(smem, bx, by, b, xThi, xTlo, (long)KN_ * KC2_, KC2_, KC2_,
                        Wkhi, Wklo, 0, KC2_, xkhi, xklo, (long)KN_ * KC2_, KC2_,
                        3 * KC2_, ep);
  }
}

// XR partial GEMM: split-K x2 (grid (32,2,8))
__global__ __launch_bounds__(256) void xr_kernel(
    const unsigned short* __restrict__ x_v, const unsigned short* __restrict__ uT,
    float* __restrict__ P) {
  __shared__ __align__(16) char smem[65536];
  int bx, by, b;
  xcd_swizzle(bx, by, b);
  int split = bx >> 4; bx &= 15;
  EpiParams ep{};
  gemm_core<EPI_PART>(smem, bx, by, b,
                      x_v + split * (KN_ / 2), nullptr, (long)KC2_ * KN_, KN_, 0,
                      uT + split * (KN_ / 2), nullptr, (long)KN_ * KN_, KN_,
                      P + (size_t)split * KB_ * KC2_ * KN_, nullptr,
                      (long)KC2_ * KN_, KN_, KN_ / 2, ep);
}

// reduce split-K partials + renorm + residual-subtract + transpose -> tT[m][c]
__global__ __launch_bounds__(256) void xr_reduce_kernel(
    const float* __restrict__ P, const float* __restrict__ x,
    const float* __restrict__ denom, unsigned short* __restrict__ tT) {
  int b = blockIdx.z;
  const float* P0 = P + (size_t)b * KC2_ * KN_;
  const float* P1 = P0 + (size_t)KB_ * KC2_ * KN_;
  const float* X  = x + (size_t)b * KC2_ * KN_;
  const float* D  = denom + (size_t)b * KN_;
  __shared__ unsigned short tile[64][72];
  int t = threadIdx.x;
  int c0 = blockIdx.y * 64, m0 = blockIdx.x * 64;  // rows = c, cols = m
#pragma unroll
  for (int k = 0; k < 4; k++) {
    int vi = k * 256 + t, rr = vi >> 4, cv = vi & 15;
    size_t o = (size_t)(c0 + rr) * KN_ + m0 + cv * 4;
    float4 p0 = *(const float4*)&P0[o];
    float4 p1 = *(const float4*)&P1[o];
    float4 xv = *(const float4*)&X[o];
    float4 dv = *(const float4*)&D[m0 + cv * 4];
    tile[rr][cv * 4 + 0] = f2bf(xv.x - (p0.x + p1.x) / (1e-9f + dv.x));
    tile[rr][cv * 4 + 1] = f2bf(xv.y - (p0.y + p1.y) / (1e-9f + dv.y));
    tile[rr][cv * 4 + 2] = f2bf(xv.z - (p0.z + p1.z) / (1e-9f + dv.z));
    tile[rr][cv * 4 + 3] = f2bf(xv.w - (p0.w + p1.w) / (1e-9f + dv.w));
  }
  __syncthreads();
#pragma unroll
  for (int k = 0; k < 4; k++) {
    int vi = k * 256 + t, cc = vi >> 4, rv = vi & 15;
    ushort4 u = { tile[rv * 4 + 0][cc], tile[rv * 4 + 1][cc],
                  tile[rv * 4 + 2][cc], tile[rv * 4 + 3][cc] };
    *(ushort4*)&tT[(size_t)b * KN_ * KC2_ + (size_t)(m0 + cc) * KC2_ + c0 + rv * 4] = u;
  }
}

// ---------------- launcher ----------------
extern "C" void kernel_launch(void* const* d_in, const int* in_sizes, int n_in,
                              void* d_out, int out_size, void* d_ws, size_t ws_size,
                              hipStream_t stream) {
  (void)in_sizes; (void)n_in; (void)out_size; (void)ws_size;
  const float* q     = (const float*)d_in[0];
  const float* x     = (const float*)d_in[1];
  const float* Wq    = (const float*)d_in[2];
  const float* Wk    = (const float*)d_in[3];
  const float* Wv    = (const float*)d_in[4];
  const float* bv    = (const float*)d_in[5];
  const float* Wt    = (const float*)d_in[6];
  const float* bt    = (const float*)d_in[7];
  const float* gamma = (const float*)d_in[8];
  const float* beta  = (const float*)d_in[9];
  const float* rmean = (const float*)d_in[10];
  const float* rvar  = (const float*)d_in[11];
  float* out = (float*)d_out;

  // workspace (~196 MiB)
  const size_t SZ_qT = (size_t)KB_ * KN_ * KC_ * 2;   // 16 MiB
  const size_t SZ_xT = (size_t)KB_ * KN_ * KC2_ * 2;  //  8 MiB
  char* ws = (char*)d_ws;
  size_t off = 0;
  auto alloc = [&](size_t bytes) {
    char* p = ws + off;
    off += (bytes + 255) & ~(size_t)255;
    return p;
  };
  unsigned short* qThi = (unsigned short*)alloc(SZ_qT);
  unsigned short* qTlo = (unsigned short*)alloc(SZ_qT);
  unsigned short* xThi = (unsigned short*)alloc(SZ_xT);
  unsigned short* xTlo = (unsigned short*)alloc(SZ_xT);
  unsigned short* xqhi = (unsigned short*)alloc(SZ_xT);
  unsigned short* xqlo = (unsigned short*)alloc(SZ_xT);
  unsigned short* xkhi = (unsigned short*)alloc(SZ_xT);
  unsigned short* xklo = (unsigned short*)alloc(SZ_xT);
  unsigned short* x_v  = (unsigned short*)alloc((size_t)KB_ * KC2_ * KN_ * 2);
  unsigned short* tT   = (unsigned short*)alloc(SZ_xT);
  unsigned short* Wqhi = (unsigned short*)alloc((size_t)KC2_ * KC_ * 2);
  unsigned short* Wqlo = (unsigned short*)alloc((size_t)KC2_ * KC_ * 2);
  unsigned short* Wkhi = (unsigned short*)alloc((size_t)KC2_ * KC2_ * 2);
  unsigned short* Wklo = (unsigned short*)alloc((size_t)KC2_ * KC2_ * 2);
  unsigned short* Wvb  = (unsigned short*)alloc((size_t)KC2_ * KC_ * 2);
  unsigned short* Wtb  = (unsigned short*)alloc((size_t)KC2_ * KC2_ * 2);
  float* rsv     = (float*)alloc((size_t)KB_ * KN_ * 4);
  float* denom   = (float*)alloc((size_t)KB_ * KN_ * 4);
  float* rowpart = (float*)alloc((size_t)KB_ * KN_ * 32 * 4);
  float* P       = (float*)alloc((size_t)2 * KB_ * KC2_ * KN_ * 4);           // 32 MiB
  unsigned short* uT = (unsigned short*)alloc((size_t)KB_ * KN_ * KN_ * 2);   // 64 MiB

  dim3 blk(256);

  // weights -> bf16
  cvt_pair_kernel<<<dim3(KC2_ * KC_ / 1024), blk, 0, stream>>>(Wq, Wqhi, Wqlo, KC2_ * KC_);
  cvt_pair_kernel<<<dim3(KC2_ * KC2_ / 1024), blk, 0, stream>>>(Wk, Wkhi, Wklo, KC2_ * KC2_);
  cvt_kernel<<<dim3(KC2_ * KC_ / 1024), blk, 0, stream>>>(Wv, Wvb, KC2_ * KC_);
  cvt_kernel<<<dim3(KC2_ * KC2_ / 1024), blk, 0, stream>>>(Wt, Wtb, KC2_ * KC2_);

  // q^T, x^T fp32 -> hi/lo bf16 pairs (K contiguous)
  transpose_pair_kernel<<<dim3(KN_ / 64, KC_ / 64, KB_), blk, 0, stream>>>(
      q, (long)KC_ * KN_, qThi, qTlo, (long)KN_ * KC_, KC_, KN_);
  transpose_pair_kernel<<<dim3(KN_ / 64, KC2_ / 64, KB_), blk, 0, stream>>>(
      x, (long)KC2_ * KN_, xThi, xTlo, (long)KN_ * KC2_, KC2_, KN_);

  // x_q / x_kT projections (fp32-grade via segmented-K)
  proj2_kernel<<<dim3(512), blk, 0, stream>>>(qThi, qTlo, Wqhi, Wqlo, xqhi, xqlo,
                                              xThi, xTlo, Wkhi, Wklo, xkhi, xklo);

  // energy + exp + transpose + row partials (2-phase dbuf)
  energy_kernel<<<dim3(KN_ / 128, KN_ / 128, KB_), blk, 0, stream>>>(
      xqhi, xqlo, xkhi, xklo, uT, rowpart);
  rowreduce_kernel<<<dim3(KB_ * KN_ / 256), blk, 0, stream>>>(rowpart, rsv);

  // x_v'[b][o][n] = (Wv[o][:].qT[n][:] + bv[o]) * rsv[b][n]
  EpiParams e3{}; e3.bias = bv; e3.scale = rsv; e3.scale_stride = KN_;
  gemm_one<EPI_VSCALE><<<dim3(KN_ / 128, KC2_ / 128, KB_), blk, 0, stream>>>(
      Wvb, nullptr, 0, KC_, 0, qThi, nullptr, (long)KN_ * KC_, KC_,
      x_v, nullptr, (long)KC2_ * KN_, KN_, KC_, e3);

  // denom[b][m] = sum_n uT[m][n] * rsv[n]
  denom_kernel<<<dim3(KN_ / 4, KB_), blk, 0, stream>>>(uT, rsv, denom);

  // x_r partials (split-K x2) then reduce + renorm + subtract + transpose -> tT
  xr_kernel<<<dim3(32, 2, 8), blk, 0, stream>>>(x_v, uT, P);
  xr_reduce_kernel<<<dim3(KN_ / 64, KC2_ / 64, KB_), blk, 0, stream>>>(P, x, denom, tT);

  // out[b][o][n] = relu(BN(Wt[o][:].tT[n][:] + bt[o])) + x[b][o][n]
  EpiParams e6{}; e6.bias = bt; e6.xf = x; e6.xf_stride = (long)KC2_ * KN_;
  e6.gamma = gamma; e6.beta = beta; e6.mean = rmean; e6.var = rvar;
  gemm_one<EPI_FINAL><<<dim3(KN_ / 128, KC2_ / 128, KB_), blk, 0, stream>>>(
      Wtb, nullptr, 0, KC2_, 0, tT, nullptr, (long)KN_ * KC2_, KC2_,
      out, nullptr, (long)KC2_ * KN_, KN_, KC2_, e6);
}

// Round 8
// 207.206 us; speedup vs baseline: 1.4684x; 1.0103x over previous
//
#include <hip/hip_runtime.h>
#include <cstdint>
#include <cstddef>

// Problem constants (B, C, N fixed by the reference)
#define KB_  8
#define KC_  512
#define KC2_ 256
#define KN_  2048

typedef __attribute__((ext_vector_type(8))) __bf16 bf16x8;
typedef __attribute__((ext_vector_type(8))) unsigned short u16x8;
typedef __attribute__((ext_vector_type(4))) float f32x4;

__device__ __forceinline__ unsigned short f2bf(float f) {
  union { float f; unsigned u; } x; x.f = f;
  unsigned r = x.u + 0x7fffu + ((x.u >> 16) & 1u);  // RNE (finite values only)
  return (unsigned short)(r >> 16);
}
__device__ __forceinline__ float bf2f(unsigned short h) {
  union { unsigned u; float f; } x; x.u = ((unsigned)h) << 16;
  return x.f;
}

// async global->LDS, 16B per lane; LDS dest = wave-uniform base + lane*16 (linear!)
#define GLD16(g, l) __builtin_amdgcn_global_load_lds( \
    (__attribute__((address_space(1))) void*)(g),     \
    (__attribute__((address_space(3))) void*)(l), 16, 0, 0)

// counted-vmcnt barrier pair (T4): wait only the CURRENT buffer's 8 loads;
// next-tile loads stay in flight across the barrier.
#define WAIT_VM8()  asm volatile("s_waitcnt vmcnt(8)" ::: "memory")
#define WAIT_VM0()  asm volatile("s_waitcnt vmcnt(0)" ::: "memory")
#define BARRIER()   __builtin_amdgcn_s_barrier()

// bijective XCD-aware block swizzle (nb % 8 == 0 for all our grids)
__device__ __forceinline__ void xcd_swizzle(int& bx, int& by, int& bz) {
  const int gx = gridDim.x, gy = gridDim.y;
  const int nb = gx * gy * (int)gridDim.z;
  int f = ((int)blockIdx.z * gy + (int)blockIdx.y) * gx + (int)blockIdx.x;
  if ((nb & 7) == 0) f = (f & 7) * (nb >> 3) + (f >> 3);
  const int gxy = gx * gy;
  bz = f / gxy; int rem = f - bz * gxy;
  by = rem / gx; bx = rem - by * gx;
}

// ---------------- weight fp32 -> bf16 convert (single) ----------------
__global__ __launch_bounds__(256) void cvt_kernel(const float* __restrict__ in,
                                                  unsigned short* __restrict__ out, int n) {
  int i = (blockIdx.x * 256 + threadIdx.x) * 4;
  if (i >= n) return;
  float4 f = *(const float4*)(in + i);
  ushort4 u = { f2bf(f.x), f2bf(f.y), f2bf(f.z), f2bf(f.w) };
  *(ushort4*)(out + i) = u;
}

// ---------------- weight fp32 -> bf16 hi/lo pair ----------------
__global__ __launch_bounds__(256) void cvt_pair_kernel(const float* __restrict__ in,
                                                       unsigned short* __restrict__ hi,
                                                       unsigned short* __restrict__ lo, int n) {
  int i = (blockIdx.x * 256 + threadIdx.x) * 4;
  if (i >= n) return;
  float4 f = *(const float4*)(in + i);
  ushort4 h = { f2bf(f.x), f2bf(f.y), f2bf(f.z), f2bf(f.w) };
  ushort4 l = { f2bf(f.x - bf2f(h.x)), f2bf(f.y - bf2f(h.y)),
                f2bf(f.z - bf2f(h.z)), f2bf(f.w - bf2f(h.w)) };
  *(ushort4*)(hi + i) = h;
  *(ushort4*)(lo + i) = l;
}

// ---------------- tiled transpose: fp32 [R][Cc] -> bf16 hi/lo [Cc][R] ----------------
__global__ __launch_bounds__(256) void transpose_pair_kernel(const float* __restrict__ in,
                                                             long sIn,
                                                             unsigned short* __restrict__ hi,
                                                             unsigned short* __restrict__ lo,
                                                             long sOut, int R, int Cc) {
  int b = blockIdx.z;
  const float* I = in + (size_t)b * sIn;
  __shared__ float tile[64][65];
  int t = threadIdx.x;
  int r0 = blockIdx.y * 64, c0 = blockIdx.x * 64;
#pragma unroll
  for (int k = 0; k < 4; k++) {
    int vi = k * 256 + t, rr = vi >> 4, cv = vi & 15;
    float4 f = *(const float4*)&I[(size_t)(r0 + rr) * Cc + c0 + cv * 4];
    tile[rr][cv * 4 + 0] = f.x; tile[rr][cv * 4 + 1] = f.y;
    tile[rr][cv * 4 + 2] = f.z; tile[rr][cv * 4 + 3] = f.w;
  }
  __syncthreads();
#pragma unroll
  for (int k = 0; k < 4; k++) {
    int vi = k * 256 + t, cc = vi >> 4, rv = vi & 15;
    float f0 = tile[rv * 4 + 0][cc], f1 = tile[rv * 4 + 1][cc];
    float f2 = tile[rv * 4 + 2][cc], f3 = tile[rv * 4 + 3][cc];
    ushort4 h = { f2bf(f0), f2bf(f1), f2bf(f2), f2bf(f3) };
    ushort4 l = { f2bf(f0 - bf2f(h.x)), f2bf(f1 - bf2f(h.y)),
                  f2bf(f2 - bf2f(h.z)), f2bf(f3 - bf2f(h.w)) };
    size_t o = (size_t)b * sOut + (size_t)(c0 + cc) * R + r0 + rv * 4;
    *(ushort4*)&hi[o] = h;
    *(ushort4*)&lo[o] = l;
  }
}

// ---------------- rsv[b][n] = 1 / sum_k rowpart[b][n][k] ----------------
__global__ __launch_bounds__(256) void rowreduce_kernel(const float* __restrict__ rowpart,
                                                        float* __restrict__ rsv) {
  int idx = blockIdx.x * 256 + threadIdx.x;  // 8*2048 rows
  const float* p = rowpart + (size_t)idx * 32;
  float s = 0.f;
#pragma unroll
  for (int k = 0; k < 32; k++) s += p[k];
  rsv[idx] = 1.0f / s;
}

// ---------------- denom[b][m] = sum_n uT[b][m][n] * rsv[b][n] ----------------
__global__ __launch_bounds__(256) void denom_kernel(const unsigned short* __restrict__ uT,
                                                    const float* __restrict__ rsv,
                                                    float* __restrict__ denom) {
  int b = blockIdx.y;
  int m = blockIdx.x * 4 + (threadIdx.x >> 6);
  int lane = threadIdx.x & 63;
  const unsigned short* U = uT + ((size_t)b * KN_ + m) * KN_;
  const float* R = rsv + (size_t)b * KN_;
  float s = 0.f;
#pragma unroll
  for (int c = 0; c < 4; c++) {
    int n = c * 512 + lane * 8;
    u16x8 u = *(const u16x8*)&U[n];
    float4 r0 = *(const float4*)&R[n];
    float4 r1 = *(const float4*)&R[n + 4];
    s += bf2f(u[0]) * r0.x + bf2f(u[1]) * r0.y + bf2f(u[2]) * r0.z + bf2f(u[3]) * r0.w;
    s += bf2f(u[4]) * r1.x + bf2f(u[5]) * r1.y + bf2f(u[6]) * r1.z + bf2f(u[7]) * r1.w;
  }
#pragma unroll
  for (int o = 32; o > 0; o >>= 1) s += __shfl_xor(s, o, 64);
  if (lane == 0) denom[(size_t)b * KN_ + m] = s;
}

// ---------------- energy kernel: 2-phase dbuf (counted vmcnt) split-GEMM + exp
//                   + transpose + row-partials ----
__global__ __launch_bounds__(256) void energy_kernel(
    const unsigned short* __restrict__ Ahi, const unsigned short* __restrict__ Alo,
    const unsigned short* __restrict__ Bhi, const unsigned short* __restrict__ Blo,
    unsigned short* __restrict__ uT, float* __restrict__ rowpart) {
  int bx, by, b;
  xcd_swizzle(bx, by, b);  // grid (16,16,8): each XCD owns one batch
  Ahi += (size_t)b * KN_ * KC2_; Alo += (size_t)b * KN_ * KC2_;
  Bhi += (size_t)b * KN_ * KC2_; Blo += (size_t)b * KN_ * KC2_;
  const int m0 = by * 128;  // rows = n (query idx)
  const int n0 = bx * 128;  // cols = m (key idx)
  __shared__ __align__(16) char smem[65536];  // 2 phases x 32KB; phase0 reused for transpose
  const int t = threadIdx.x, lane = t & 63, w = t >> 6;
  const int wr = w >> 1, wc = w & 1;
  const int srow = t >> 2;
  const int scol = (((t & 3) ^ ((srow >> 1) & 3)) * 8);   // pre-swizzled k-chunk
  const int lr = lane & 15, lk = (lane >> 4) * 8;
  const int rsw = ((lr >> 1) & 3) << 4;                   // read-side XOR (bytes)

  auto STAGE = [&](char* dst, int kt) {
    const size_t ga = (size_t)(m0 + srow) * KC2_ + kt + scol;
    const size_t gb = (size_t)(n0 + srow) * KC2_ + kt + scol;
    GLD16(Ahi + ga, dst + 0 + w * 1024);
    GLD16(Ahi + ga + (size_t)64 * KC2_, dst + 4096 + w * 1024);
    GLD16(Alo + ga, dst + 8192 + w * 1024);
    GLD16(Alo + ga + (size_t)64 * KC2_, dst + 12288 + w * 1024);
    GLD16(Bhi + gb, dst + 16384 + w * 1024);
    GLD16(Bhi + gb + (size_t)64 * KC2_, dst + 20480 + w * 1024);
    GLD16(Blo + gb, dst + 24576 + w * 1024);
    GLD16(Blo + gb + (size_t)64 * KC2_, dst + 28672 + w * 1024);
  };

  f32x4 acc[4][4];
  const f32x4 z = {0.f, 0.f, 0.f, 0.f};
#pragma unroll
  for (int i = 0; i < 4; i++)
#pragma unroll
    for (int j = 0; j < 4; j++) acc[i][j] = z;

  STAGE(smem, 0);
  for (int kt8 = 0; kt8 < 8; kt8++) {
    char* cur = smem + (kt8 & 1) * 32768;
    char* nxt = smem + ((kt8 & 1) ^ 1) * 32768;
    if (kt8 < 7) {
      STAGE(nxt, (kt8 + 1) * 32);  // +8 loads in flight
      WAIT_VM8();                  // wait only cur's 8 (oldest)
    } else {
      WAIT_VM0();
    }
    BARRIER();                     // all waves' cur-loads visible
    bf16x8 ah[4], al[4], bh[4], bl[4];
#pragma unroll
    for (int i = 0; i < 4; i++) {
      int ro = (wr * 64 + i * 16 + lr) * 64 + ((lk * 2) ^ rsw);
      ah[i] = *(const bf16x8*)(cur + 0 + ro);
      al[i] = *(const bf16x8*)(cur + 8192 + ro);
    }
#pragma unroll
    for (int j = 0; j < 4; j++) {
      int ro = (wc * 64 + j * 16 + lr) * 64 + ((lk * 2) ^ rsw);
      bh[j] = *(const bf16x8*)(cur + 16384 + ro);
      bl[j] = *(const bf16x8*)(cur + 24576 + ro);
    }
#pragma unroll
    for (int i = 0; i < 4; i++)
#pragma unroll
      for (int j = 0; j < 4; j++) {
        acc[i][j] = __builtin_amdgcn_mfma_f32_16x16x32_bf16(al[i], bh[j], acc[i][j], 0, 0, 0);
        acc[i][j] = __builtin_amdgcn_mfma_f32_16x16x32_bf16(ah[i], bl[j], acc[i][j], 0, 0, 0);
        acc[i][j] = __builtin_amdgcn_mfma_f32_16x16x32_bf16(ah[i], bh[j], acc[i][j], 0, 0, 0);
      }
    BARRIER();                     // all reads of cur done before it's restaged
  }

  // ---- u = exp(E - 40) ----
#pragma unroll
  for (int i = 0; i < 4; i++)
#pragma unroll
    for (int j = 0; j < 4; j++)
#pragma unroll
      for (int r = 0; r < 4; r++) acc[i][j][r] = __expf(acc[i][j][r] - 40.f);

  // ---- partial row sums ----
#pragma unroll
  for (int i = 0; i < 4; i++) {
#pragma unroll
    for (int r = 0; r < 4; r++) {
      float s = acc[i][0][r] + acc[i][1][r] + acc[i][2][r] + acc[i][3][r];
      s += __shfl_xor(s, 1, 64); s += __shfl_xor(s, 2, 64);
      s += __shfl_xor(s, 4, 64); s += __shfl_xor(s, 8, 64);
      if ((lane & 15) == 0) {
        int row = m0 + wr * 64 + i * 16 + ((lane >> 4) << 2) + r;
        rowpart[((size_t)b * KN_ + row) * 32 + bx * 2 + wc] = s;
      }
    }
  }

  // ---- transpose to uT via LDS (XOR-swizzled banks) ----
#pragma unroll
  for (int i = 0; i < 4; i++) {
#pragma unroll
    for (int j = 0; j < 4; j++) {
#pragma unroll
      for (int r2 = 0; r2 < 4; r2 += 2) {
        int qn = wr * 64 + i * 16 + ((lane >> 4) << 2) + r2;
        int km = wc * 64 + j * 16 + lr;
        unsigned pk = (unsigned)f2bf(acc[i][j][r2]) |
                      ((unsigned)f2bf(acc[i][j][r2 + 1]) << 16);
        int a = ((km << 8) + (qn << 1)) ^ ((km & 15) << 4);
        *(unsigned*)(smem + a) = pk;
      }
    }
  }
  __syncthreads();
  // read 16B per lane, 16 lanes cooperate per uT row -> 256B coalesced bursts
#pragma unroll
  for (int it = 0; it < 8; it++) {
    int km = (t >> 4) + it * 16, chunk = t & 15;
    int a = ((km << 8) + (chunk << 4)) ^ ((km & 15) << 4);
    size_t g = ((size_t)b * KN_ + (n0 + km)) * KN_ + m0 + chunk * 8;
    *(bf16x8*)&uT[g] = *(const bf16x8*)(smem + a);
  }
}

// ---------------- epilogue variants ----------------
enum { EPI_PAIR = 0, EPI_VSCALE = 2, EPI_PART = 3, EPI_FINAL = 4 };

struct EpiParams {
  const float* bias;
  const float* xf;  long xf_stride;
  const float* scale; long scale_stride;
  const float* gamma; const float* beta; const float* mean; const float* var;
};

// ============== unified MFMA GEMM core, 128x128 tile, BK=64, 2-phase dbuf
// with counted vmcnt; segmented-K: if seg>0 (K=3*seg): A'=[A0|A1|A0], B'=[B0|B0|B1]. ====
template<int EPI>
__device__ __forceinline__ void gemm_core(
    char* __restrict__ smem, int bx, int by, int b,
    const unsigned short* __restrict__ A0, const unsigned short* __restrict__ A1,
    long sA, int lda, int seg,
    const unsigned short* __restrict__ B0, const unsigned short* __restrict__ B1,
    long sB, int ldb,
    void* __restrict__ Cv, void* __restrict__ Cv2, long sC, int ldc, int K,
    const EpiParams& ep) {
  A0 += (size_t)b * sA; A1 += (size_t)b * sA;
  B0 += (size_t)b * sB; B1 += (size_t)b * sB;
  const int m0 = by * 128, n0 = bx * 128;
  const int t = threadIdx.x, lane = t & 63, w = t >> 6;
  const int wr = w >> 1, wc = w & 1;
  const int srow = t >> 2;
  const int scol = (((t & 3) ^ ((srow >> 1) & 3)) * 8);   // pre-swizzled k-chunk
  const int lr = lane & 15, lk = (lane >> 4) * 8;
  const int rsw = ((lr >> 1) & 3) << 4;                   // read-side XOR (bytes)

  auto STAGE = [&](char* dst, int kt) {
    int s = seg ? ((kt >= seg) + (kt >= 2 * seg)) : 0;
    int kl = kt - s * seg;
    const unsigned short* Ab = (s == 1) ? A1 : A0;
    const unsigned short* Bb = (s == 2) ? B1 : B0;
    const unsigned short* gA = Ab + (size_t)(m0 + srow) * lda + kl + scol;
    const unsigned short* gB = Bb + (size_t)(n0 + srow) * ldb + kl + scol;
    GLD16(gA, dst + w * 1024);                         // A k0
    GLD16(gA + (size_t)64 * lda, dst + 4096 + w * 1024);
    GLD16(gA + 32, dst + 8192 + w * 1024);             // A k1
    GLD16(gA + (size_t)64 * lda + 32, dst + 12288 + w * 1024);
    GLD16(gB, dst + 16384 + w * 1024);                 // B k0
    GLD16(gB + (size_t)64 * ldb, dst + 20480 + w * 1024);
    GLD16(gB + 32, dst + 24576 + w * 1024);            // B k1
    GLD16(gB + (size_t)64 * ldb + 32, dst + 28672 + w * 1024);
  };

  f32x4 acc[4][4];
  const f32x4 z = {0.f, 0.f, 0.f, 0.f};
#pragma unroll
  for (int i = 0; i < 4; i++)
#pragma unroll
    for (int j = 0; j < 4; j++) acc[i][j] = z;

  const int nt = K >> 6;
  STAGE(smem, 0);
  for (int t8 = 0; t8 < nt; t8++) {
    char* cur = smem + (t8 & 1) * 32768;
    char* nxt = smem + ((t8 & 1) ^ 1) * 32768;
    if (t8 < nt - 1) {
      STAGE(nxt, (t8 + 1) * 64);
      WAIT_VM8();
    } else {
      WAIT_VM0();
    }
    BARRIER();
#pragma unroll
    for (int kk = 0; kk < 2; kk++) {
      bf16x8 af[4], bfv[4];
#pragma unroll
      for (int i = 0; i < 4; i++)
        af[i] = *(const bf16x8*)(cur + kk * 8192 +
                                 (wr * 64 + i * 16 + lr) * 64 + ((lk * 2) ^ rsw));
#pragma unroll
      for (int j = 0; j < 4; j++)
        bfv[j] = *(const bf16x8*)(cur + 16384 + kk * 8192 +
                                  (wc * 64 + j * 16 + lr) * 64 + ((lk * 2) ^ rsw));
#pragma unroll
      for (int i = 0; i < 4; i++)
#pragma unroll
        for (int j = 0; j < 4; j++)
          acc[i][j] = __builtin_amdgcn_mfma_f32_16x16x32_bf16(af[i], bfv[j], acc[i][j], 0, 0, 0);
    }
    BARRIER();
  }

#pragma unroll
  for (int i = 0; i < 4; i++) {
#pragma unroll
    for (int r = 0; r < 4; r++) {
      const int row = m0 + wr * 64 + i * 16 + ((lane >> 4) << 2) + r;
      float pbias = 0.f, pinv = 1.f, padd = 0.f;
      if constexpr (EPI == EPI_VSCALE) pbias = ep.bias[row];
      if constexpr (EPI == EPI_FINAL) {
        pbias = ep.bias[row];
        float iv = ep.gamma[row] * rsqrtf(ep.var[row] + 1e-5f);
        pinv = iv;
        padd = ep.beta[row] - ep.mean[row] * iv;
      }
#pragma unroll
      for (int j = 0; j < 4; j++) {
        const int col = n0 + wc * 64 + j * 16 + lr;
        float v = acc[i][j][r];
        size_t o = (size_t)b * sC + (size_t)row * ldc + col;
        if constexpr (EPI == EPI_PAIR) {
          unsigned short h = f2bf(v);
          ((unsigned short*)Cv)[o] = h;
          ((unsigned short*)Cv2)[o] = f2bf(v - bf2f(h));
        } else if constexpr (EPI == EPI_VSCALE) {
          float sc = ep.scale[(size_t)b * ep.scale_stride + col];
          ((unsigned short*)Cv)[o] = f2bf((v + pbias) * sc);
        } else if constexpr (EPI == EPI_PART) {
          ((float*)Cv)[o] = v;
        } else {  // EPI_FINAL
          float h = (v + pbias) * pinv + padd;
          h = fmaxf(h, 0.f);
          float xval = ep.xf[(size_t)b * ep.xf_stride + o - (size_t)b * sC];
          ((float*)Cv)[o] = h + xval;
        }
      }
    }
  }
}

// generic single-GEMM kernel (64 KB LDS, 2-phase)
template<int EPI>
__global__ __launch_bounds__(256) void gemm_one(
    const unsigned short* __restrict__ A0, const unsigned short* __restrict__ A1,
    long sA, int lda, int seg,
    const unsigned short* __restrict__ B0, const unsigned short* __restrict__ B1,
    long sB, int ldb,
    void* __restrict__ Cv, void* __restrict__ Cv2, long sC, int ldc, int K,
    EpiParams ep) {
  __shared__ __align__(16) char smem[65536];
  int bx, by, b;
  xcd_swizzle(bx, by, b);
  gemm_core<EPI>(smem, bx, by, b, A0, A1, sA, lda, seg, B0, B1, sB, ldb,
                 Cv, Cv2, sC, ldc, K, ep);
}

// fused x_q + x_k projections: one 512-block launch
__global__ __launch_bounds__(256) void proj2_kernel(
    const unsigned short* __restrict__ qThi, const unsigned short* __restrict__ qTlo,
    const unsigned short* __restrict__ Wqhi, const unsigned short* __restrict__ Wqlo,
    unsigned short* __restrict__ xqhi, unsigned short* __restrict__ xqlo,
    const unsigned short* __restrict__ xThi, const unsigned short* __restrict__ xTlo,
    const unsigned short* __restrict__ Wkhi, const unsigned short* __restrict__ Wklo,
    unsigned short* __restrict__ xkhi, unsigned short* __restrict__ xklo) {
  __shared__ __align__(16) char smem[65536];
  int f = (int)blockIdx.x;
  f = (f & 7) * 64 + (f >> 3);  // XCD swizzle over 512
  EpiParams ep{};
  if (f < 256) {
    int bx = f & 1, by = (f >> 1) & 15, b = f >> 5;
    gemm_core<EPI_PAIR>(smem, bx, by, b, qThi, qTlo, (long)KN_ * KC_, KC_, KC_,
                        Wqhi, Wqlo, 0, KC_, xqhi, xqlo, (long)KN_ * KC2_, KC2_,
                        3 * KC_, ep);
  } else {
    int g = f - 256;
    int bx = g & 1, by = (g >> 1) & 15, b = g >> 5;
    gemm_core<EPI_PAIR>(smem, bx, by, b, xThi, xTlo, (long)KN_ * KC2_, KC2_, KC2_,
                        Wkhi, Wklo, 0, KC2_, xkhi, xklo, (long)KN_ * KC2_, KC2_,
                        3 * KC2_, ep);
  }
}

// XR partial GEMM: split-K x2 (grid (32,2,8))
__global__ __launch_bounds__(256) void xr_kernel(
    const unsigned short* __restrict__ x_v, const unsigned short* __restrict__ uT,
    float* __restrict__ P) {
  __shared__ __align__(16) char smem[65536];
  int bx, by, b;
  xcd_swizzle(bx, by, b);
  int split = bx >> 4; bx &= 15;
  EpiParams ep{};
  gemm_core<EPI_PART>(smem, bx, by, b,
                      x_v + split * (KN_ / 2), nullptr, (long)KC2_ * KN_, KN_, 0,
                      uT + split * (KN_ / 2), nullptr, (long)KN_ * KN_, KN_,
                      P + (size_t)split * KB_ * KC2_ * KN_, nullptr,
                      (long)KC2_ * KN_, KN_, KN_ / 2, ep);
}

// reduce split-K partials + renorm + residual-subtract + transpose -> tT[m][c]
__global__ __launch_bounds__(256) void xr_reduce_kernel(
    const float* __restrict__ P, const float* __restrict__ x,
    const float* __restrict__ denom, unsigned short* __restrict__ tT) {
  int b = blockIdx.z;
  const float* P0 = P + (size_t)b * KC2_ * KN_;
  const float* P1 = P0 + (size_t)KB_ * KC2_ * KN_;
  const float* X  = x + (size_t)b * KC2_ * KN_;
  const float* D  = denom + (size_t)b * KN_;
  __shared__ unsigned short tile[64][72];
  int t = threadIdx.x;
  int c0 = blockIdx.y * 64, m0 = blockIdx.x * 64;  // rows = c, cols = m
#pragma unroll
  for (int k = 0; k < 4; k++) {
    int vi = k * 256 + t, rr = vi >> 4, cv = vi & 15;
    size_t o = (size_t)(c0 + rr) * KN_ + m0 + cv * 4;
    float4 p0 = *(const float4*)&P0[o];
    float4 p1 = *(const float4*)&P1[o];
    float4 xv = *(const float4*)&X[o];
    float4 dv = *(const float4*)&D[m0 + cv * 4];
    tile[rr][cv * 4 + 0] = f2bf(xv.x - (p0.x + p1.x) / (1e-9f + dv.x));
    tile[rr][cv * 4 + 1] = f2bf(xv.y - (p0.y + p1.y) / (1e-9f + dv.y));
    tile[rr][cv * 4 + 2] = f2bf(xv.z - (p0.z + p1.z) / (1e-9f + dv.z));
    tile[rr][cv * 4 + 3] = f2bf(xv.w - (p0.w + p1.w) / (1e-9f + dv.w));
  }
  __syncthreads();
#pragma unroll
  for (int k = 0; k < 4; k++) {
    int vi = k * 256 + t, cc = vi >> 4, rv = vi & 15;
    ushort4 u = { tile[rv * 4 + 0][cc], tile[rv * 4 + 1][cc],
                  tile[rv * 4 + 2][cc], tile[rv * 4 + 3][cc] };
    *(ushort4*)&tT[(size_t)b * KN_ * KC2_ + (size_t)(m0 + cc) * KC2_ + c0 + rv * 4] = u;
  }
}

// ---------------- launcher ----------------
extern "C" void kernel_launch(void* const* d_in, const int* in_sizes, int n_in,
                              void* d_out, int out_size, void* d_ws, size_t ws_size,
                              hipStream_t stream) {
  (void)in_sizes; (void)n_in; (void)out_size; (void)ws_size;
  const float* q     = (const float*)d_in[0];
  const float* x     = (const float*)d_in[1];
  const float* Wq    = (const float*)d_in[2];
  const float* Wk    = (const float*)d_in[3];
  const float* Wv    = (const float*)d_in[4];
  const float* bv    = (const float*)d_in[5];
  const float* Wt    = (const float*)d_in[6];
  const float* bt    = (const float*)d_in[7];
  const float* gamma = (const float*)d_in[8];
  const float* beta  = (const float*)d_in[9];
  const float* rmean = (const float*)d_in[10];
  const float* rvar  = (const float*)d_in[11];
  float* out = (float*)d_out;

  // workspace (~196 MiB)
  const size_t SZ_qT = (size_t)KB_ * KN_ * KC_ * 2;   // 16 MiB
  const size_t SZ_xT = (size_t)KB_ * KN_ * KC2_ * 2;  //  8 MiB
  char* ws = (char*)d_ws;
  size_t off = 0;
  auto alloc = [&](size_t bytes) {
    char* p = ws + off;
    off += (bytes + 255) & ~(size_t)255;
    return p;
  };
  unsigned short* qThi = (unsigned short*)alloc(SZ_qT);
  unsigned short* qTlo = (unsigned short*)alloc(SZ_qT);
  unsigned short* xThi = (unsigned short*)alloc(SZ_xT);
  unsigned short* xTlo = (unsigned short*)alloc(SZ_xT);
  unsigned short* xqhi = (unsigned short*)alloc(SZ_xT);
  unsigned short* xqlo = (unsigned short*)alloc(SZ_xT);
  unsigned short* xkhi = (unsigned short*)alloc(SZ_xT);
  unsigned short* xklo = (unsigned short*)alloc(SZ_xT);
  unsigned short* x_v  = (unsigned short*)alloc((size_t)KB_ * KC2_ * KN_ * 2);
  unsigned short* tT   = (unsigned short*)alloc(SZ_xT);
  unsigned short* Wqhi = (unsigned short*)alloc((size_t)KC2_ * KC_ * 2);
  unsigned short* Wqlo = (unsigned short*)alloc((size_t)KC2_ * KC_ * 2);
  unsigned short* Wkhi = (unsigned short*)alloc((size_t)KC2_ * KC2_ * 2);
  unsigned short* Wklo = (unsigned short*)alloc((size_t)KC2_ * KC2_ * 2);
  unsigned short* Wvb  = (unsigned short*)alloc((size_t)KC2_ * KC_ * 2);
  unsigned short* Wtb  = (unsigned short*)alloc((size_t)KC2_ * KC2_ * 2);
  float* rsv     = (float*)alloc((size_t)KB_ * KN_ * 4);
  float* denom   = (float*)alloc((size_t)KB_ * KN_ * 4);
  float* rowpart = (float*)alloc((size_t)KB_ * KN_ * 32 * 4);
  float* P       = (float*)alloc((size_t)2 * KB_ * KC2_ * KN_ * 4);           // 32 MiB
  unsigned short* uT = (unsigned short*)alloc((size_t)KB_ * KN_ * KN_ * 2);   // 64 MiB

  dim3 blk(256);

  // weights -> bf16
  cvt_pair_kernel<<<dim3(KC2_ * KC_ / 1024), blk, 0, stream>>>(Wq, Wqhi, Wqlo, KC2_ * KC_);
  cvt_pair_kernel<<<dim3(KC2_ * KC2_ / 1024), blk, 0, stream>>>(Wk, Wkhi, Wklo, KC2_ * KC2_);
  cvt_kernel<<<dim3(KC2_ * KC_ / 1024), blk, 0, stream>>>(Wv, Wvb, KC2_ * KC_);
  cvt_kernel<<<dim3(KC2_ * KC2_ / 1024), blk, 0, stream>>>(Wt, Wtb, KC2_ * KC2_);

  // q^T, x^T fp32 -> hi/lo bf16 pairs (K contiguous)
  transpose_pair_kernel<<<dim3(KN_ / 64, KC_ / 64, KB_), blk, 0, stream>>>(
      q, (long)KC_ * KN_, qThi, qTlo, (long)KN_ * KC_, KC_, KN_);
  transpose_pair_kernel<<<dim3(KN_ / 64, KC2_ / 64, KB_), blk, 0, stream>>>(
      x, (long)KC2_ * KN_, xThi, xTlo, (long)KN_ * KC2_, KC2_, KN_);

  // x_q / x_kT projections (fp32-grade via segmented-K)
  proj2_kernel<<<dim3(512), blk, 0, stream>>>(qThi, qTlo, Wqhi, Wqlo, xqhi, xqlo,
                                              xThi, xTlo, Wkhi, Wklo, xkhi, xklo);

  // energy + exp + transpose + row partials (2-phase dbuf, counted vmcnt)
  energy_kernel<<<dim3(KN_ / 128, KN_ / 128, KB_), blk, 0, stream>>>(
      xqhi, xqlo, xkhi, xklo, uT, rowpart);
  rowreduce_kernel<<<dim3(KB_ * KN_ / 256), blk, 0, stream>>>(rowpart, rsv);

  // x_v'[b][o][n] = (Wv[o][:].qT[n][:] + bv[o]) * rsv[b][n]
  EpiParams e3{}; e3.bias = bv; e3.scale = rsv; e3.scale_stride = KN_;
  gemm_one<EPI_VSCALE><<<dim3(KN_ / 128, KC2_ / 128, KB_), blk, 0, stream>>>(
      Wvb, nullptr, 0, KC_, 0, qThi, nullptr, (long)KN_ * KC_, KC_,
      x_v, nullptr, (long)KC2_ * KN_, KN_, KC_, e3);

  // denom[b][m] = sum_n uT[m][n] * rsv[n]
  denom_kernel<<<dim3(KN_ / 4, KB_), blk, 0, stream>>>(uT, rsv, denom);

  // x_r partials (split-K x2) then reduce + renorm + subtract + transpose -> tT
  xr_kernel<<<dim3(32, 2, 8), blk, 0, stream>>>(x_v, uT, P);
  xr_reduce_kernel<<<dim3(KN_ / 64, KC2_ / 64, KB_), blk, 0, stream>>>(P, x, denom, tT);

  // out[b][o][n] = relu(BN(Wt[o][:].tT[n][:] + bt[o])) + x[b][o][n]
  EpiParams e6{}; e6.bias = bt; e6.xf = x; e6.xf_stride = (long)KC2_ * KN_;
  e6.gamma = gamma; e6.beta = beta; e6.mean = rmean; e6.var = rvar;
  gemm_one<EPI_FINAL><<<dim3(KN_ / 128, KC2_ / 128, KB_), blk, 0, stream>>>(
      Wtb, nullptr, 0, KC2_, 0, tT, nullptr, (long)KN_ * KC2_, KC2_,
      out, nullptr, (long)KC2_ * KN_, KN_, KC2_, e6);
}

// Round 9
// 197.160 us; speedup vs baseline: 1.5432x; 1.0510x over previous
//
#include <hip/hip_runtime.h>
#include <cstdint>
#include <cstddef>

// Problem constants (B, C, N fixed by the reference)
#define KB_  8
#define KC_  512
#define KC2_ 256
#define KN_  2048

typedef __attribute__((ext_vector_type(8))) __bf16 bf16x8;
typedef __attribute__((ext_vector_type(8))) unsigned short u16x8;
typedef __attribute__((ext_vector_type(4))) float f32x4;

__device__ __forceinline__ unsigned short f2bf(float f) {
  union { float f; unsigned u; } x; x.f = f;
  unsigned r = x.u + 0x7fffu + ((x.u >> 16) & 1u);  // RNE (finite values only)
  return (unsigned short)(r >> 16);
}
__device__ __forceinline__ float bf2f(unsigned short h) {
  union { unsigned u; float f; } x; x.u = ((unsigned)h) << 16;
  return x.f;
}

// async global->LDS, 16B per lane; LDS dest = wave-uniform base + lane*16 (linear!)
#define GLD16(g, l) __builtin_amdgcn_global_load_lds( \
    (__attribute__((address_space(1))) void*)(g),     \
    (__attribute__((address_space(3))) void*)(l), 16, 0, 0)

// counted-vmcnt barrier pair (T4): wait only the CURRENT buffer's 8 loads;
// next-tile loads stay in flight across the barrier.
#define WAIT_VM8()  asm volatile("s_waitcnt vmcnt(8)" ::: "memory")
#define WAIT_VM0()  asm volatile("s_waitcnt vmcnt(0)" ::: "memory")
#define BARRIER()   __builtin_amdgcn_s_barrier()

// bijective XCD-aware block swizzle (nb % 8 == 0 for all our grids)
__device__ __forceinline__ void xcd_swizzle(int& bx, int& by, int& bz) {
  const int gx = gridDim.x, gy = gridDim.y;
  const int nb = gx * gy * (int)gridDim.z;
  int f = ((int)blockIdx.z * gy + (int)blockIdx.y) * gx + (int)blockIdx.x;
  if ((nb & 7) == 0) f = (f & 7) * (nb >> 3) + (f >> 3);
  const int gxy = gx * gy;
  bz = f / gxy; int rem = f - bz * gxy;
  by = rem / gx; bx = rem - by * gx;
}

// ---------------- weight fp32 -> bf16 convert (single) ----------------
__global__ __launch_bounds__(256) void cvt_kernel(const float* __restrict__ in,
                                                  unsigned short* __restrict__ out, int n) {
  int i = (blockIdx.x * 256 + threadIdx.x) * 4;
  if (i >= n) return;
  float4 f = *(const float4*)(in + i);
  ushort4 u = { f2bf(f.x), f2bf(f.y), f2bf(f.z), f2bf(f.w) };
  *(ushort4*)(out + i) = u;
}

// ---------------- weight fp32 -> bf16 hi/lo pair ----------------
__global__ __launch_bounds__(256) void cvt_pair_kernel(const float* __restrict__ in,
                                                       unsigned short* __restrict__ hi,
                                                       unsigned short* __restrict__ lo, int n) {
  int i = (blockIdx.x * 256 + threadIdx.x) * 4;
  if (i >= n) return;
  float4 f = *(const float4*)(in + i);
  ushort4 h = { f2bf(f.x), f2bf(f.y), f2bf(f.z), f2bf(f.w) };
  ushort4 l = { f2bf(f.x - bf2f(h.x)), f2bf(f.y - bf2f(h.y)),
                f2bf(f.z - bf2f(h.z)), f2bf(f.w - bf2f(h.w)) };
  *(ushort4*)(hi + i) = h;
  *(ushort4*)(lo + i) = l;
}

// ---------------- tiled transpose: fp32 [R][Cc] -> bf16 hi/lo [Cc][R] ----------------
__global__ __launch_bounds__(256) void transpose_pair_kernel(const float* __restrict__ in,
                                                             long sIn,
                                                             unsigned short* __restrict__ hi,
                                                             unsigned short* __restrict__ lo,
                                                             long sOut, int R, int Cc) {
  int b = blockIdx.z;
  const float* I = in + (size_t)b * sIn;
  __shared__ float tile[64][65];
  int t = threadIdx.x;
  int r0 = blockIdx.y * 64, c0 = blockIdx.x * 64;
#pragma unroll
  for (int k = 0; k < 4; k++) {
    int vi = k * 256 + t, rr = vi >> 4, cv = vi & 15;
    float4 f = *(const float4*)&I[(size_t)(r0 + rr) * Cc + c0 + cv * 4];
    tile[rr][cv * 4 + 0] = f.x; tile[rr][cv * 4 + 1] = f.y;
    tile[rr][cv * 4 + 2] = f.z; tile[rr][cv * 4 + 3] = f.w;
  }
  __syncthreads();
#pragma unroll
  for (int k = 0; k < 4; k++) {
    int vi = k * 256 + t, cc = vi >> 4, rv = vi & 15;
    float f0 = tile[rv * 4 + 0][cc], f1 = tile[rv * 4 + 1][cc];
    float f2 = tile[rv * 4 + 2][cc], f3 = tile[rv * 4 + 3][cc];
    ushort4 h = { f2bf(f0), f2bf(f1), f2bf(f2), f2bf(f3) };
    ushort4 l = { f2bf(f0 - bf2f(h.x)), f2bf(f1 - bf2f(h.y)),
                  f2bf(f2 - bf2f(h.z)), f2bf(f3 - bf2f(h.w)) };
    size_t o = (size_t)b * sOut + (size_t)(c0 + cc) * R + r0 + rv * 4;
    *(ushort4*)&hi[o] = h;
    *(ushort4*)&lo[o] = l;
  }
}

// ---------------- rsv[b][n] = 1 / sum_k rowpart[b][n][k] ----------------
__global__ __launch_bounds__(256) void rowreduce_kernel(const float* __restrict__ rowpart,
                                                        float* __restrict__ rsv) {
  int idx = blockIdx.x * 256 + threadIdx.x;  // 8*2048 rows
  const float* p = rowpart + (size_t)idx * 32;
  float s = 0.f;
#pragma unroll
  for (int k = 0; k < 32; k++) s += p[k];
  rsv[idx] = 1.0f / s;
}

// ---------------- denom[b][m] = sum_n uT[b][m][n] * rsv[b][n] ----------------
__global__ __launch_bounds__(256) void denom_kernel(const unsigned short* __restrict__ uT,
                                                    const float* __restrict__ rsv,
                                                    float* __restrict__ denom) {
  int b = blockIdx.y;
  int m = blockIdx.x * 4 + (threadIdx.x >> 6);
  int lane = threadIdx.x & 63;
  const unsigned short* U = uT + ((size_t)b * KN_ + m) * KN_;
  const float* R = rsv + (size_t)b * KN_;
  float s = 0.f;
#pragma unroll
  for (int c = 0; c < 4; c++) {
    int n = c * 512 + lane * 8;
    u16x8 u = *(const u16x8*)&U[n];
    float4 r0 = *(const float4*)&R[n];
    float4 r1 = *(const float4*)&R[n + 4];
    s += bf2f(u[0]) * r0.x + bf2f(u[1]) * r0.y + bf2f(u[2]) * r0.z + bf2f(u[3]) * r0.w;
    s += bf2f(u[4]) * r1.x + bf2f(u[5]) * r1.y + bf2f(u[6]) * r1.z + bf2f(u[7]) * r1.w;
  }
#pragma unroll
  for (int o = 32; o > 0; o >>= 1) s += __shfl_xor(s, o, 64);
  if (lane == 0) denom[(size_t)b * KN_ + m] = s;
}

// ---------------- energy kernel: 2-phase dbuf (counted vmcnt) split-GEMM + exp
//                   + transpose + row-partials ----
__global__ __launch_bounds__(256) void energy_kernel(
    const unsigned short* __restrict__ Ahi, const unsigned short* __restrict__ Alo,
    const unsigned short* __restrict__ Bhi, const unsigned short* __restrict__ Blo,
    unsigned short* __restrict__ uT, float* __restrict__ rowpart) {
  int bx, by, b;
  xcd_swizzle(bx, by, b);  // grid (16,16,8): each XCD owns one batch
  Ahi += (size_t)b * KN_ * KC2_; Alo += (size_t)b * KN_ * KC2_;
  Bhi += (size_t)b * KN_ * KC2_; Blo += (size_t)b * KN_ * KC2_;
  const int m0 = by * 128;  // rows = n (query idx)
  const int n0 = bx * 128;  // cols = m (key idx)
  __shared__ __align__(16) char smem[65536];  // 2 phases x 32KB; phase0 reused for transpose
  const int t = threadIdx.x, lane = t & 63, w = t >> 6;
  const int wr = w >> 1, wc = w & 1;
  const int srow = t >> 2;
  const int scol = (((t & 3) ^ ((srow >> 1) & 3)) * 8);   // pre-swizzled k-chunk
  const int lr = lane & 15, lk = (lane >> 4) * 8;
  const int rsw = ((lr >> 1) & 3) << 4;                   // read-side XOR (bytes)

  auto STAGE = [&](char* dst, int kt) {
    const size_t ga = (size_t)(m0 + srow) * KC2_ + kt + scol;
    const size_t gb = (size_t)(n0 + srow) * KC2_ + kt + scol;
    GLD16(Ahi + ga, dst + 0 + w * 1024);
    GLD16(Ahi + ga + (size_t)64 * KC2_, dst + 4096 + w * 1024);
    GLD16(Alo + ga, dst + 8192 + w * 1024);
    GLD16(Alo + ga + (size_t)64 * KC2_, dst + 12288 + w * 1024);
    GLD16(Bhi + gb, dst + 16384 + w * 1024);
    GLD16(Bhi + gb + (size_t)64 * KC2_, dst + 20480 + w * 1024);
    GLD16(Blo + gb, dst + 24576 + w * 1024);
    GLD16(Blo + gb + (size_t)64 * KC2_, dst + 28672 + w * 1024);
  };

  f32x4 acc[4][4];
  const f32x4 z = {0.f, 0.f, 0.f, 0.f};
#pragma unroll
  for (int i = 0; i < 4; i++)
#pragma unroll
    for (int j = 0; j < 4; j++) acc[i][j] = z;

  STAGE(smem, 0);
  for (int kt8 = 0; kt8 < 8; kt8++) {
    char* cur = smem + (kt8 & 1) * 32768;
    char* nxt = smem + ((kt8 & 1) ^ 1) * 32768;
    if (kt8 < 7) {
      STAGE(nxt, (kt8 + 1) * 32);  // +8 loads in flight
      WAIT_VM8();                  // wait only cur's 8 (oldest)
    } else {
      WAIT_VM0();
    }
    BARRIER();                     // all waves' cur-loads visible
    bf16x8 ah[4], al[4], bh[4], bl[4];
#pragma unroll
    for (int i = 0; i < 4; i++) {
      int ro = (wr * 64 + i * 16 + lr) * 64 + ((lk * 2) ^ rsw);
      ah[i] = *(const bf16x8*)(cur + 0 + ro);
      al[i] = *(const bf16x8*)(cur + 8192 + ro);
    }
#pragma unroll
    for (int j = 0; j < 4; j++) {
      int ro = (wc * 64 + j * 16 + lr) * 64 + ((lk * 2) ^ rsw);
      bh[j] = *(const bf16x8*)(cur + 16384 + ro);
      bl[j] = *(const bf16x8*)(cur + 24576 + ro);
    }
#pragma unroll
    for (int i = 0; i < 4; i++)
#pragma unroll
      for (int j = 0; j < 4; j++) {
        acc[i][j] = __builtin_amdgcn_mfma_f32_16x16x32_bf16(al[i], bh[j], acc[i][j], 0, 0, 0);
        acc[i][j] = __builtin_amdgcn_mfma_f32_16x16x32_bf16(ah[i], bl[j], acc[i][j], 0, 0, 0);
        acc[i][j] = __builtin_amdgcn_mfma_f32_16x16x32_bf16(ah[i], bh[j], acc[i][j], 0, 0, 0);
      }
    BARRIER();                     // all reads of cur done before it's restaged
  }

  // ---- u = exp(E - 40) ----
#pragma unroll
  for (int i = 0; i < 4; i++)
#pragma unroll
    for (int j = 0; j < 4; j++)
#pragma unroll
      for (int r = 0; r < 4; r++) acc[i][j][r] = __expf(acc[i][j][r] - 40.f);

  // ---- partial row sums ----
#pragma unroll
  for (int i = 0; i < 4; i++) {
#pragma unroll
    for (int r = 0; r < 4; r++) {
      float s = acc[i][0][r] + acc[i][1][r] + acc[i][2][r] + acc[i][3][r];
      s += __shfl_xor(s, 1, 64); s += __shfl_xor(s, 2, 64);
      s += __shfl_xor(s, 4, 64); s += __shfl_xor(s, 8, 64);
      if ((lane & 15) == 0) {
        int row = m0 + wr * 64 + i * 16 + ((lane >> 4) << 2) + r;
        rowpart[((size_t)b * KN_ + row) * 32 + bx * 2 + wc] = s;
      }
    }
  }

  // ---- transpose to uT via LDS (XOR-swizzled banks) ----
#pragma unroll
  for (int i = 0; i < 4; i++) {
#pragma unroll
    for (int j = 0; j < 4; j++) {
#pragma unroll
      for (int r2 = 0; r2 < 4; r2 += 2) {
        int qn = wr * 64 + i * 16 + ((lane >> 4) << 2) + r2;
        int km = wc * 64 + j * 16 + lr;
        unsigned pk = (unsigned)f2bf(acc[i][j][r2]) |
                      ((unsigned)f2bf(acc[i][j][r2 + 1]) << 16);
        int a = ((km << 8) + (qn << 1)) ^ ((km & 15) << 4);
        *(unsigned*)(smem + a) = pk;
      }
    }
  }
  __syncthreads();
  // read 16B per lane, 16 lanes cooperate per uT row -> 256B coalesced bursts
#pragma unroll
  for (int it = 0; it < 8; it++) {
    int km = (t >> 4) + it * 16, chunk = t & 15;
    int a = ((km << 8) + (chunk << 4)) ^ ((km & 15) << 4);
    size_t g = ((size_t)b * KN_ + (n0 + km)) * KN_ + m0 + chunk * 8;
    *(bf16x8*)&uT[g] = *(const bf16x8*)(smem + a);
  }
}

// ---------------- epilogue variants ----------------
enum { EPI_PAIR = 0, EPI_VSCALE = 2, EPI_XRT = 3, EPI_FINAL = 4 };

struct EpiParams {
  const float* bias;
  const float* xf;  long xf_stride;
  const float* scale; long scale_stride;
  const float* gamma; const float* beta; const float* mean; const float* var;
};

// ============== unified MFMA GEMM core, 128x128 tile, BK=64, 2-phase dbuf
// with counted vmcnt; segmented-K: if seg>0 (K=3*seg): A'=[A0|A1|A0], B'=[B0|B0|B1]. ====
template<int EPI>
__device__ __forceinline__ void gemm_core(
    char* __restrict__ smem, int bx, int by, int b,
    const unsigned short* __restrict__ A0, const unsigned short* __restrict__ A1,
    long sA, int lda, int seg,
    const unsigned short* __restrict__ B0, const unsigned short* __restrict__ B1,
    long sB, int ldb,
    void* __restrict__ Cv, void* __restrict__ Cv2, long sC, int ldc, int K,
    const EpiParams& ep) {
  A0 += (size_t)b * sA; A1 += (size_t)b * sA;
  B0 += (size_t)b * sB; B1 += (size_t)b * sB;
  const int m0 = by * 128, n0 = bx * 128;
  const int t = threadIdx.x, lane = t & 63, w = t >> 6;
  const int wr = w >> 1, wc = w & 1;
  const int srow = t >> 2;
  const int scol = (((t & 3) ^ ((srow >> 1) & 3)) * 8);   // pre-swizzled k-chunk
  const int lr = lane & 15, lk = (lane >> 4) * 8;
  const int rsw = ((lr >> 1) & 3) << 4;                   // read-side XOR (bytes)

  auto STAGE = [&](char* dst, int kt) {
    int s = seg ? ((kt >= seg) + (kt >= 2 * seg)) : 0;
    int kl = kt - s * seg;
    const unsigned short* Ab = (s == 1) ? A1 : A0;
    const unsigned short* Bb = (s == 2) ? B1 : B0;
    const unsigned short* gA = Ab + (size_t)(m0 + srow) * lda + kl + scol;
    const unsigned short* gB = Bb + (size_t)(n0 + srow) * ldb + kl + scol;
    GLD16(gA, dst + w * 1024);                         // A k0
    GLD16(gA + (size_t)64 * lda, dst + 4096 + w * 1024);
    GLD16(gA + 32, dst + 8192 + w * 1024);             // A k1
    GLD16(gA + (size_t)64 * lda + 32, dst + 12288 + w * 1024);
    GLD16(gB, dst + 16384 + w * 1024);                 // B k0
    GLD16(gB + (size_t)64 * ldb, dst + 20480 + w * 1024);
    GLD16(gB + 32, dst + 24576 + w * 1024);            // B k1
    GLD16(gB + (size_t)64 * ldb + 32, dst + 28672 + w * 1024);
  };

  f32x4 acc[4][4];
  const f32x4 z = {0.f, 0.f, 0.f, 0.f};
#pragma unroll
  for (int i = 0; i < 4; i++)
#pragma unroll
    for (int j = 0; j < 4; j++) acc[i][j] = z;

  const int nt = K >> 6;
  STAGE(smem, 0);
  for (int t8 = 0; t8 < nt; t8++) {
    char* cur = smem + (t8 & 1) * 32768;
    char* nxt = smem + ((t8 & 1) ^ 1) * 32768;
    if (t8 < nt - 1) {
      STAGE(nxt, (t8 + 1) * 64);
      WAIT_VM8();
    } else {
      WAIT_VM0();
    }
    BARRIER();
#pragma unroll
    for (int kk = 0; kk < 2; kk++) {
      bf16x8 af[4], bfv[4];
#pragma unroll
      for (int i = 0; i < 4; i++)
        af[i] = *(const bf16x8*)(cur + kk * 8192 +
                                 (wr * 64 + i * 16 + lr) * 64 + ((lk * 2) ^ rsw));
#pragma unroll
      for (int j = 0; j < 4; j++)
        bfv[j] = *(const bf16x8*)(cur + 16384 + kk * 8192 +
                                  (wc * 64 + j * 16 + lr) * 64 + ((lk * 2) ^ rsw));
#pragma unroll
      for (int i = 0; i < 4; i++)
#pragma unroll
        for (int j = 0; j < 4; j++)
          acc[i][j] = __builtin_amdgcn_mfma_f32_16x16x32_bf16(af[i], bfv[j], acc[i][j], 0, 0, 0);
    }
    BARRIER();
  }

  if constexpr (EPI == EPI_XRT) {
    // t[c][m] = x[c][m] - acc/(1e-9+denom[m]); transpose in LDS -> tT[m][c] (bf16)
    float dinv[4];
#pragma unroll
    for (int j = 0; j < 4; j++)
      dinv[j] = 1.0f / (1e-9f + ep.scale[(size_t)b * ep.scale_stride +
                                         n0 + wc * 64 + j * 16 + lr]);
    const float* X = ep.xf + (size_t)b * ep.xf_stride;
#pragma unroll
    for (int i = 0; i < 4; i++) {
#pragma unroll
      for (int j = 0; j < 4; j++) {
#pragma unroll
        for (int r2 = 0; r2 < 4; r2 += 2) {
          int cl = wr * 64 + i * 16 + ((lane >> 4) << 2) + r2;
          int ml = wc * 64 + j * 16 + lr;
          float x0 = X[(size_t)(m0 + cl) * KN_ + n0 + ml];
          float x1 = X[(size_t)(m0 + cl + 1) * KN_ + n0 + ml];
          float t0 = x0 - acc[i][j][r2] * dinv[j];
          float t1 = x1 - acc[i][j][r2 + 1] * dinv[j];
          unsigned pk = (unsigned)f2bf(t0) | ((unsigned)f2bf(t1) << 16);
          int a = ((ml << 8) + (cl << 1)) ^ ((ml & 15) << 4);
          *(unsigned*)(smem + a) = pk;
        }
      }
    }
    __syncthreads();
    unsigned short* tT = (unsigned short*)Cv;
#pragma unroll
    for (int it = 0; it < 8; it++) {
      int ml = (t >> 4) + it * 16, chunk = t & 15;
      int a = ((ml << 8) + (chunk << 4)) ^ ((ml & 15) << 4);
      size_t g = ((size_t)b * KN_ + (n0 + ml)) * KC2_ + m0 + chunk * 8;
      *(bf16x8*)&tT[g] = *(const bf16x8*)(smem + a);
    }
    return;
  }

#pragma unroll
  for (int i = 0; i < 4; i++) {
#pragma unroll
    for (int r = 0; r < 4; r++) {
      const int row = m0 + wr * 64 + i * 16 + ((lane >> 4) << 2) + r;
      float pbias = 0.f, pinv = 1.f, padd = 0.f;
      if constexpr (EPI == EPI_VSCALE) pbias = ep.bias[row];
      if constexpr (EPI == EPI_FINAL) {
        pbias = ep.bias[row];
        float iv = ep.gamma[row] * rsqrtf(ep.var[row] + 1e-5f);
        pinv = iv;
        padd = ep.beta[row] - ep.mean[row] * iv;
      }
#pragma unroll
      for (int j = 0; j < 4; j++) {
        const int col = n0 + wc * 64 + j * 16 + lr;
        float v = acc[i][j][r];
        size_t o = (size_t)b * sC + (size_t)row * ldc + col;
        if constexpr (EPI == EPI_PAIR) {
          unsigned short h = f2bf(v);
          ((unsigned short*)Cv)[o] = h;
          ((unsigned short*)Cv2)[o] = f2bf(v - bf2f(h));
        } else if constexpr (EPI == EPI_VSCALE) {
          float sc = ep.scale[(size_t)b * ep.scale_stride + col];
          ((unsigned short*)Cv)[o] = f2bf((v + pbias) * sc);
        } else {  // EPI_FINAL
          float h = (v + pbias) * pinv + padd;
          h = fmaxf(h, 0.f);
          float xval = ep.xf[(size_t)b * ep.xf_stride + o - (size_t)b * sC];
          ((float*)Cv)[o] = h + xval;
        }
      }
    }
  }
}

// generic single-GEMM kernel (64 KB LDS, 2-phase)
template<int EPI>
__global__ __launch_bounds__(256) void gemm_one(
    const unsigned short* __restrict__ A0, const unsigned short* __restrict__ A1,
    long sA, int lda, int seg,
    const unsigned short* __restrict__ B0, const unsigned short* __restrict__ B1,
    long sB, int ldb,
    void* __restrict__ Cv, void* __restrict__ Cv2, long sC, int ldc, int K,
    EpiParams ep) {
  __shared__ __align__(16) char smem[65536];
  int bx, by, b;
  xcd_swizzle(bx, by, b);
  gemm_core<EPI>(smem, bx, by, b, A0, A1, sA, lda, seg, B0, B1, sB, ldb,
                 Cv, Cv2, sC, ldc, K, ep);
}

// fused x_q + x_k projections: one 512-block launch
__global__ __launch_bounds__(256) void proj2_kernel(
    const unsigned short* __restrict__ qThi, const unsigned short* __restrict__ qTlo,
    const unsigned short* __restrict__ Wqhi, const unsigned short* __restrict__ Wqlo,
    unsigned short* __restrict__ xqhi, unsigned short* __restrict__ xqlo,
    const unsigned short* __restrict__ xThi, const unsigned short* __restrict__ xTlo,
    const unsigned short* __restrict__ Wkhi, const unsigned short* __restrict__ Wklo,
    unsigned short* __restrict__ xkhi, unsigned short* __restrict__ xklo) {
  __shared__ __align__(16) char smem[65536];
  int f = (int)blockIdx.x;
  f = (f & 7) * 64 + (f >> 3);  // XCD swizzle over 512
  EpiParams ep{};
  if (f < 256) {
    int bx = f & 1, by = (f >> 1) & 15, b = f >> 5;
    gemm_core<EPI_PAIR>(smem, bx, by, b, qThi, qTlo, (long)KN_ * KC_, KC_, KC_,
                        Wqhi, Wqlo, 0, KC_, xqhi, xqlo, (long)KN_ * KC2_, KC2_,
                        3 * KC_, ep);
  } else {
    int g = f - 256;
    int bx = g & 1, by = (g >> 1) & 15, b = g >> 5;
    gemm_core<EPI_PAIR>(smem, bx, by, b, xThi, xTlo, (long)KN_ * KC2_, KC2_, KC2_,
                        Wkhi, Wklo, 0, KC2_, xkhi, xklo, (long)KN_ * KC2_, KC2_,
                        3 * KC2_, ep);
  }
}

// ---------------- launcher ----------------
extern "C" void kernel_launch(void* const* d_in, const int* in_sizes, int n_in,
                              void* d_out, int out_size, void* d_ws, size_t ws_size,
                              hipStream_t stream) {
  (void)in_sizes; (void)n_in; (void)out_size; (void)ws_size;
  const float* q     = (const float*)d_in[0];
  const float* x     = (const float*)d_in[1];
  const float* Wq    = (const float*)d_in[2];
  const float* Wk    = (const float*)d_in[3];
  const float* Wv    = (const float*)d_in[4];
  const float* bv    = (const float*)d_in[5];
  const float* Wt    = (const float*)d_in[6];
  const float* bt    = (const float*)d_in[7];
  const float* gamma = (const float*)d_in[8];
  const float* beta  = (const float*)d_in[9];
  const float* rmean = (const float*)d_in[10];
  const float* rvar  = (const float*)d_in[11];
  float* out = (float*)d_out;

  // workspace (~164 MiB)
  const size_t SZ_qT = (size_t)KB_ * KN_ * KC_ * 2;   // 16 MiB
  const size_t SZ_xT = (size_t)KB_ * KN_ * KC2_ * 2;  //  8 MiB
  char* ws = (char*)d_ws;
  size_t off = 0;
  auto alloc = [&](size_t bytes) {
    char* p = ws + off;
    off += (bytes + 255) & ~(size_t)255;
    return p;
  };
  unsigned short* qThi = (unsigned short*)alloc(SZ_qT);
  unsigned short* qTlo = (unsigned short*)alloc(SZ_qT);
  unsigned short* xThi = (unsigned short*)alloc(SZ_xT);
  unsigned short* xTlo = (unsigned short*)alloc(SZ_xT);
  unsigned short* xqhi = (unsigned short*)alloc(SZ_xT);
  unsigned short* xqlo = (unsigned short*)alloc(SZ_xT);
  unsigned short* xkhi = (unsigned short*)alloc(SZ_xT);
  unsigned short* xklo = (unsigned short*)alloc(SZ_xT);
  unsigned short* x_v  = (unsigned short*)alloc((size_t)KB_ * KC2_ * KN_ * 2);
  unsigned short* tT   = (unsigned short*)alloc(SZ_xT);
  unsigned short* Wqhi = (unsigned short*)alloc((size_t)KC2_ * KC_ * 2);
  unsigned short* Wqlo = (unsigned short*)alloc((size_t)KC2_ * KC_ * 2);
  unsigned short* Wkhi = (unsigned short*)alloc((size_t)KC2_ * KC2_ * 2);
  unsigned short* Wklo = (unsigned short*)alloc((size_t)KC2_ * KC2_ * 2);
  unsigned short* Wvb  = (unsigned short*)alloc((size_t)KC2_ * KC_ * 2);
  unsigned short* Wtb  = (unsigned short*)alloc((size_t)KC2_ * KC2_ * 2);
  float* rsv     = (float*)alloc((size_t)KB_ * KN_ * 4);
  float* denom   = (float*)alloc((size_t)KB_ * KN_ * 4);
  float* rowpart = (float*)alloc((size_t)KB_ * KN_ * 32 * 4);
  unsigned short* uT = (unsigned short*)alloc((size_t)KB_ * KN_ * KN_ * 2);   // 64 MiB

  dim3 blk(256);

  // weights -> bf16
  cvt_pair_kernel<<<dim3(KC2_ * KC_ / 1024), blk, 0, stream>>>(Wq, Wqhi, Wqlo, KC2_ * KC_);
  cvt_pair_kernel<<<dim3(KC2_ * KC2_ / 1024), blk, 0, stream>>>(Wk, Wkhi, Wklo, KC2_ * KC2_);
  cvt_kernel<<<dim3(KC2_ * KC_ / 1024), blk, 0, stream>>>(Wv, Wvb, KC2_ * KC_);
  cvt_kernel<<<dim3(KC2_ * KC2_ / 1024), blk, 0, stream>>>(Wt, Wtb, KC2_ * KC2_);

  // q^T, x^T fp32 -> hi/lo bf16 pairs (K contiguous)
  transpose_pair_kernel<<<dim3(KN_ / 64, KC_ / 64, KB_), blk, 0, stream>>>(
      q, (long)KC_ * KN_, qThi, qTlo, (long)KN_ * KC_, KC_, KN_);
  transpose_pair_kernel<<<dim3(KN_ / 64, KC2_ / 64, KB_), blk, 0, stream>>>(
      x, (long)KC2_ * KN_, xThi, xTlo, (long)KN_ * KC2_, KC2_, KN_);

  // x_q / x_kT projections (fp32-grade via segmented-K)
  proj2_kernel<<<dim3(512), blk, 0, stream>>>(qThi, qTlo, Wqhi, Wqlo, xqhi, xqlo,
                                              xThi, xTlo, Wkhi, Wklo, xkhi, xklo);

  // energy + exp + transpose + row partials (2-phase dbuf, counted vmcnt)
  energy_kernel<<<dim3(KN_ / 128, KN_ / 128, KB_), blk, 0, stream>>>(
      xqhi, xqlo, xkhi, xklo, uT, rowpart);
  rowreduce_kernel<<<dim3(KB_ * KN_ / 256), blk, 0, stream>>>(rowpart, rsv);

  // x_v'[b][o][n] = (Wv[o][:].qT[n][:] + bv[o]) * rsv[b][n]
  EpiParams e3{}; e3.bias = bv; e3.scale = rsv; e3.scale_stride = KN_;
  gemm_one<EPI_VSCALE><<<dim3(KN_ / 128, KC2_ / 128, KB_), blk, 0, stream>>>(
      Wvb, nullptr, 0, KC_, 0, qThi, nullptr, (long)KN_ * KC_, KC_,
      x_v, nullptr, (long)KC2_ * KN_, KN_, KC_, e3);

  // denom[b][m] = sum_n uT[m][n] * rsv[n]
  denom_kernel<<<dim3(KN_ / 4, KB_), blk, 0, stream>>>(uT, rsv, denom);

  // x_r GEMM with fused renorm + subtract + transpose -> tT[m][c]
  EpiParams e5{}; e5.xf = x; e5.xf_stride = (long)KC2_ * KN_;
  e5.scale = denom; e5.scale_stride = KN_;
  gemm_one<EPI_XRT><<<dim3(KN_ / 128, KC2_ / 128, KB_), blk, 0, stream>>>(
      x_v, nullptr, (long)KC2_ * KN_, KN_, 0, uT, nullptr, (long)KN_ * KN_, KN_,
      tT, nullptr, 0, 0, KN_, e5);

  // out[b][o][n] = relu(BN(Wt[o][:].tT[n][:] + bt[o])) + x[b][o][n]
  EpiParams e6{}; e6.bias = bt; e6.xf = x; e6.xf_stride = (long)KC2_ * KN_;
  e6.gamma = gamma; e6.beta = beta; e6.mean = rmean; e6.var = rvar;
  gemm_one<EPI_FINAL><<<dim3(KN_ / 128, KC2_ / 128, KB_), blk, 0, stream>>>(
      Wtb, nullptr, 0, KC2_, 0, tT, nullptr, (long)KN_ * KC2_, KC2_,
      out, nullptr, (long)KC2_ * KN_, KN_, KC2_, e6);
}